// Round 4
// baseline (1693.224 us; speedup 1.0000x reference)
//
#include <hip/hip_runtime.h>
#include <math.h>

#define NG    64
#define NN    20000
#define NE    160000
#define NE2   180000
#define FEATN 128
#define HIDN  64
#define HEADS 8
#define HD    512  // HEADS*HIDN

typedef unsigned short u16;
typedef __bf16 bf16x8 __attribute__((ext_vector_type(8)));
typedef u16 us8 __attribute__((ext_vector_type(8)));
typedef float f32x4 __attribute__((ext_vector_type(4)));

static __device__ __forceinline__ void atomicMaxNonneg(float* addr, float v) {
  atomicMax((unsigned int*)addr, __float_as_uint(v));
}

static __device__ __forceinline__ u16 f2bf(float f) {
  unsigned int u = __float_as_uint(f);
  u += 0x7fffu + ((u >> 16) & 1u);  // RNE
  return (u16)(u >> 16);
}
static __device__ __forceinline__ float bf2f(u16 s) {
  return __uint_as_float(((unsigned int)s) << 16);
}

__global__ void zero_u32(unsigned int* __restrict__ p, int n) {
  int i = blockIdx.x * 256 + threadIdx.x;
  if (i < n) p[i] = 0u;
}

// deg histogram over dst (with self loops) + batch histogram, one pass
__global__ void build_counts(const int* __restrict__ ei, const int* __restrict__ batch,
                             int* __restrict__ deg, int* __restrict__ gcnt) {
  int i = blockIdx.x * 256 + threadIdx.x;
  if (i < NE2) {
    int d = (i < NE) ? ei[NE + i] : (i - NE);
    atomicAdd(&deg[d], 1);
  }
  if (i < NN) atomicAdd(&gcnt[batch[i]], 1);
}

__global__ __launch_bounds__(1024) void scan_exclusive(const int* __restrict__ deg,
                                                       int* __restrict__ off,
                                                       int* __restrict__ cur, int n) {
  __shared__ int tmp[1024];
  __shared__ int carry_s;
  int tid = (int)threadIdx.x;
  if (tid == 0) carry_s = 0;
  __syncthreads();
  for (int base = 0; base < n; base += 1024) {
    int i = base + tid;
    int v = (i < n) ? deg[i] : 0;
    tmp[tid] = v;
    __syncthreads();
    for (int o = 1; o < 1024; o <<= 1) {
      int t = 0;
      if (tid >= o) t = tmp[tid - o];
      __syncthreads();
      tmp[tid] += t;
      __syncthreads();
    }
    int carry = carry_s;
    if (i < n) {
      int e = carry + tmp[tid] - v;  // exclusive
      off[i] = e;
      cur[i] = e;
    }
    __syncthreads();
    if (tid == 0) carry_s = carry + tmp[1023];
    __syncthreads();
  }
  if (tid == 0) off[n] = carry_s;
}

__global__ void scatter_csr(const int* __restrict__ ei, int* __restrict__ cur,
                            int* __restrict__ csr) {
  int e = blockIdx.x * 256 + threadIdx.x;
  if (e >= NE2) return;
  int d = (e < NE) ? ei[NE + e] : (e - NE);
  int p = atomicAdd(&cur[d], 1);
  csr[p] = e;
}

// fp32 [M][K] -> bf16 hi/lo [M][K] (flat, 4 elems/thread)
__global__ void split_mat(const float* __restrict__ X, u16* __restrict__ hi,
                          u16* __restrict__ lo, int n4) {
  int i = blockIdx.x * 256 + threadIdx.x;
  if (i >= n4) return;
  float4 v = ((const float4*)X)[i];
  ushort4 h, l;
  h.x = f2bf(v.x); l.x = f2bf(v.x - bf2f(h.x));
  h.y = f2bf(v.y); l.y = f2bf(v.y - bf2f(h.y));
  h.z = f2bf(v.z); l.z = f2bf(v.z - bf2f(h.z));
  h.w = f2bf(v.w); l.w = f2bf(v.w - bf2f(h.w));
  ((ushort4*)hi)[i] = h;
  ((ushort4*)lo)[i] = l;
}

// W[K][N] row-major -> WT hi/lo [N][K] bf16, all three GAT weights in one launch
__global__ void split_weightsT(const float* __restrict__ W1, const float* __restrict__ W2,
                               const float* __restrict__ W3,
                               u16* __restrict__ w1h, u16* __restrict__ w1l,
                               u16* __restrict__ w2h, u16* __restrict__ w2l,
                               u16* __restrict__ w3h, u16* __restrict__ w3l) {
  const int S1 = FEATN * HD;       // 65536
  const int S2 = S1 + HD * HD;     // + 262144
  const int S3 = S2 + HD * HD;
  int i = blockIdx.x * 256 + threadIdx.x;
  if (i >= S3) return;
  if (i < S1) {
    int k = i / HD, n = i % HD;
    float v = W1[i];
    u16 h = f2bf(v), l = f2bf(v - bf2f(h));
    w1h[n * FEATN + k] = h;
    w1l[n * FEATN + k] = l;
  } else if (i < S2) {
    int j = i - S1;
    int k = j / HD, n = j % HD;
    float v = W2[j];
    u16 h = f2bf(v), l = f2bf(v - bf2f(h));
    w2h[n * HD + k] = h;
    w2l[n * HD + k] = l;
  } else {
    int j = i - S2;
    int k = j / HD, n = j % HD;
    float v = W3[j];
    u16 h = f2bf(v), l = f2bf(v - bf2f(h));
    w3h[n * HD + k] = h;
    w3l[n * HD + k] = l;
  }
}

// ---------- bf16-split MFMA GEMM: C[M,N] = A[M,K] @ B[K,N] ----------
// A given as hi/lo bf16 [M][K]; B given as hi/lo bf16 TRANSPOSED [N][K].
// C = Ah*Bh + Ah*Bl + Al*Bh (fp32 accum). Tile 128x128, BK=32, 4 waves (2x2).
template <int K, int N>
__global__ __launch_bounds__(256) void gemm_bf3(const u16* __restrict__ Ahg,
                                                const u16* __restrict__ Alg,
                                                const u16* __restrict__ Bhg,
                                                const u16* __restrict__ Blg,
                                                float* __restrict__ C, int M) {
  constexpr int BKP = 40;  // padded LDS k-stride (2-way bank conflict max)
  __shared__ u16 sAh[128][BKP], sAl[128][BKP], sBh[128][BKP], sBl[128][BKP];
  const int t = (int)threadIdx.x;
  const int bm = blockIdx.x * 128, bn = blockIdx.y * 128;
  const int lane = t & 63, w = t >> 6;
  const int wm = w >> 1, wn = w & 1;
  const int fr = lane & 15, kg = lane >> 4;

  f32x4 zero4 = {0.f, 0.f, 0.f, 0.f};
  f32x4 acc[4][4];
#pragma unroll
  for (int i = 0; i < 4; i++)
#pragma unroll
    for (int j = 0; j < 4; j++) acc[i][j] = zero4;

  for (int k0 = 0; k0 < K; k0 += 32) {
    __syncthreads();  // previous tile consumed
#pragma unroll
    for (int i = 0; i < 2; i++) {
      int idx = t * 2 + i;           // 0..511
      int r = idx >> 2, c = (idx & 3) * 8;
      int arow = bm + r;
      us8 vh, vl;
      if (arow < M) {
        vh = *(const us8*)(Ahg + (size_t)arow * K + k0 + c);
        vl = *(const us8*)(Alg + (size_t)arow * K + k0 + c);
      } else {
        vh = (us8)(u16)0;
        vl = (us8)(u16)0;
      }
      *(us8*)&sAh[r][c] = vh;
      *(us8*)&sAl[r][c] = vl;
      int brow = bn + r;  // always < N (N % 128 == 0)
      *(us8*)&sBh[r][c] = *(const us8*)(Bhg + (size_t)brow * K + k0 + c);
      *(us8*)&sBl[r][c] = *(const us8*)(Blg + (size_t)brow * K + k0 + c);
    }
    __syncthreads();
    bf16x8 fah[4], fal[4], fbh[4], fbl[4];
#pragma unroll
    for (int mi = 0; mi < 4; mi++) {
      fah[mi] = *(const bf16x8*)&sAh[wm * 64 + mi * 16 + fr][kg * 8];
      fal[mi] = *(const bf16x8*)&sAl[wm * 64 + mi * 16 + fr][kg * 8];
    }
#pragma unroll
    for (int ni = 0; ni < 4; ni++) {
      fbh[ni] = *(const bf16x8*)&sBh[wn * 64 + ni * 16 + fr][kg * 8];
      fbl[ni] = *(const bf16x8*)&sBl[wn * 64 + ni * 16 + fr][kg * 8];
    }
#pragma unroll
    for (int mi = 0; mi < 4; mi++)
#pragma unroll
      for (int ni = 0; ni < 4; ni++) {
        acc[mi][ni] = __builtin_amdgcn_mfma_f32_16x16x32_bf16(fah[mi], fbh[ni], acc[mi][ni], 0, 0, 0);
        acc[mi][ni] = __builtin_amdgcn_mfma_f32_16x16x32_bf16(fah[mi], fbl[ni], acc[mi][ni], 0, 0, 0);
        acc[mi][ni] = __builtin_amdgcn_mfma_f32_16x16x32_bf16(fal[mi], fbh[ni], acc[mi][ni], 0, 0, 0);
      }
  }
  // epilogue: D layout col=lane&15, row=4*(lane>>4)+reg  [m89/m91 verified]
#pragma unroll
  for (int mi = 0; mi < 4; mi++) {
    int rbase = bm + wm * 64 + mi * 16 + kg * 4;
#pragma unroll
    for (int ni = 0; ni < 4; ni++) {
      int col = bn + wn * 64 + ni * 16 + fr;
#pragma unroll
      for (int r = 0; r < 4; r++) {
        int row = rbase + r;
        if (row < M) C[(size_t)row * N + col] = acc[mi][ni][r];
      }
    }
  }
}

// ---------------- fp32 tiled GEMM (kept for the small Wg GEMM) ----------------
template <int BN, int TN>
__global__ __launch_bounds__(256) void gemm_f32(const float* __restrict__ A,
                                                const float* __restrict__ B,
                                                float* __restrict__ C, int M, int K, int Nld) {
  constexpr int BM = 128, BK = 16, TM = 8;
  __shared__ float As[BK][BM + 4];
  __shared__ float Bs[BK][BN + 4];
  const int tid = (int)threadIdx.x;
  const int bm = blockIdx.x * BM;
  const int bn = blockIdx.y * BN;
  const int arow = tid >> 1;
  const int acol = (tid & 1) * 8;
  const int brow = tid >> 4;
  const int bcol = (tid & 15) * (BN / 16);
  const int tmr = (tid >> 4) * TM;
  const int tnc = (tid & 15) * TN;

  float acc[TM][TN];
#pragma unroll
  for (int i = 0; i < TM; i++)
#pragma unroll
    for (int j = 0; j < TN; j++) acc[i][j] = 0.f;

  const bool avalid = (bm + arow) < M;
  const float* Arow = A + (size_t)(bm + arow) * K + acol;

  for (int k0 = 0; k0 < K; k0 += BK) {
    float4 a0, a1;
    if (avalid) {
      a0 = *(const float4*)(Arow + k0);
      a1 = *(const float4*)(Arow + k0 + 4);
    } else {
      a0 = make_float4(0.f, 0.f, 0.f, 0.f);
      a1 = a0;
    }
    float4 bv[BN / 64];
#pragma unroll
    for (int l = 0; l < BN / 64; l++)
      bv[l] = *(const float4*)(B + (size_t)(k0 + brow) * Nld + bn + bcol + 4 * l);
    __syncthreads();
    As[acol + 0][arow] = a0.x; As[acol + 1][arow] = a0.y;
    As[acol + 2][arow] = a0.z; As[acol + 3][arow] = a0.w;
    As[acol + 4][arow] = a1.x; As[acol + 5][arow] = a1.y;
    As[acol + 6][arow] = a1.z; As[acol + 7][arow] = a1.w;
#pragma unroll
    for (int l = 0; l < BN / 64; l++) *(float4*)&Bs[brow][bcol + 4 * l] = bv[l];
    __syncthreads();
#pragma unroll
    for (int k = 0; k < BK; k++) {
      float a[TM], b[TN];
#pragma unroll
      for (int i = 0; i < TM; i += 4) {
        float4 t = *(const float4*)&As[k][tmr + i];
        a[i] = t.x; a[i + 1] = t.y; a[i + 2] = t.z; a[i + 3] = t.w;
      }
#pragma unroll
      for (int j = 0; j < TN; j += 4) {
        float4 t = *(const float4*)&Bs[k][tnc + j];
        b[j] = t.x; b[j + 1] = t.y; b[j + 2] = t.z; b[j + 3] = t.w;
      }
#pragma unroll
      for (int i = 0; i < TM; i++)
#pragma unroll
        for (int j = 0; j < TN; j++) acc[i][j] += a[i] * b[j];
    }
  }
#pragma unroll
  for (int i = 0; i < TM; i++) {
    int row = bm + tmr + i;
    if (row < M) {
#pragma unroll
      for (int j = 0; j < TN; j += 4) {
        float4 t = make_float4(acc[i][j], acc[i][j + 1], acc[i][j + 2], acc[i][j + 3]);
        *(float4*)(C + (size_t)row * Nld + bn + tnc + j) = t;
      }
    }
  }
}

// as_h[n,h] = sum_c hfeat[n,h,c]*aS[h,c]; same for ad_h. One wave per node.
__global__ void attn_proj(const float* __restrict__ hfeat, const float* __restrict__ aS,
                          const float* __restrict__ aD, float* __restrict__ as_h,
                          float* __restrict__ ad_h) {
  int wid = (blockIdx.x * 256 + (int)threadIdx.x) >> 6;
  int lane = (int)threadIdx.x & 63;
  if (wid >= NN) return;
  const float* hp = hfeat + (size_t)wid * HD;
#pragma unroll
  for (int h = 0; h < HEADS; h++) {
    float hv = hp[h * HIDN + lane];
    float sv = hv * aS[h * HIDN + lane];
    float dv = hv * aD[h * HIDN + lane];
#pragma unroll
    for (int o = 32; o; o >>= 1) {
      sv += __shfl_xor(sv, o);
      dv += __shfl_xor(dv, o);
    }
    if (lane == 0) {
      as_h[wid * HEADS + h] = sv;
      ad_h[wid * HEADS + h] = dv;
    }
  }
}

// One wave per (node, head): two-pass segment softmax + aggregate.
__global__ void gat_agg(const float* __restrict__ hfeat, const float* __restrict__ as_h,
                        const float* __restrict__ ad_h, const int* __restrict__ off,
                        const int* __restrict__ csr, const int* __restrict__ ei,
                        const float* __restrict__ bias, float* __restrict__ outb) {
  int wid = (blockIdx.x * 256 + (int)threadIdx.x) >> 6;
  int lane = (int)threadIdx.x & 63;
  if (wid >= NN * HEADS) return;
  int n = wid >> 3, h = wid & 7;
  int s0 = off[n], s1 = off[n + 1];
  float adn = ad_h[n * HEADS + h];
  float m = -1e30f;
  for (int p = s0; p < s1; ++p) {
    int e = csr[p];
    int src = (e < NE) ? ei[e] : (e - NE);
    float ev = as_h[src * HEADS + h] + adn;
    ev = (ev > 0.f) ? ev : 0.2f * ev;
    m = fmaxf(m, ev);
  }
  float ssum = 0.f, acc = 0.f;
  for (int p = s0; p < s1; ++p) {
    int e = csr[p];
    int src = (e < NE) ? ei[e] : (e - NE);
    float ev = as_h[src * HEADS + h] + adn;
    ev = (ev > 0.f) ? ev : 0.2f * ev;
    float wgt = expf(ev - m);
    ssum += wgt;
    acc += wgt * hfeat[(size_t)src * HD + h * HIDN + lane];
  }
  acc *= 1.f / (ssum + 1e-16f);
  if (bias) acc += bias[h * HIDN + lane];
  outb[(size_t)n * HD + h * HIDN + lane] = acc;
}

// One wave per node. y = relu(sum norm*h[src] + bg); segmax into z2 region.
__global__ void gcn_agg(const float* __restrict__ h, const int* __restrict__ deg,
                        const int* __restrict__ off, const int* __restrict__ csr,
                        const int* __restrict__ ei, const float* __restrict__ bg,
                        const int* __restrict__ batch, float* __restrict__ z) {
  int wid = (blockIdx.x * 256 + (int)threadIdx.x) >> 6;
  int lane = (int)threadIdx.x & 63;
  if (wid >= NN) return;
  int n = wid;
  float dinv_n = rsqrtf((float)deg[n]);
  int s0 = off[n], s1 = off[n + 1];
  float acc = 0.f;
  for (int p = s0; p < s1; ++p) {
    int e = csr[p];
    int src = (e < NE) ? ei[e] : (e - NE);
    float nrm = rsqrtf((float)deg[src]) * dinv_n;
    acc += nrm * h[(size_t)src * HIDN + lane];
  }
  float y = fmaxf(acc + bg[lane], 0.f);
  atomicMaxNonneg(&z[batch[n] * 128 + 64 + lane], y);
}

// Block-level merge of per-wave (graph, sum, sumsq) then atomics.
// Requires: every wave in the block active (grids are exact multiples of 4 waves).
static __device__ __forceinline__ void block_stats_accum(float v, float v2, int g, int lane,
                                                         float* __restrict__ gsum,
                                                         float* __restrict__ gsumsq) {
#pragma unroll
  for (int o = 32; o; o >>= 1) {
    v += __shfl_xor(v, o);
    v2 += __shfl_xor(v2, o);
  }
  __shared__ float s_v[4], s_v2[4];
  __shared__ int s_g[4];
  int wavei = (int)threadIdx.x >> 6;
  if (lane == 0) {
    s_v[wavei] = v;
    s_v2[wavei] = v2;
    s_g[wavei] = g;
  }
  __syncthreads();
  if (threadIdx.x == 0) {
#pragma unroll
    for (int a = 0; a < 4; a++) {
      int ga = s_g[a];
      if (ga < 0) continue;
      float V = s_v[a], V2 = s_v2[a];
#pragma unroll
      for (int b = a + 1; b < 4; b++)
        if (s_g[b] == ga) {
          V += s_v[b];
          V2 += s_v2[b];
          s_g[b] = -1;
        }
      atomicAdd(&gsum[ga], V);
      atomicAdd(&gsumsq[ga], V2);
    }
  }
}

// Graph-LN stats: one wave per row (grid exact: NN % 4 == 0).
template <int F>
__global__ void ln_stats(const float* __restrict__ in, const int* __restrict__ batch,
                         float* __restrict__ gsum, float* __restrict__ gsumsq) {
  int wid = (blockIdx.x * 256 + (int)threadIdx.x) >> 6;
  int lane = (int)threadIdx.x & 63;
  float v = 0.f, v2 = 0.f;
  const float* row = in + (size_t)wid * F;
#pragma unroll
  for (int f = lane; f < F; f += 64) {
    float x = row[f];
    v += x;
    v2 += x * x;
  }
  block_stats_accum(v, v2, batch[wid], lane, gsum, gsumsq);
}

// Layer 3: head-mean + b3 -> h3, fused with LN stats. One wave per node (exact grid).
__global__ void head_mean_stats(const float* __restrict__ agg, const float* __restrict__ b3,
                                const int* __restrict__ batch, float* __restrict__ h3,
                                float* __restrict__ gsum, float* __restrict__ gsumsq) {
  int wid = (blockIdx.x * 256 + (int)threadIdx.x) >> 6;
  int lane = (int)threadIdx.x & 63;
  float s = 0.f;
#pragma unroll
  for (int h = 0; h < HEADS; h++) s += agg[(size_t)wid * HD + h * HIDN + lane];
  s = s * 0.125f + b3[lane];
  h3[wid * HIDN + lane] = s;
  block_stats_accum(s, s * s, batch[wid], lane, gsum, gsumsq);
}

template <int F, bool ZMAX>
__global__ void ln_apply(float* __restrict__ buf, const int* __restrict__ batch,
                         const float* __restrict__ gsum, const float* __restrict__ gsumsq,
                         const int* __restrict__ gcnt, const float* __restrict__ w,
                         const float* __restrict__ b, float* __restrict__ z) {
  int i = blockIdx.x * 256 + (int)threadIdx.x;
  if (i >= NN * F) return;
  int n = i / F, f = i % F;
  int g = batch[n];
  float cnt = (float)gcnt[g] * (float)F;
  float mean = gsum[g] / cnt;
  float var = gsumsq[g] / cnt - mean * mean;
  float y = (buf[i] - mean) * rsqrtf(var + 1e-5f) * w[f] + b[f];
  y = fmaxf(y, 0.f);
  buf[i] = y;
  if (ZMAX) atomicMaxNonneg(&z[g * 128 + f], y);
}

__global__ __launch_bounds__(64) void mlp_head(const float* __restrict__ z,
                                               const float* __restrict__ Wl0, const float* __restrict__ bl0,
                                               const float* __restrict__ Wl1, const float* __restrict__ bl1,
                                               const float* __restrict__ Wl2, const float* __restrict__ bl2,
                                               const float* __restrict__ Wo, const float* __restrict__ bo,
                                               float* __restrict__ out) {
  __shared__ float zs[128], t0[64], t1[64], t2[64];
  int g = blockIdx.x, t = (int)threadIdx.x;
  zs[t] = z[g * 128 + t];
  zs[64 + t] = z[g * 128 + 64 + t];
  __syncthreads();
  float a = bl0[t];
  for (int k = 0; k < 128; k++) a += zs[k] * Wl0[k * 64 + t];
  t0[t] = fmaxf(a, 0.f);
  __syncthreads();
  a = bl1[t];
  for (int k = 0; k < 64; k++) a += t0[k] * Wl1[k * 64 + t];
  t1[t] = fmaxf(a, 0.f);
  __syncthreads();
  a = bl2[t];
  for (int k = 0; k < 64; k++) a += t1[k] * Wl2[k * 64 + t];
  t2[t] = fmaxf(a, 0.f);
  __syncthreads();
  if (t < 2) {
    float o = bo[t];
    for (int k = 0; k < 64; k++) o += t2[k] * Wo[k * 2 + t];
    out[g * 2 + t] = o;
  }
  out[128 + g * 128 + t] = zs[t];
  out[128 + g * 128 + 64 + t] = zs[64 + t];
}

extern "C" void kernel_launch(void* const* d_in, const int* in_sizes, int n_in,
                              void* d_out, int out_size, void* d_ws, size_t ws_size,
                              hipStream_t stream) {
  const float* x = (const float*)d_in[0];
  const int* ei = (const int*)d_in[1];
  const int* batch = (const int*)d_in[2];
  const float* W1 = (const float*)d_in[3];
  const float* aS1 = (const float*)d_in[4];
  const float* aD1 = (const float*)d_in[5];
  const float* b1 = (const float*)d_in[6];
  const float* W2 = (const float*)d_in[7];
  const float* aS2 = (const float*)d_in[8];
  const float* aD2 = (const float*)d_in[9];
  const float* b2 = (const float*)d_in[10];
  const float* W3 = (const float*)d_in[11];
  const float* aS3 = (const float*)d_in[12];
  const float* aD3 = (const float*)d_in[13];
  const float* b3 = (const float*)d_in[14];
  const float* Wg = (const float*)d_in[15];
  const float* bg = (const float*)d_in[16];
  const float* nw1 = (const float*)d_in[17];
  const float* nb1 = (const float*)d_in[18];
  const float* nw2 = (const float*)d_in[19];
  const float* nb2 = (const float*)d_in[20];
  const float* nw3 = (const float*)d_in[21];
  const float* nb3 = (const float*)d_in[22];
  const float* Wl0 = (const float*)d_in[23];
  const float* bl0 = (const float*)d_in[24];
  const float* Wl1 = (const float*)d_in[25];
  const float* bl1 = (const float*)d_in[26];
  const float* Wl2 = (const float*)d_in[27];
  const float* bl2 = (const float*)d_in[28];
  const float* Wo = (const float*)d_in[29];
  const float* bo = (const float*)d_in[30];
  float* out = (float*)d_out;

  char* wp = (char*)d_ws;
  auto alloc = [&](size_t bytes) -> void* {
    void* p = (void*)wp;
    wp += ((bytes + 255) & ~(size_t)255);
    return p;
  };
  float* bufH = (float*)alloc((size_t)NN * HD * 4);   // GEMM output (h features)
  float* bufA = (float*)alloc((size_t)NN * HD * 4);   // aggregation output
  float* f64b = (float*)alloc((size_t)NN * HIDN * 4); // gcn_h, later h3
  float* as_h = (float*)alloc((size_t)NN * HEADS * 4);
  float* ad_h = (float*)alloc((size_t)NN * HEADS * 4);
  // contiguous zero-init region: deg | gcnt | stats(6*NG) | zbuf(NG*128)
  const int ZWORDS = NN + NG + 6 * NG + NG * 128;
  int* initblk = (int*)alloc((size_t)ZWORDS * 4);
  int* deg = initblk;
  int* gcnt = deg + NN;
  float* stats = (float*)(gcnt + NG);
  float* zbuf = stats + 6 * NG;
  int* off = (int*)alloc((size_t)(NN + 1) * 4);
  int* cur = (int*)alloc((size_t)NN * 4);
  int* csr = (int*)alloc((size_t)NE2 * 4);
  // bf16 split buffers
  u16* xhi = (u16*)alloc((size_t)NN * FEATN * 2);
  u16* xlo = (u16*)alloc((size_t)NN * FEATN * 2);
  u16* ahi = (u16*)alloc((size_t)NN * HD * 2);
  u16* alo = (u16*)alloc((size_t)NN * HD * 2);
  u16* w1h = (u16*)alloc((size_t)FEATN * HD * 2);
  u16* w1l = (u16*)alloc((size_t)FEATN * HD * 2);
  u16* w2h = (u16*)alloc((size_t)HD * HD * 2);
  u16* w2l = (u16*)alloc((size_t)HD * HD * 2);
  u16* w3h = (u16*)alloc((size_t)HD * HD * 2);
  u16* w3l = (u16*)alloc((size_t)HD * HD * 2);

  dim3 b256(256);
  zero_u32<<<(ZWORDS + 255) / 256, b256, 0, stream>>>((unsigned int*)initblk, ZWORDS);
  build_counts<<<(NE2 + 255) / 256, b256, 0, stream>>>(ei, batch, deg, gcnt);
  scan_exclusive<<<1, 1024, 0, stream>>>(deg, off, cur, NN);
  scatter_csr<<<(NE2 + 255) / 256, b256, 0, stream>>>(ei, cur, csr);
  // weight + input splits
  const int WTOT = FEATN * HD + 2 * HD * HD;
  split_weightsT<<<(WTOT + 255) / 256, b256, 0, stream>>>(W1, W2, W3, w1h, w1l, w2h, w2l, w3h, w3l);
  split_mat<<<(NN * FEATN / 4 + 255) / 256, b256, 0, stream>>>(x, xhi, xlo, NN * FEATN / 4);

  const int wgrid = (NN * 64) / 256;               // one wave per node (exact: 5000)
  const int hgrid = (NN * HEADS * 64 + 255) / 256; // one wave per (node,head)
  dim3 gmm((NN + 127) / 128, HD / 128);            // MFMA gemm grid (157 x 4)

  // GCN branch (fp32 path, isolated from MFMA changes)
  {
    dim3 g((NN + 127) / 128, 1);
    gemm_f32<64, 4><<<g, b256, 0, stream>>>(x, Wg, f64b, NN, FEATN, HIDN);
    gcn_agg<<<wgrid, b256, 0, stream>>>(f64b, deg, off, csr, ei, bg, batch, zbuf);
  }
  // GAT layer 1: x[N,128] -> bufA[N,512] (post-LN+relu)
  {
    gemm_bf3<FEATN, HD><<<gmm, b256, 0, stream>>>(xhi, xlo, w1h, w1l, bufH, NN);
    attn_proj<<<wgrid, b256, 0, stream>>>(bufH, aS1, aD1, as_h, ad_h);
    gat_agg<<<hgrid, b256, 0, stream>>>(bufH, as_h, ad_h, off, csr, ei, b1, bufA);
    ln_stats<HD><<<wgrid, b256, 0, stream>>>(bufA, batch, stats + 0, stats + NG);
    ln_apply<HD, false><<<(NN * HD + 255) / 256, b256, 0, stream>>>(
        bufA, batch, stats + 0, stats + NG, gcnt, nw1, nb1, nullptr);
  }
  // GAT layer 2
  {
    split_mat<<<(NN * HD / 4 + 255) / 256, b256, 0, stream>>>(bufA, ahi, alo, NN * HD / 4);
    gemm_bf3<HD, HD><<<gmm, b256, 0, stream>>>(ahi, alo, w2h, w2l, bufH, NN);
    attn_proj<<<wgrid, b256, 0, stream>>>(bufH, aS2, aD2, as_h, ad_h);
    gat_agg<<<hgrid, b256, 0, stream>>>(bufH, as_h, ad_h, off, csr, ei, b2, bufA);
    ln_stats<HD><<<wgrid, b256, 0, stream>>>(bufA, batch, stats + 2 * NG, stats + 3 * NG);
    ln_apply<HD, false><<<(NN * HD + 255) / 256, b256, 0, stream>>>(
        bufA, batch, stats + 2 * NG, stats + 3 * NG, gcnt, nw2, nb2, nullptr);
  }
  // GAT layer 3 (concat=False -> head mean), LN, relu, segmax into z1
  {
    split_mat<<<(NN * HD / 4 + 255) / 256, b256, 0, stream>>>(bufA, ahi, alo, NN * HD / 4);
    gemm_bf3<HD, HD><<<gmm, b256, 0, stream>>>(ahi, alo, w3h, w3l, bufH, NN);
    attn_proj<<<wgrid, b256, 0, stream>>>(bufH, aS3, aD3, as_h, ad_h);
    gat_agg<<<hgrid, b256, 0, stream>>>(bufH, as_h, ad_h, off, csr, ei, nullptr, bufA);
    head_mean_stats<<<wgrid, b256, 0, stream>>>(bufA, b3, batch, f64b,
                                                stats + 4 * NG, stats + 5 * NG);
    ln_apply<HIDN, true><<<(NN * HIDN + 255) / 256, b256, 0, stream>>>(
        f64b, batch, stats + 4 * NG, stats + 5 * NG, gcnt, nw3, nb3, zbuf);
  }
  // MLP head + z copy to output
  mlp_head<<<NG, 64, 0, stream>>>(zbuf, Wl0, bl0, Wl1, bl1, Wl2, bl2, Wo, bo, out);
}

// Round 6
// 1035.433 us; speedup vs baseline: 1.6353x; 1.6353x over previous
//
#include <hip/hip_runtime.h>
#include <math.h>

#define NG    64
#define NN    20000
#define NE    160000
#define NE2   180000
#define FEATN 128
#define HIDN  64
#define HEADS 8
#define HD    512  // HEADS*HIDN

typedef unsigned short u16;
typedef __bf16 bf16x8 __attribute__((ext_vector_type(8)));
typedef u16 us8 __attribute__((ext_vector_type(8)));
typedef float f32x4 __attribute__((ext_vector_type(4)));

static __device__ __forceinline__ void atomicMaxNonneg(float* addr, float v) {
  atomicMax((unsigned int*)addr, __float_as_uint(v));
}

static __device__ __forceinline__ u16 f2bf(float f) {
  unsigned int u = __float_as_uint(f);
  u += 0x7fffu + ((u >> 16) & 1u);  // RNE
  return (u16)(u >> 16);
}
static __device__ __forceinline__ float bf2f(u16 s) {
  return __uint_as_float(((unsigned int)s) << 16);
}

__global__ void zero_u32(unsigned int* __restrict__ p, int n) {
  int i = blockIdx.x * 256 + threadIdx.x;
  if (i < n) p[i] = 0u;
}

// deg histogram over dst (with self loops) + batch histogram, one pass
__global__ void build_counts(const int* __restrict__ ei, const int* __restrict__ batch,
                             int* __restrict__ deg, int* __restrict__ gcnt) {
  int i = blockIdx.x * 256 + threadIdx.x;
  if (i < NE2) {
    int d = (i < NE) ? ei[NE + i] : (i - NE);
    atomicAdd(&deg[d], 1);
  }
  if (i < NN) atomicAdd(&gcnt[batch[i]], 1);
}

__global__ void compute_dinv(const int* __restrict__ deg, float* __restrict__ dinv) {
  int i = blockIdx.x * 256 + threadIdx.x;
  if (i < NN) dinv[i] = rsqrtf((float)deg[i]);
}

__global__ __launch_bounds__(1024) void scan_exclusive(const int* __restrict__ deg,
                                                       int* __restrict__ off,
                                                       int* __restrict__ cur, int n) {
  __shared__ int tmp[1024];
  __shared__ int carry_s;
  int tid = (int)threadIdx.x;
  if (tid == 0) carry_s = 0;
  __syncthreads();
  for (int base = 0; base < n; base += 1024) {
    int i = base + tid;
    int v = (i < n) ? deg[i] : 0;
    tmp[tid] = v;
    __syncthreads();
    for (int o = 1; o < 1024; o <<= 1) {
      int t = 0;
      if (tid >= o) t = tmp[tid - o];
      __syncthreads();
      tmp[tid] += t;
      __syncthreads();
    }
    int carry = carry_s;
    if (i < n) {
      int e = carry + tmp[tid] - v;  // exclusive
      off[i] = e;
      cur[i] = e;
    }
    __syncthreads();
    if (tid == 0) carry_s = carry + tmp[1023];
    __syncthreads();
  }
  if (tid == 0) off[n] = carry_s;
}

// CSR by dst, materializing src ids per slot (dst of a segment == segment owner)
__global__ void scatter_csr(const int* __restrict__ ei, int* __restrict__ cur,
                            int* __restrict__ src_csr) {
  int e = blockIdx.x * 256 + threadIdx.x;
  if (e >= NE2) return;
  int s, d;
  if (e < NE) {
    s = ei[e];
    d = ei[NE + e];
  } else {
    s = e - NE;
    d = e - NE;
  }
  int p = atomicAdd(&cur[d], 1);
  src_csr[p] = s;
}

// fp32 [M][K] -> bf16 hi/lo [M][K] (flat, 4 elems/thread)
__global__ void split_mat(const float* __restrict__ X, u16* __restrict__ hi,
                          u16* __restrict__ lo, int n4) {
  int i = blockIdx.x * 256 + threadIdx.x;
  if (i >= n4) return;
  float4 v = ((const float4*)X)[i];
  ushort4 h, l;
  h.x = f2bf(v.x); l.x = f2bf(v.x - bf2f(h.x));
  h.y = f2bf(v.y); l.y = f2bf(v.y - bf2f(h.y));
  h.z = f2bf(v.z); l.z = f2bf(v.z - bf2f(h.z));
  h.w = f2bf(v.w); l.w = f2bf(v.w - bf2f(h.w));
  ((ushort4*)hi)[i] = h;
  ((ushort4*)lo)[i] = l;
}

// W[K][N] row-major -> WT hi/lo [N][K] bf16, all three GAT weights in one launch
__global__ void split_weightsT(const float* __restrict__ W1, const float* __restrict__ W2,
                               const float* __restrict__ W3,
                               u16* __restrict__ w1h, u16* __restrict__ w1l,
                               u16* __restrict__ w2h, u16* __restrict__ w2l,
                               u16* __restrict__ w3h, u16* __restrict__ w3l) {
  const int S1 = FEATN * HD;
  const int S2 = S1 + HD * HD;
  const int S3 = S2 + HD * HD;
  int i = blockIdx.x * 256 + threadIdx.x;
  if (i >= S3) return;
  if (i < S1) {
    int k = i / HD, n = i % HD;
    float v = W1[i];
    u16 h = f2bf(v), l = f2bf(v - bf2f(h));
    w1h[n * FEATN + k] = h;
    w1l[n * FEATN + k] = l;
  } else if (i < S2) {
    int j = i - S1;
    int k = j / HD, n = j % HD;
    float v = W2[j];
    u16 h = f2bf(v), l = f2bf(v - bf2f(h));
    w2h[n * HD + k] = h;
    w2l[n * HD + k] = l;
  } else {
    int j = i - S2;
    int k = j / HD, n = j % HD;
    float v = W3[j];
    u16 h = f2bf(v), l = f2bf(v - bf2f(h));
    w3h[n * HD + k] = h;
    w3l[n * HD + k] = l;
  }
}

// ---------- bf16-split MFMA GEMM: C[M,N] = A[M,K] @ B[K,N] ----------
template <int K, int N>
__global__ __launch_bounds__(256) void gemm_bf3(const u16* __restrict__ Ahg,
                                                const u16* __restrict__ Alg,
                                                const u16* __restrict__ Bhg,
                                                const u16* __restrict__ Blg,
                                                float* __restrict__ C, int M) {
  constexpr int BKP = 40;
  __shared__ u16 sAh[128][BKP], sAl[128][BKP], sBh[128][BKP], sBl[128][BKP];
  const int t = (int)threadIdx.x;
  const int bm = blockIdx.x * 128, bn = blockIdx.y * 128;
  const int lane = t & 63, w = t >> 6;
  const int wm = w >> 1, wn = w & 1;
  const int fr = lane & 15, kg = lane >> 4;

  f32x4 zero4 = {0.f, 0.f, 0.f, 0.f};
  f32x4 acc[4][4];
#pragma unroll
  for (int i = 0; i < 4; i++)
#pragma unroll
    for (int j = 0; j < 4; j++) acc[i][j] = zero4;

  for (int k0 = 0; k0 < K; k0 += 32) {
    __syncthreads();
#pragma unroll
    for (int i = 0; i < 2; i++) {
      int idx = t * 2 + i;
      int r = idx >> 2, c = (idx & 3) * 8;
      int arow = bm + r;
      us8 vh, vl;
      if (arow < M) {
        vh = *(const us8*)(Ahg + (size_t)arow * K + k0 + c);
        vl = *(const us8*)(Alg + (size_t)arow * K + k0 + c);
      } else {
        vh = (us8)(u16)0;
        vl = (us8)(u16)0;
      }
      *(us8*)&sAh[r][c] = vh;
      *(us8*)&sAl[r][c] = vl;
      int brow = bn + r;
      *(us8*)&sBh[r][c] = *(const us8*)(Bhg + (size_t)brow * K + k0 + c);
      *(us8*)&sBl[r][c] = *(const us8*)(Blg + (size_t)brow * K + k0 + c);
    }
    __syncthreads();
    bf16x8 fah[4], fal[4], fbh[4], fbl[4];
#pragma unroll
    for (int mi = 0; mi < 4; mi++) {
      fah[mi] = *(const bf16x8*)&sAh[wm * 64 + mi * 16 + fr][kg * 8];
      fal[mi] = *(const bf16x8*)&sAl[wm * 64 + mi * 16 + fr][kg * 8];
    }
#pragma unroll
    for (int ni = 0; ni < 4; ni++) {
      fbh[ni] = *(const bf16x8*)&sBh[wn * 64 + ni * 16 + fr][kg * 8];
      fbl[ni] = *(const bf16x8*)&sBl[wn * 64 + ni * 16 + fr][kg * 8];
    }
#pragma unroll
    for (int mi = 0; mi < 4; mi++)
#pragma unroll
      for (int ni = 0; ni < 4; ni++) {
        acc[mi][ni] = __builtin_amdgcn_mfma_f32_16x16x32_bf16(fah[mi], fbh[ni], acc[mi][ni], 0, 0, 0);
        acc[mi][ni] = __builtin_amdgcn_mfma_f32_16x16x32_bf16(fah[mi], fbl[ni], acc[mi][ni], 0, 0, 0);
        acc[mi][ni] = __builtin_amdgcn_mfma_f32_16x16x32_bf16(fal[mi], fbh[ni], acc[mi][ni], 0, 0, 0);
      }
  }
#pragma unroll
  for (int mi = 0; mi < 4; mi++) {
    int rbase = bm + wm * 64 + mi * 16 + kg * 4;
#pragma unroll
    for (int ni = 0; ni < 4; ni++) {
      int col = bn + wn * 64 + ni * 16 + fr;
#pragma unroll
      for (int r = 0; r < 4; r++) {
        int row = rbase + r;
        if (row < M) C[(size_t)row * N + col] = acc[mi][ni][r];
      }
    }
  }
}

// ---------------- fp32 tiled GEMM (kept for the small Wg GEMM) ----------------
template <int BN, int TN>
__global__ __launch_bounds__(256) void gemm_f32(const float* __restrict__ A,
                                                const float* __restrict__ B,
                                                float* __restrict__ C, int M, int K, int Nld) {
  constexpr int BM = 128, BK = 16, TM = 8;
  __shared__ float As[BK][BM + 4];
  __shared__ float Bs[BK][BN + 4];
  const int tid = (int)threadIdx.x;
  const int bm = blockIdx.x * BM;
  const int bn = blockIdx.y * BN;
  const int arow = tid >> 1;
  const int acol = (tid & 1) * 8;
  const int brow = tid >> 4;
  const int bcol = (tid & 15) * (BN / 16);
  const int tmr = (tid >> 4) * TM;
  const int tnc = (tid & 15) * TN;

  float acc[TM][TN];
#pragma unroll
  for (int i = 0; i < TM; i++)
#pragma unroll
    for (int j = 0; j < TN; j++) acc[i][j] = 0.f;

  const bool avalid = (bm + arow) < M;
  const float* Arow = A + (size_t)(bm + arow) * K + acol;

  for (int k0 = 0; k0 < K; k0 += BK) {
    float4 a0, a1;
    if (avalid) {
      a0 = *(const float4*)(Arow + k0);
      a1 = *(const float4*)(Arow + k0 + 4);
    } else {
      a0 = make_float4(0.f, 0.f, 0.f, 0.f);
      a1 = a0;
    }
    float4 bv[BN / 64];
#pragma unroll
    for (int l = 0; l < BN / 64; l++)
      bv[l] = *(const float4*)(B + (size_t)(k0 + brow) * Nld + bn + bcol + 4 * l);
    __syncthreads();
    As[acol + 0][arow] = a0.x; As[acol + 1][arow] = a0.y;
    As[acol + 2][arow] = a0.z; As[acol + 3][arow] = a0.w;
    As[acol + 4][arow] = a1.x; As[acol + 5][arow] = a1.y;
    As[acol + 6][arow] = a1.z; As[acol + 7][arow] = a1.w;
#pragma unroll
    for (int l = 0; l < BN / 64; l++) *(float4*)&Bs[brow][bcol + 4 * l] = bv[l];
    __syncthreads();
#pragma unroll
    for (int k = 0; k < BK; k++) {
      float a[TM], b[TN];
#pragma unroll
      for (int i = 0; i < TM; i += 4) {
        float4 t = *(const float4*)&As[k][tmr + i];
        a[i] = t.x; a[i + 1] = t.y; a[i + 2] = t.z; a[i + 3] = t.w;
      }
#pragma unroll
      for (int j = 0; j < TN; j += 4) {
        float4 t = *(const float4*)&Bs[k][tnc + j];
        b[j] = t.x; b[j + 1] = t.y; b[j + 2] = t.z; b[j + 3] = t.w;
      }
#pragma unroll
      for (int i = 0; i < TM; i++)
#pragma unroll
        for (int j = 0; j < TN; j++) acc[i][j] += a[i] * b[j];
    }
  }
#pragma unroll
  for (int i = 0; i < TM; i++) {
    int row = bm + tmr + i;
    if (row < M) {
#pragma unroll
      for (int j = 0; j < TN; j += 4) {
        float4 t = make_float4(acc[i][j], acc[i][j + 1], acc[i][j + 2], acc[i][j + 3]);
        *(float4*)(C + (size_t)row * Nld + bn + tnc + j) = t;
      }
    }
  }
}

// as_h[n,h] = sum_c hfeat[n,h,c]*aS[h,c]; same for ad_h. One wave per node.
__global__ void attn_proj(const float* __restrict__ hfeat, const float* __restrict__ aS,
                          const float* __restrict__ aD, float* __restrict__ as_h,
                          float* __restrict__ ad_h) {
  int wid = (blockIdx.x * 256 + (int)threadIdx.x) >> 6;
  int lane = (int)threadIdx.x & 63;
  if (wid >= NN) return;
  const float* hp = hfeat + (size_t)wid * HD;
#pragma unroll
  for (int h = 0; h < HEADS; h++) {
    float hv = hp[h * HIDN + lane];
    float sv = hv * aS[h * HIDN + lane];
    float dv = hv * aD[h * HIDN + lane];
#pragma unroll
    for (int o = 32; o; o >>= 1) {
      sv += __shfl_xor(sv, o);
      dv += __shfl_xor(dv, o);
    }
    if (lane == 0) {
      as_h[wid * HEADS + h] = sv;
      ad_h[wid * HEADS + h] = dv;
    }
  }
}

// One wave per (node, head). Scores computed in-register (dst == wave's node);
// softmax lane-parallel; feature loop gets (wgt, src) via register shuffles.
__global__ void gat_agg(const float* __restrict__ hfeat, const float* __restrict__ as_h,
                        const float* __restrict__ ad_h, const int* __restrict__ src_csr,
                        const int* __restrict__ off, const float* __restrict__ bias,
                        float* __restrict__ outb) {
  int wid = (blockIdx.x * 256 + (int)threadIdx.x) >> 6;
  int lane = (int)threadIdx.x & 63;
  if (wid >= NN * HEADS) return;
  int n = wid >> 3, h = wid & 7;
  int s0 = off[n], s1 = off[n + 1];
  int deg = s1 - s0;
  float adn = ad_h[n * HEADS + h];

  // pass A: lane-parallel leaky-relu scores + wave max
  float m = -1e30f;
  for (int base = 0; base < deg; base += 64) {
    int i = base + lane;
    float ev = -1e30f;
    if (i < deg) {
      ev = as_h[src_csr[s0 + i] * HEADS + h] + adn;
      ev = (ev > 0.f) ? ev : 0.2f * ev;
    }
    m = fmaxf(m, ev);
  }
#pragma unroll
  for (int o = 32; o; o >>= 1) m = fmaxf(m, __shfl_xor(m, o));

  // pass B: weights + gather-accumulate
  float ssum = 0.f, acc = 0.f;
  for (int base = 0; base < deg; base += 64) {
    int i = base + lane;
    float wl = 0.f;
    int msrc = 0;
    if (i < deg) {
      msrc = src_csr[s0 + i];
      float ev = as_h[msrc * HEADS + h] + adn;
      ev = (ev > 0.f) ? ev : 0.2f * ev;
      wl = expf(ev - m);
    }
    ssum += wl;
    int cnt = min(64, deg - base);
    for (int p = 0; p < cnt; ++p) {
      float wgt = __shfl(wl, p);
      int src = __shfl(msrc, p);
      acc += wgt * hfeat[(size_t)src * HD + h * HIDN + lane];
    }
  }
#pragma unroll
  for (int o = 32; o; o >>= 1) ssum += __shfl_xor(ssum, o);

  acc *= 1.f / (ssum + 1e-16f);
  if (bias) acc += bias[h * HIDN + lane];
  outb[(size_t)n * HD + h * HIDN + lane] = acc;
}

// One wave per node; same prefetch+shuffle structure.
__global__ void gcn_agg(const float* __restrict__ h, const float* __restrict__ dinv,
                        const int* __restrict__ off, const int* __restrict__ src_csr,
                        const float* __restrict__ bg, const int* __restrict__ batch,
                        float* __restrict__ z) {
  int wid = (blockIdx.x * 256 + (int)threadIdx.x) >> 6;
  int lane = (int)threadIdx.x & 63;
  if (wid >= NN) return;
  int n = wid;
  int s0 = off[n], s1 = off[n + 1];
  int deg = s1 - s0;
  float acc = 0.f;
  for (int base = 0; base < deg; base += 64) {
    int i = base + lane;
    int msrc = (i < deg) ? src_csr[s0 + i] : 0;
    float mdv = (i < deg) ? dinv[msrc] : 0.f;
    int cnt = min(64, deg - base);
    for (int p = 0; p < cnt; ++p) {
      float dv = __shfl(mdv, p);
      int src = __shfl(msrc, p);
      acc += dv * h[(size_t)src * HIDN + lane];
    }
  }
  float y = fmaxf(acc * dinv[n] + bg[lane], 0.f);
  atomicMaxNonneg(&z[batch[n] * 128 + 64 + lane], y);
}

// Block-level merge of per-wave (graph, sum, sumsq) then atomics.
static __device__ __forceinline__ void block_stats_accum(float v, float v2, int g, int lane,
                                                         float* __restrict__ gsum,
                                                         float* __restrict__ gsumsq) {
#pragma unroll
  for (int o = 32; o; o >>= 1) {
    v += __shfl_xor(v, o);
    v2 += __shfl_xor(v2, o);
  }
  __shared__ float s_v[4], s_v2[4];
  __shared__ int s_g[4];
  int wavei = (int)threadIdx.x >> 6;
  if (lane == 0) {
    s_v[wavei] = v;
    s_v2[wavei] = v2;
    s_g[wavei] = g;
  }
  __syncthreads();
  if (threadIdx.x == 0) {
#pragma unroll
    for (int a = 0; a < 4; a++) {
      int ga = s_g[a];
      if (ga < 0) continue;
      float V = s_v[a], V2 = s_v2[a];
#pragma unroll
      for (int b = a + 1; b < 4; b++)
        if (s_g[b] == ga) {
          V += s_v[b];
          V2 += s_v2[b];
          s_g[b] = -1;
        }
      atomicAdd(&gsum[ga], V);
      atomicAdd(&gsumsq[ga], V2);
    }
  }
}

template <int F>
__global__ void ln_stats(const float* __restrict__ in, const int* __restrict__ batch,
                         float* __restrict__ gsum, float* __restrict__ gsumsq) {
  int wid = (blockIdx.x * 256 + (int)threadIdx.x) >> 6;
  int lane = (int)threadIdx.x & 63;
  float v = 0.f, v2 = 0.f;
  const float* row = in + (size_t)wid * F;
#pragma unroll
  for (int f = lane; f < F; f += 64) {
    float x = row[f];
    v += x;
    v2 += x * x;
  }
  block_stats_accum(v, v2, batch[wid], lane, gsum, gsumsq);
}

__global__ void head_mean_stats(const float* __restrict__ agg, const float* __restrict__ b3,
                                const int* __restrict__ batch, float* __restrict__ h3,
                                float* __restrict__ gsum, float* __restrict__ gsumsq) {
  int wid = (blockIdx.x * 256 + (int)threadIdx.x) >> 6;
  int lane = (int)threadIdx.x & 63;
  float s = 0.f;
#pragma unroll
  for (int h = 0; h < HEADS; h++) s += agg[(size_t)wid * HD + h * HIDN + lane];
  s = s * 0.125f + b3[lane];
  h3[wid * HIDN + lane] = s;
  block_stats_accum(s, s * s, batch[wid], lane, gsum, gsumsq);
}

// LN+ReLU, writing bf16 hi/lo split directly (feeds next layer's MFMA GEMM only)
template <int F>
__global__ void ln_apply_split(const float* __restrict__ buf, const int* __restrict__ batch,
                               const float* __restrict__ gsum, const float* __restrict__ gsumsq,
                               const int* __restrict__ gcnt, const float* __restrict__ w,
                               const float* __restrict__ b, u16* __restrict__ hi,
                               u16* __restrict__ lo) {
  int i = blockIdx.x * 256 + (int)threadIdx.x;
  if (i >= NN * F) return;
  int n = i / F, f = i % F;
  int g = batch[n];
  float cnt = (float)gcnt[g] * (float)F;
  float mean = gsum[g] / cnt;
  float var = gsumsq[g] / cnt - mean * mean;
  float y = (buf[i] - mean) * rsqrtf(var + 1e-5f) * w[f] + b[f];
  y = fmaxf(y, 0.f);
  u16 hh = f2bf(y);
  hi[i] = hh;
  lo[i] = f2bf(y - bf2f(hh));
}

template <int F, bool ZMAX>
__global__ void ln_apply(float* __restrict__ buf, const int* __restrict__ batch,
                         const float* __restrict__ gsum, const float* __restrict__ gsumsq,
                         const int* __restrict__ gcnt, const float* __restrict__ w,
                         const float* __restrict__ b, float* __restrict__ z) {
  int i = blockIdx.x * 256 + (int)threadIdx.x;
  if (i >= NN * F) return;
  int n = i / F, f = i % F;
  int g = batch[n];
  float cnt = (float)gcnt[g] * (float)F;
  float mean = gsum[g] / cnt;
  float var = gsumsq[g] / cnt - mean * mean;
  float y = (buf[i] - mean) * rsqrtf(var + 1e-5f) * w[f] + b[f];
  y = fmaxf(y, 0.f);
  buf[i] = y;
  if (ZMAX) atomicMaxNonneg(&z[g * 128 + f], y);
}

__global__ __launch_bounds__(64) void mlp_head(const float* __restrict__ z,
                                               const float* __restrict__ Wl0, const float* __restrict__ bl0,
                                               const float* __restrict__ Wl1, const float* __restrict__ bl1,
                                               const float* __restrict__ Wl2, const float* __restrict__ bl2,
                                               const float* __restrict__ Wo, const float* __restrict__ bo,
                                               float* __restrict__ out) {
  __shared__ float zs[128], t0[64], t1[64], t2[64];
  int g = blockIdx.x, t = (int)threadIdx.x;
  zs[t] = z[g * 128 + t];
  zs[64 + t] = z[g * 128 + 64 + t];
  __syncthreads();
  float a = bl0[t];
  for (int k = 0; k < 128; k++) a += zs[k] * Wl0[k * 64 + t];
  t0[t] = fmaxf(a, 0.f);
  __syncthreads();
  a = bl1[t];
  for (int k = 0; k < 64; k++) a += t0[k] * Wl1[k * 64 + t];
  t1[t] = fmaxf(a, 0.f);
  __syncthreads();
  a = bl2[t];
  for (int k = 0; k < 64; k++) a += t1[k] * Wl2[k * 64 + t];
  t2[t] = fmaxf(a, 0.f);
  __syncthreads();
  if (t < 2) {
    float o = bo[t];
    for (int k = 0; k < 64; k++) o += t2[k] * Wo[k * 2 + t];
    out[g * 2 + t] = o;
  }
  out[128 + g * 128 + t] = zs[t];
  out[128 + g * 128 + 64 + t] = zs[64 + t];
}

extern "C" void kernel_launch(void* const* d_in, const int* in_sizes, int n_in,
                              void* d_out, int out_size, void* d_ws, size_t ws_size,
                              hipStream_t stream) {
  const float* x = (const float*)d_in[0];
  const int* ei = (const int*)d_in[1];
  const int* batch = (const int*)d_in[2];
  const float* W1 = (const float*)d_in[3];
  const float* aS1 = (const float*)d_in[4];
  const float* aD1 = (const float*)d_in[5];
  const float* b1 = (const float*)d_in[6];
  const float* W2 = (const float*)d_in[7];
  const float* aS2 = (const float*)d_in[8];
  const float* aD2 = (const float*)d_in[9];
  const float* b2 = (const float*)d_in[10];
  const float* W3 = (const float*)d_in[11];
  const float* aS3 = (const float*)d_in[12];
  const float* aD3 = (const float*)d_in[13];
  const float* b3 = (const float*)d_in[14];
  const float* Wg = (const float*)d_in[15];
  const float* bg = (const float*)d_in[16];
  const float* nw1 = (const float*)d_in[17];
  const float* nb1 = (const float*)d_in[18];
  const float* nw2 = (const float*)d_in[19];
  const float* nb2 = (const float*)d_in[20];
  const float* nw3 = (const float*)d_in[21];
  const float* nb3 = (const float*)d_in[22];
  const float* Wl0 = (const float*)d_in[23];
  const float* bl0 = (const float*)d_in[24];
  const float* Wl1 = (const float*)d_in[25];
  const float* bl1 = (const float*)d_in[26];
  const float* Wl2 = (const float*)d_in[27];
  const float* bl2 = (const float*)d_in[28];
  const float* Wo = (const float*)d_in[29];
  const float* bo = (const float*)d_in[30];
  float* out = (float*)d_out;

  char* wp = (char*)d_ws;
  auto alloc = [&](size_t bytes) -> void* {
    void* p = (void*)wp;
    wp += ((bytes + 255) & ~(size_t)255);
    return p;
  };
  float* bufH = (float*)alloc((size_t)NN * HD * 4);
  float* bufA = (float*)alloc((size_t)NN * HD * 4);
  float* f64b = (float*)alloc((size_t)NN * HIDN * 4);
  float* as_h = (float*)alloc((size_t)NN * HEADS * 4);
  float* ad_h = (float*)alloc((size_t)NN * HEADS * 4);
  const int ZWORDS = NN + NG + 6 * NG + NG * 128;
  int* initblk = (int*)alloc((size_t)ZWORDS * 4);
  int* deg = initblk;
  int* gcnt = deg + NN;
  float* stats = (float*)(gcnt + NG);
  float* zbuf = stats + 6 * NG;
  int* off = (int*)alloc((size_t)(NN + 1) * 4);
  int* cur = (int*)alloc((size_t)NN * 4);
  int* src_csr = (int*)alloc((size_t)NE2 * 4);
  float* dinv = (float*)alloc((size_t)NN * 4);
  u16* xhi = (u16*)alloc((size_t)NN * FEATN * 2);
  u16* xlo = (u16*)alloc((size_t)NN * FEATN * 2);
  u16* ahi = (u16*)alloc((size_t)NN * HD * 2);
  u16* alo = (u16*)alloc((size_t)NN * HD * 2);
  u16* w1h = (u16*)alloc((size_t)FEATN * HD * 2);
  u16* w1l = (u16*)alloc((size_t)FEATN * HD * 2);
  u16* w2h = (u16*)alloc((size_t)HD * HD * 2);
  u16* w2l = (u16*)alloc((size_t)HD * HD * 2);
  u16* w3h = (u16*)alloc((size_t)HD * HD * 2);
  u16* w3l = (u16*)alloc((size_t)HD * HD * 2);

  dim3 b256(256);
  zero_u32<<<(ZWORDS + 255) / 256, b256, 0, stream>>>((unsigned int*)initblk, ZWORDS);
  build_counts<<<(NE2 + 255) / 256, b256, 0, stream>>>(ei, batch, deg, gcnt);
  scan_exclusive<<<1, 1024, 0, stream>>>(deg, off, cur, NN);
  scatter_csr<<<(NE2 + 255) / 256, b256, 0, stream>>>(ei, cur, src_csr);
  compute_dinv<<<(NN + 255) / 256, b256, 0, stream>>>(deg, dinv);
  const int WTOT = FEATN * HD + 2 * HD * HD;
  split_weightsT<<<(WTOT + 255) / 256, b256, 0, stream>>>(W1, W2, W3, w1h, w1l, w2h, w2l, w3h, w3l);
  split_mat<<<(NN * FEATN / 4 + 255) / 256, b256, 0, stream>>>(x, xhi, xlo, NN * FEATN / 4);

  const int wgrid = (NN * 64) / 256;               // one wave per node (exact)
  const int hgrid = (NN * HEADS * 64 + 255) / 256; // one wave per (node,head)
  dim3 gmm((NN + 127) / 128, HD / 128);

  // GCN branch
  {
    dim3 g((NN + 127) / 128, 1);
    gemm_f32<64, 4><<<g, b256, 0, stream>>>(x, Wg, f64b, NN, FEATN, HIDN);
    gcn_agg<<<wgrid, b256, 0, stream>>>(f64b, dinv, off, src_csr, bg, batch, zbuf);
  }
  // GAT layer 1
  {
    gemm_bf3<FEATN, HD><<<gmm, b256, 0, stream>>>(xhi, xlo, w1h, w1l, bufH, NN);
    attn_proj<<<wgrid, b256, 0, stream>>>(bufH, aS1, aD1, as_h, ad_h);
    gat_agg<<<hgrid, b256, 0, stream>>>(bufH, as_h, ad_h, src_csr, off, b1, bufA);
    ln_stats<HD><<<wgrid, b256, 0, stream>>>(bufA, batch, stats + 0, stats + NG);
    ln_apply_split<HD><<<(NN * HD + 255) / 256, b256, 0, stream>>>(
        bufA, batch, stats + 0, stats + NG, gcnt, nw1, nb1, ahi, alo);
  }
  // GAT layer 2
  {
    gemm_bf3<HD, HD><<<gmm, b256, 0, stream>>>(ahi, alo, w2h, w2l, bufH, NN);
    attn_proj<<<wgrid, b256, 0, stream>>>(bufH, aS2, aD2, as_h, ad_h);
    gat_agg<<<hgrid, b256, 0, stream>>>(bufH, as_h, ad_h, src_csr, off, b2, bufA);
    ln_stats<HD><<<wgrid, b256, 0, stream>>>(bufA, batch, stats + 2 * NG, stats + 3 * NG);
    ln_apply_split<HD><<<(NN * HD + 255) / 256, b256, 0, stream>>>(
        bufA, batch, stats + 2 * NG, stats + 3 * NG, gcnt, nw2, nb2, ahi, alo);
  }
  // GAT layer 3
  {
    gemm_bf3<HD, HD><<<gmm, b256, 0, stream>>>(ahi, alo, w3h, w3l, bufH, NN);
    attn_proj<<<wgrid, b256, 0, stream>>>(bufH, aS3, aD3, as_h, ad_h);
    gat_agg<<<hgrid, b256, 0, stream>>>(bufH, as_h, ad_h, src_csr, off, nullptr, bufA);
    head_mean_stats<<<wgrid, b256, 0, stream>>>(bufA, b3, batch, f64b,
                                                stats + 4 * NG, stats + 5 * NG);
    ln_apply<HIDN, true><<<(NN * HIDN + 255) / 256, b256, 0, stream>>>(
        f64b, batch, stats + 4 * NG, stats + 5 * NG, gcnt, nw3, nb3, zbuf);
  }
  mlp_head<<<NG, 64, 0, stream>>>(zbuf, Wl0, bl0, Wl1, bl1, Wl2, bl2, Wo, bo, out);
}

// Round 8
// 754.082 us; speedup vs baseline: 2.2454x; 1.3731x over previous
//
#include <hip/hip_runtime.h>
#include <math.h>

#define NG    64
#define NN    20000
#define NE    160000
#define NE2   180000
#define FEATN 128
#define HIDN  64
#define HEADS 8
#define HD    512  // HEADS*HIDN

typedef unsigned short u16;
typedef __bf16 bf16x8 __attribute__((ext_vector_type(8)));
typedef u16 us8 __attribute__((ext_vector_type(8)));
typedef float f32x4 __attribute__((ext_vector_type(4)));

static __device__ __forceinline__ void atomicMaxNonneg(float* addr, float v) {
  atomicMax((unsigned int*)addr, __float_as_uint(v));
}

static __device__ __forceinline__ u16 f2bf(float f) {
  unsigned int u = __float_as_uint(f);
  u += 0x7fffu + ((u >> 16) & 1u);  // RNE
  return (u16)(u >> 16);
}
static __device__ __forceinline__ float bf2f(u16 s) {
  return __uint_as_float(((unsigned int)s) << 16);
}

__global__ void zero_u32(unsigned int* __restrict__ p, int n) {
  int i = blockIdx.x * 256 + threadIdx.x;
  if (i < n) p[i] = 0u;
}

// deg histogram over dst (with self loops) + batch histogram, one pass
__global__ void build_counts(const int* __restrict__ ei, const int* __restrict__ batch,
                             int* __restrict__ deg, int* __restrict__ gcnt) {
  int i = blockIdx.x * 256 + threadIdx.x;
  if (i < NE2) {
    int d = (i < NE) ? ei[NE + i] : (i - NE);
    atomicAdd(&deg[d], 1);
  }
  if (i < NN) atomicAdd(&gcnt[batch[i]], 1);
}

__global__ void compute_dinv(const int* __restrict__ deg, float* __restrict__ dinv) {
  int i = blockIdx.x * 256 + threadIdx.x;
  if (i < NN) dinv[i] = rsqrtf((float)deg[i]);
}

// ---- hierarchical exclusive scan (3 phases, replaces serial 1-block scan) ----
__global__ void scan_phase1(const int* __restrict__ deg, int* __restrict__ off,
                            int* __restrict__ bsum, int n) {
  __shared__ int tmp[256];
  int tid = (int)threadIdx.x;
  int i = blockIdx.x * 256 + tid;
  int v = (i < n) ? deg[i] : 0;
  tmp[tid] = v;
  __syncthreads();
  for (int o = 1; o < 256; o <<= 1) {
    int t = (tid >= o) ? tmp[tid - o] : 0;
    __syncthreads();
    tmp[tid] += t;
    __syncthreads();
  }
  if (i < n) off[i] = tmp[tid] - v;  // block-local exclusive
  if (tid == 255) bsum[blockIdx.x] = tmp[255];
}

__global__ __launch_bounds__(256) void scan_phase2(const int* __restrict__ bsum,
                                                   int* __restrict__ boff, int nb,
                                                   int* __restrict__ off_last) {
  __shared__ int tmp[256];
  int tid = (int)threadIdx.x;
  int v = (tid < nb) ? bsum[tid] : 0;
  tmp[tid] = v;
  __syncthreads();
  for (int o = 1; o < 256; o <<= 1) {
    int t = (tid >= o) ? tmp[tid - o] : 0;
    __syncthreads();
    tmp[tid] += t;
    __syncthreads();
  }
  if (tid < nb) boff[tid] = tmp[tid] - v;
  if (tid == 255) *off_last = tmp[255];  // total == NE2
}

__global__ void scan_phase3(int* __restrict__ off, const int* __restrict__ boff,
                            int* __restrict__ cur, int n) {
  int i = blockIdx.x * 256 + threadIdx.x;
  if (i < n) {
    int e = off[i] + boff[blockIdx.x];
    off[i] = e;
    cur[i] = e;
  }
}

// CSR by dst, materializing src ids per slot
__global__ void scatter_csr(const int* __restrict__ ei, int* __restrict__ cur,
                            int* __restrict__ src_csr) {
  int e = blockIdx.x * 256 + threadIdx.x;
  if (e >= NE2) return;
  int s, d;
  if (e < NE) {
    s = ei[e];
    d = ei[NE + e];
  } else {
    s = e - NE;
    d = e - NE;
  }
  int p = atomicAdd(&cur[d], 1);
  src_csr[p] = s;
}

// fp32 [M][K] -> bf16 hi/lo [M][K] (flat, 4 elems/thread)
__global__ void split_mat(const float* __restrict__ X, u16* __restrict__ hi,
                          u16* __restrict__ lo, int n4) {
  int i = blockIdx.x * 256 + threadIdx.x;
  if (i >= n4) return;
  float4 v = ((const float4*)X)[i];
  ushort4 h, l;
  h.x = f2bf(v.x); l.x = f2bf(v.x - bf2f(h.x));
  h.y = f2bf(v.y); l.y = f2bf(v.y - bf2f(h.y));
  h.z = f2bf(v.z); l.z = f2bf(v.z - bf2f(h.z));
  h.w = f2bf(v.w); l.w = f2bf(v.w - bf2f(h.w));
  ((ushort4*)hi)[i] = h;
  ((ushort4*)lo)[i] = l;
}

// W[K][N] row-major -> WT hi/lo [N][K] bf16, all three GAT weights in one launch
__global__ void split_weightsT(const float* __restrict__ W1, const float* __restrict__ W2,
                               const float* __restrict__ W3,
                               u16* __restrict__ w1h, u16* __restrict__ w1l,
                               u16* __restrict__ w2h, u16* __restrict__ w2l,
                               u16* __restrict__ w3h, u16* __restrict__ w3l) {
  const int S1 = FEATN * HD;
  const int S2 = S1 + HD * HD;
  const int S3 = S2 + HD * HD;
  int i = blockIdx.x * 256 + threadIdx.x;
  if (i >= S3) return;
  if (i < S1) {
    int k = i / HD, n = i % HD;
    float v = W1[i];
    u16 h = f2bf(v), l = f2bf(v - bf2f(h));
    w1h[n * FEATN + k] = h;
    w1l[n * FEATN + k] = l;
  } else if (i < S2) {
    int j = i - S1;
    int k = j / HD, n = j % HD;
    float v = W2[j];
    u16 h = f2bf(v), l = f2bf(v - bf2f(h));
    w2h[n * HD + k] = h;
    w2l[n * HD + k] = l;
  } else {
    int j = i - S2;
    int k = j / HD, n = j % HD;
    float v = W3[j];
    u16 h = f2bf(v), l = f2bf(v - bf2f(h));
    w3h[n * HD + k] = h;
    w3l[n * HD + k] = l;
  }
}

// ---------- bf16-split MFMA GEMM: C[M,N] = A[M,K] @ B[K,N] ----------
template <int K, int N>
__global__ __launch_bounds__(256) void gemm_bf3(const u16* __restrict__ Ahg,
                                                const u16* __restrict__ Alg,
                                                const u16* __restrict__ Bhg,
                                                const u16* __restrict__ Blg,
                                                float* __restrict__ C, int M) {
  constexpr int BKP = 40;
  __shared__ u16 sAh[128][BKP], sAl[128][BKP], sBh[128][BKP], sBl[128][BKP];
  const int t = (int)threadIdx.x;
  const int bm = blockIdx.x * 128, bn = blockIdx.y * 128;
  const int lane = t & 63, w = t >> 6;
  const int wm = w >> 1, wn = w & 1;
  const int fr = lane & 15, kg = lane >> 4;

  f32x4 zero4 = {0.f, 0.f, 0.f, 0.f};
  f32x4 acc[4][4];
#pragma unroll
  for (int i = 0; i < 4; i++)
#pragma unroll
    for (int j = 0; j < 4; j++) acc[i][j] = zero4;

  for (int k0 = 0; k0 < K; k0 += 32) {
    __syncthreads();
#pragma unroll
    for (int i = 0; i < 2; i++) {
      int idx = t * 2 + i;
      int r = idx >> 2, c = (idx & 3) * 8;
      int arow = bm + r;
      us8 vh, vl;
      if (arow < M) {
        vh = *(const us8*)(Ahg + (size_t)arow * K + k0 + c);
        vl = *(const us8*)(Alg + (size_t)arow * K + k0 + c);
      } else {
        vh = (us8)(u16)0;
        vl = (us8)(u16)0;
      }
      *(us8*)&sAh[r][c] = vh;
      *(us8*)&sAl[r][c] = vl;
      int brow = bn + r;
      *(us8*)&sBh[r][c] = *(const us8*)(Bhg + (size_t)brow * K + k0 + c);
      *(us8*)&sBl[r][c] = *(const us8*)(Blg + (size_t)brow * K + k0 + c);
    }
    __syncthreads();
    bf16x8 fah[4], fal[4], fbh[4], fbl[4];
#pragma unroll
    for (int mi = 0; mi < 4; mi++) {
      fah[mi] = *(const bf16x8*)&sAh[wm * 64 + mi * 16 + fr][kg * 8];
      fal[mi] = *(const bf16x8*)&sAl[wm * 64 + mi * 16 + fr][kg * 8];
    }
#pragma unroll
    for (int ni = 0; ni < 4; ni++) {
      fbh[ni] = *(const bf16x8*)&sBh[wn * 64 + ni * 16 + fr][kg * 8];
      fbl[ni] = *(const bf16x8*)&sBl[wn * 64 + ni * 16 + fr][kg * 8];
    }
#pragma unroll
    for (int mi = 0; mi < 4; mi++)
#pragma unroll
      for (int ni = 0; ni < 4; ni++) {
        acc[mi][ni] = __builtin_amdgcn_mfma_f32_16x16x32_bf16(fah[mi], fbh[ni], acc[mi][ni], 0, 0, 0);
        acc[mi][ni] = __builtin_amdgcn_mfma_f32_16x16x32_bf16(fah[mi], fbl[ni], acc[mi][ni], 0, 0, 0);
        acc[mi][ni] = __builtin_amdgcn_mfma_f32_16x16x32_bf16(fal[mi], fbh[ni], acc[mi][ni], 0, 0, 0);
      }
  }
#pragma unroll
  for (int mi = 0; mi < 4; mi++) {
    int rbase = bm + wm * 64 + mi * 16 + kg * 4;
#pragma unroll
    for (int ni = 0; ni < 4; ni++) {
      int col = bn + wn * 64 + ni * 16 + fr;
#pragma unroll
      for (int r = 0; r < 4; r++) {
        int row = rbase + r;
        if (row < M) C[(size_t)row * N + col] = acc[mi][ni][r];
      }
    }
  }
}

// ---------------- fp32 tiled GEMM (kept for the small Wg GEMM) ----------------
template <int BN, int TN>
__global__ __launch_bounds__(256) void gemm_f32(const float* __restrict__ A,
                                                const float* __restrict__ B,
                                                float* __restrict__ C, int M, int K, int Nld) {
  constexpr int BM = 128, BK = 16, TM = 8;
  __shared__ float As[BK][BM + 4];
  __shared__ float Bs[BK][BN + 4];
  const int tid = (int)threadIdx.x;
  const int bm = blockIdx.x * BM;
  const int bn = blockIdx.y * BN;
  const int arow = tid >> 1;
  const int acol = (tid & 1) * 8;
  const int brow = tid >> 4;
  const int bcol = (tid & 15) * (BN / 16);
  const int tmr = (tid >> 4) * TM;
  const int tnc = (tid & 15) * TN;

  float acc[TM][TN];
#pragma unroll
  for (int i = 0; i < TM; i++)
#pragma unroll
    for (int j = 0; j < TN; j++) acc[i][j] = 0.f;

  const bool avalid = (bm + arow) < M;
  const float* Arow = A + (size_t)(bm + arow) * K + acol;

  for (int k0 = 0; k0 < K; k0 += BK) {
    float4 a0, a1;
    if (avalid) {
      a0 = *(const float4*)(Arow + k0);
      a1 = *(const float4*)(Arow + k0 + 4);
    } else {
      a0 = make_float4(0.f, 0.f, 0.f, 0.f);
      a1 = a0;
    }
    float4 bv[BN / 64];
#pragma unroll
    for (int l = 0; l < BN / 64; l++)
      bv[l] = *(const float4*)(B + (size_t)(k0 + brow) * Nld + bn + bcol + 4 * l);
    __syncthreads();
    As[acol + 0][arow] = a0.x; As[acol + 1][arow] = a0.y;
    As[acol + 2][arow] = a0.z; As[acol + 3][arow] = a0.w;
    As[acol + 4][arow] = a1.x; As[acol + 5][arow] = a1.y;
    As[acol + 6][arow] = a1.z; As[acol + 7][arow] = a1.w;
#pragma unroll
    for (int l = 0; l < BN / 64; l++) *(float4*)&Bs[brow][bcol + 4 * l] = bv[l];
    __syncthreads();
#pragma unroll
    for (int k = 0; k < BK; k++) {
      float a[TM], b[TN];
#pragma unroll
      for (int i = 0; i < TM; i += 4) {
        float4 t = *(const float4*)&As[k][tmr + i];
        a[i] = t.x; a[i + 1] = t.y; a[i + 2] = t.z; a[i + 3] = t.w;
      }
#pragma unroll
      for (int j = 0; j < TN; j += 4) {
        float4 t = *(const float4*)&Bs[k][tnc + j];
        b[j] = t.x; b[j + 1] = t.y; b[j + 2] = t.z; b[j + 3] = t.w;
      }
#pragma unroll
      for (int i = 0; i < TM; i++)
#pragma unroll
        for (int j = 0; j < TN; j++) acc[i][j] += a[i] * b[j];
    }
  }
#pragma unroll
  for (int i = 0; i < TM; i++) {
    int row = bm + tmr + i;
    if (row < M) {
#pragma unroll
      for (int j = 0; j < TN; j += 4) {
        float4 t = make_float4(acc[i][j], acc[i][j + 1], acc[i][j + 2], acc[i][j + 3]);
        *(float4*)(C + (size_t)row * Nld + bn + tnc + j) = t;
      }
    }
  }
}

// as_h[n,h] = sum_c hfeat[n,h,c]*aS[h,c]; same for ad_h. One wave per node.
__global__ void attn_proj(const float* __restrict__ hfeat, const float* __restrict__ aS,
                          const float* __restrict__ aD, float* __restrict__ as_h,
                          float* __restrict__ ad_h) {
  int wid = (blockIdx.x * 256 + (int)threadIdx.x) >> 6;
  int lane = (int)threadIdx.x & 63;
  if (wid >= NN) return;
  const float* hp = hfeat + (size_t)wid * HD;
#pragma unroll
  for (int h = 0; h < HEADS; h++) {
    float hv = hp[h * HIDN + lane];
    float sv = hv * aS[h * HIDN + lane];
    float dv = hv * aD[h * HIDN + lane];
#pragma unroll
    for (int o = 32; o; o >>= 1) {
      sv += __shfl_xor(sv, o);
      dv += __shfl_xor(dv, o);
    }
    if (lane == 0) {
      as_h[wid * HEADS + h] = sv;
      ad_h[wid * HEADS + h] = dv;
    }
  }
}

// Block-level merge of per-wave (graph, sum, sumsq) then atomics.
// Requires: every wave in the block active (grids exact multiples of 4 waves).
static __device__ __forceinline__ void block_stats_accum(float v, float v2, int g, int lane,
                                                         float* __restrict__ gsum,
                                                         float* __restrict__ gsumsq) {
#pragma unroll
  for (int o = 32; o; o >>= 1) {
    v += __shfl_xor(v, o);
    v2 += __shfl_xor(v2, o);
  }
  __shared__ float s_v[4], s_v2[4];
  __shared__ int s_g[4];
  int wavei = (int)threadIdx.x >> 6;
  if (lane == 0) {
    s_v[wavei] = v;
    s_v2[wavei] = v2;
    s_g[wavei] = g;
  }
  __syncthreads();
  if (threadIdx.x == 0) {
#pragma unroll
    for (int a = 0; a < 4; a++) {
      int ga = s_g[a];
      if (ga < 0) continue;
      float V = s_v[a], V2 = s_v2[a];
#pragma unroll
      for (int b = a + 1; b < 4; b++)
        if (s_g[b] == ga) {
          V += s_v[b];
          V2 += s_v2[b];
          s_g[b] = -1;
        }
      atomicAdd(&gsum[ga], V);
      atomicAdd(&gsumsq[ga], V2);
    }
  }
}

// One wave per NODE, all 8 heads together. Score role: lane = (edge_slot<<3)|head.
// Feature role: lane j covers row elems [j*8, j*8+8) -> head j>>3.
// MODE 0: out row = alpha-agg + bias, fused LN stats.
// MODE 1 (layer 3): head-mean + b3 -> h3[N,64], fused LN stats.
template <int MODE>
__global__ void gat_agg(const float* __restrict__ hfeat, const float* __restrict__ as_h,
                        const float* __restrict__ ad_h, const int* __restrict__ src_csr,
                        const int* __restrict__ off, const float* __restrict__ bias,
                        float* __restrict__ outp, const int* __restrict__ batch,
                        float* __restrict__ gsum, float* __restrict__ gsumsq) {
  int wid = (blockIdx.x * 256 + (int)threadIdx.x) >> 6;  // node (grid exact)
  int lane = (int)threadIdx.x & 63;
  int n = wid;
  int s0 = off[n], deg = off[n + 1] - s0;
  int hS = lane & 7;   // score-role head
  int eS = lane >> 3;  // score-role edge slot
  int hF = lane >> 3;  // feature-role head
  float adv = ad_h[n * HEADS + hS];

  float4 a0 = make_float4(0.f, 0.f, 0.f, 0.f), a1 = a0;
  float ssum = 0.f;
  for (int base = 0; base < deg; base += 8) {
    int i = base + eS;
    float wl = 0.f;
    int msrc = 0;
    if (i < deg) {
      msrc = src_csr[s0 + i];
      float ev = as_h[msrc * HEADS + hS] + adv;
      ev = (ev > 0.f) ? ev : 0.2f * ev;
      wl = __expf(ev);  // scores O(1); no segmax shift needed (identical ratio)
    }
    ssum += wl;
    int cnt = min(8, deg - base);
    for (int e = 0; e < cnt; ++e) {
      float wgt = __shfl(wl, e * 8 + hF);
      int src = __shfl(msrc, e * 8);
      const float4* rp = (const float4*)(hfeat + (size_t)src * HD + lane * 8);
      float4 v0 = rp[0], v1 = rp[1];
      a0.x += wgt * v0.x; a0.y += wgt * v0.y; a0.z += wgt * v0.z; a0.w += wgt * v0.w;
      a1.x += wgt * v1.x; a1.y += wgt * v1.y; a1.z += wgt * v1.z; a1.w += wgt * v1.w;
    }
  }
  // reduce ssum over edge-slot lanes (same head = same lane&7)
  ssum += __shfl_xor(ssum, 8);
  ssum += __shfl_xor(ssum, 16);
  ssum += __shfl_xor(ssum, 32);
  float inv = 1.f / (__shfl(ssum, hF) + 1e-16f);  // lane hF (<8) holds head hF total
  a0.x *= inv; a0.y *= inv; a0.z *= inv; a0.w *= inv;
  a1.x *= inv; a1.y *= inv; a1.z *= inv; a1.w *= inv;

  if (MODE == 0) {
    const float4* bp = (const float4*)(bias + lane * 8);
    float4 b0 = bp[0], b1v = bp[1];
    a0.x += b0.x; a0.y += b0.y; a0.z += b0.z; a0.w += b0.w;
    a1.x += b1v.x; a1.y += b1v.y; a1.z += b1v.z; a1.w += b1v.w;
    float4* op = (float4*)(outp + (size_t)n * HD + lane * 8);
    op[0] = a0;
    op[1] = a1;
    float v = a0.x + a0.y + a0.z + a0.w + a1.x + a1.y + a1.z + a1.w;
    float v2 = a0.x * a0.x + a0.y * a0.y + a0.z * a0.z + a0.w * a0.w +
               a1.x * a1.x + a1.y * a1.y + a1.z * a1.z + a1.w * a1.w;
    block_stats_accum(v, v2, batch[n], lane, gsum, gsumsq);
  } else {
    // sum over heads: lanes with same (lane&7) hold same cols of different heads
#pragma unroll
    for (int o = 8; o <= 32; o <<= 1) {
      a0.x += __shfl_xor(a0.x, o); a0.y += __shfl_xor(a0.y, o);
      a0.z += __shfl_xor(a0.z, o); a0.w += __shfl_xor(a0.w, o);
      a1.x += __shfl_xor(a1.x, o); a1.y += __shfl_xor(a1.y, o);
      a1.z += __shfl_xor(a1.z, o); a1.w += __shfl_xor(a1.w, o);
    }
    const float4* bp = (const float4*)(bias + (lane & 7) * 8);  // bias = b3[64]
    float4 b0 = bp[0], b1v = bp[1];
    a0.x = a0.x * 0.125f + b0.x; a0.y = a0.y * 0.125f + b0.y;
    a0.z = a0.z * 0.125f + b0.z; a0.w = a0.w * 0.125f + b0.w;
    a1.x = a1.x * 0.125f + b1v.x; a1.y = a1.y * 0.125f + b1v.y;
    a1.z = a1.z * 0.125f + b1v.z; a1.w = a1.w * 0.125f + b1v.w;
    if (lane < 8) {
      float4* op = (float4*)(outp + (size_t)n * HIDN + lane * 8);
      op[0] = a0;
      op[1] = a1;
    }
    float v = 0.f, v2 = 0.f;
    if (lane < 8) {
      v = a0.x + a0.y + a0.z + a0.w + a1.x + a1.y + a1.z + a1.w;
      v2 = a0.x * a0.x + a0.y * a0.y + a0.z * a0.z + a0.w * a0.w +
           a1.x * a1.x + a1.y * a1.y + a1.z * a1.z + a1.w * a1.w;
    }
    block_stats_accum(v, v2, batch[n], lane, gsum, gsumsq);
  }
}

// One wave per node; prefetch+shuffle structure.
__global__ void gcn_agg(const float* __restrict__ h, const float* __restrict__ dinv,
                        const int* __restrict__ off, const int* __restrict__ src_csr,
                        const float* __restrict__ bg, const int* __restrict__ batch,
                        float* __restrict__ z) {
  int wid = (blockIdx.x * 256 + (int)threadIdx.x) >> 6;
  int lane = (int)threadIdx.x & 63;
  if (wid >= NN) return;
  int n = wid;
  int s0 = off[n], s1 = off[n + 1];
  int deg = s1 - s0;
  float acc = 0.f;
  for (int base = 0; base < deg; base += 64) {
    int i = base + lane;
    int msrc = (i < deg) ? src_csr[s0 + i] : 0;
    float mdv = (i < deg) ? dinv[msrc] : 0.f;
    int cnt = min(64, deg - base);
    for (int p = 0; p < cnt; ++p) {
      float dv = __shfl(mdv, p);
      int src = __shfl(msrc, p);
      acc += dv * h[(size_t)src * HIDN + lane];
    }
  }
  float y = fmaxf(acc * dinv[n] + bg[lane], 0.f);
  atomicMaxNonneg(&z[batch[n] * 128 + 64 + lane], y);
}

// LN+ReLU, writing bf16 hi/lo split directly (feeds next layer's MFMA GEMM only)
template <int F>
__global__ void ln_apply_split(const float* __restrict__ buf, const int* __restrict__ batch,
                               const float* __restrict__ gsum, const float* __restrict__ gsumsq,
                               const int* __restrict__ gcnt, const float* __restrict__ w,
                               const float* __restrict__ b, u16* __restrict__ hi,
                               u16* __restrict__ lo) {
  int i = blockIdx.x * 256 + (int)threadIdx.x;
  if (i >= NN * F) return;
  int n = i / F, f = i % F;
  int g = batch[n];
  float cnt = (float)gcnt[g] * (float)F;
  float mean = gsum[g] / cnt;
  float var = gsumsq[g] / cnt - mean * mean;
  float y = (buf[i] - mean) * rsqrtf(var + 1e-5f) * w[f] + b[f];
  y = fmaxf(y, 0.f);
  u16 hh = f2bf(y);
  hi[i] = hh;
  lo[i] = f2bf(y - bf2f(hh));
}

template <int F, bool ZMAX>
__global__ void ln_apply(float* __restrict__ buf, const int* __restrict__ batch,
                         const float* __restrict__ gsum, const float* __restrict__ gsumsq,
                         const int* __restrict__ gcnt, const float* __restrict__ w,
                         const float* __restrict__ b, float* __restrict__ z) {
  int i = blockIdx.x * 256 + (int)threadIdx.x;
  if (i >= NN * F) return;
  int n = i / F, f = i % F;
  int g = batch[n];
  float cnt = (float)gcnt[g] * (float)F;
  float mean = gsum[g] / cnt;
  float var = gsumsq[g] / cnt - mean * mean;
  float y = (buf[i] - mean) * rsqrtf(var + 1e-5f) * w[f] + b[f];
  y = fmaxf(y, 0.f);
  buf[i] = y;
  if (ZMAX) atomicMaxNonneg(&z[g * 128 + f], y);
}

__global__ __launch_bounds__(64) void mlp_head(const float* __restrict__ z,
                                               const float* __restrict__ Wl0, const float* __restrict__ bl0,
                                               const float* __restrict__ Wl1, const float* __restrict__ bl1,
                                               const float* __restrict__ Wl2, const float* __restrict__ bl2,
                                               const float* __restrict__ Wo, const float* __restrict__ bo,
                                               float* __restrict__ out) {
  __shared__ float zs[128], t0[64], t1[64], t2[64];
  int g = blockIdx.x, t = (int)threadIdx.x;
  zs[t] = z[g * 128 + t];
  zs[64 + t] = z[g * 128 + 64 + t];
  __syncthreads();
  float a = bl0[t];
  for (int k = 0; k < 128; k++) a += zs[k] * Wl0[k * 64 + t];
  t0[t] = fmaxf(a, 0.f);
  __syncthreads();
  a = bl1[t];
  for (int k = 0; k < 64; k++) a += t0[k] * Wl1[k * 64 + t];
  t1[t] = fmaxf(a, 0.f);
  __syncthreads();
  a = bl2[t];
  for (int k = 0; k < 64; k++) a += t1[k] * Wl2[k * 64 + t];
  t2[t] = fmaxf(a, 0.f);
  __syncthreads();
  if (t < 2) {
    float o = bo[t];
    for (int k = 0; k < 64; k++) o += t2[k] * Wo[k * 2 + t];
    out[g * 2 + t] = o;
  }
  out[128 + g * 128 + t] = zs[t];
  out[128 + g * 128 + 64 + t] = zs[64 + t];
}

extern "C" void kernel_launch(void* const* d_in, const int* in_sizes, int n_in,
                              void* d_out, int out_size, void* d_ws, size_t ws_size,
                              hipStream_t stream) {
  const float* x = (const float*)d_in[0];
  const int* ei = (const int*)d_in[1];
  const int* batch = (const int*)d_in[2];
  const float* W1 = (const float*)d_in[3];
  const float* aS1 = (const float*)d_in[4];
  const float* aD1 = (const float*)d_in[5];
  const float* b1 = (const float*)d_in[6];
  const float* W2 = (const float*)d_in[7];
  const float* aS2 = (const float*)d_in[8];
  const float* aD2 = (const float*)d_in[9];
  const float* b2 = (const float*)d_in[10];
  const float* W3 = (const float*)d_in[11];
  const float* aS3 = (const float*)d_in[12];
  const float* aD3 = (const float*)d_in[13];
  const float* b3 = (const float*)d_in[14];
  const float* Wg = (const float*)d_in[15];
  const float* bg = (const float*)d_in[16];
  const float* nw1 = (const float*)d_in[17];
  const float* nb1 = (const float*)d_in[18];
  const float* nw2 = (const float*)d_in[19];
  const float* nb2 = (const float*)d_in[20];
  const float* nw3 = (const float*)d_in[21];
  const float* nb3 = (const float*)d_in[22];
  const float* Wl0 = (const float*)d_in[23];
  const float* bl0 = (const float*)d_in[24];
  const float* Wl1 = (const float*)d_in[25];
  const float* bl1 = (const float*)d_in[26];
  const float* Wl2 = (const float*)d_in[27];
  const float* bl2 = (const float*)d_in[28];
  const float* Wo = (const float*)d_in[29];
  const float* bo = (const float*)d_in[30];
  float* out = (float*)d_out;

  char* wp = (char*)d_ws;
  auto alloc = [&](size_t bytes) -> void* {
    void* p = (void*)wp;
    wp += ((bytes + 255) & ~(size_t)255);
    return p;
  };
  float* bufH = (float*)alloc((size_t)NN * HD * 4);
  float* bufA = (float*)alloc((size_t)NN * HD * 4);
  float* f64b = (float*)alloc((size_t)NN * HIDN * 4);
  float* as_h = (float*)alloc((size_t)NN * HEADS * 4);
  float* ad_h = (float*)alloc((size_t)NN * HEADS * 4);
  const int ZWORDS = NN + NG + 6 * NG + NG * 128;
  int* initblk = (int*)alloc((size_t)ZWORDS * 4);
  int* deg = initblk;
  int* gcnt = deg + NN;
  float* stats = (float*)(gcnt + NG);
  float* zbuf = stats + 6 * NG;
  int* off = (int*)alloc((size_t)(NN + 1) * 4);
  int* cur = (int*)alloc((size_t)NN * 4);
  int* src_csr = (int*)alloc((size_t)NE2 * 4);
  float* dinv = (float*)alloc((size_t)NN * 4);
  int* bsum = (int*)alloc((size_t)256 * 4);
  int* boff = (int*)alloc((size_t)256 * 4);
  u16* xhi = (u16*)alloc((size_t)NN * FEATN * 2);
  u16* xlo = (u16*)alloc((size_t)NN * FEATN * 2);
  u16* ahi = (u16*)alloc((size_t)NN * HD * 2);
  u16* alo = (u16*)alloc((size_t)NN * HD * 2);
  u16* w1h = (u16*)alloc((size_t)FEATN * HD * 2);
  u16* w1l = (u16*)alloc((size_t)FEATN * HD * 2);
  u16* w2h = (u16*)alloc((size_t)HD * HD * 2);
  u16* w2l = (u16*)alloc((size_t)HD * HD * 2);
  u16* w3h = (u16*)alloc((size_t)HD * HD * 2);
  u16* w3l = (u16*)alloc((size_t)HD * HD * 2);

  dim3 b256(256);
  const int NB = (NN + 255) / 256;  // 79 scan blocks
  zero_u32<<<(ZWORDS + 255) / 256, b256, 0, stream>>>((unsigned int*)initblk, ZWORDS);
  build_counts<<<(NE2 + 255) / 256, b256, 0, stream>>>(ei, batch, deg, gcnt);
  scan_phase1<<<NB, b256, 0, stream>>>(deg, off, bsum, NN);
  scan_phase2<<<1, b256, 0, stream>>>(bsum, boff, NB, off + NN);
  scan_phase3<<<NB, b256, 0, stream>>>(off, boff, cur, NN);
  scatter_csr<<<(NE2 + 255) / 256, b256, 0, stream>>>(ei, cur, src_csr);
  compute_dinv<<<(NN + 255) / 256, b256, 0, stream>>>(deg, dinv);
  const int WTOT = FEATN * HD + 2 * HD * HD;
  split_weightsT<<<(WTOT + 255) / 256, b256, 0, stream>>>(W1, W2, W3, w1h, w1l, w2h, w2l, w3h, w3l);
  split_mat<<<(NN * FEATN / 4 + 255) / 256, b256, 0, stream>>>(x, xhi, xlo, NN * FEATN / 4);

  const int wgrid = (NN * 64) / 256;  // one wave per node (exact: 5000 blocks)
  dim3 gmm((NN + 127) / 128, HD / 128);

  // GCN branch
  {
    dim3 g((NN + 127) / 128, 1);
    gemm_f32<64, 4><<<g, b256, 0, stream>>>(x, Wg, f64b, NN, FEATN, HIDN);
    gcn_agg<<<wgrid, b256, 0, stream>>>(f64b, dinv, off, src_csr, bg, batch, zbuf);
  }
  // GAT layer 1
  {
    gemm_bf3<FEATN, HD><<<gmm, b256, 0, stream>>>(xhi, xlo, w1h, w1l, bufH, NN);
    attn_proj<<<wgrid, b256, 0, stream>>>(bufH, aS1, aD1, as_h, ad_h);
    gat_agg<0><<<wgrid, b256, 0, stream>>>(bufH, as_h, ad_h, src_csr, off, b1, bufA,
                                           batch, stats + 0, stats + NG);
    ln_apply_split<HD><<<(NN * HD + 255) / 256, b256, 0, stream>>>(
        bufA, batch, stats + 0, stats + NG, gcnt, nw1, nb1, ahi, alo);
  }
  // GAT layer 2
  {
    gemm_bf3<HD, HD><<<gmm, b256, 0, stream>>>(ahi, alo, w2h, w2l, bufH, NN);
    attn_proj<<<wgrid, b256, 0, stream>>>(bufH, aS2, aD2, as_h, ad_h);
    gat_agg<0><<<wgrid, b256, 0, stream>>>(bufH, as_h, ad_h, src_csr, off, b2, bufA,
                                           batch, stats + 2 * NG, stats + 3 * NG);
    ln_apply_split<HD><<<(NN * HD + 255) / 256, b256, 0, stream>>>(
        bufA, batch, stats + 2 * NG, stats + 3 * NG, gcnt, nw2, nb2, ahi, alo);
  }
  // GAT layer 3 (head-mean + b3 + stats fused into gat_agg)
  {
    gemm_bf3<HD, HD><<<gmm, b256, 0, stream>>>(ahi, alo, w3h, w3l, bufH, NN);
    attn_proj<<<wgrid, b256, 0, stream>>>(bufH, aS3, aD3, as_h, ad_h);
    gat_agg<1><<<wgrid, b256, 0, stream>>>(bufH, as_h, ad_h, src_csr, off, b3, f64b,
                                           batch, stats + 4 * NG, stats + 5 * NG);
    ln_apply<HIDN, true><<<(NN * HIDN + 255) / 256, b256, 0, stream>>>(
        f64b, batch, stats + 4 * NG, stats + 5 * NG, gcnt, nw3, nb3, zbuf);
  }
  mlp_head<<<NG, 64, 0, stream>>>(zbuf, Wl0, bl0, Wl1, bl1, Wl2, bl2, Wo, bo, out);
}

// Round 9
// 695.096 us; speedup vs baseline: 2.4360x; 1.0849x over previous
//
#include <hip/hip_runtime.h>
#include <math.h>

#define NG    64
#define NN    20000
#define NE    160000
#define NE2   180000
#define FEATN 128
#define HIDN  64
#define HEADS 8
#define HD    512  // HEADS*HIDN

typedef unsigned short u16;
typedef __bf16 bf16x8 __attribute__((ext_vector_type(8)));
typedef u16 us8 __attribute__((ext_vector_type(8)));
typedef float f32x4 __attribute__((ext_vector_type(4)));

static __device__ __forceinline__ void atomicMaxNonneg(float* addr, float v) {
  atomicMax((unsigned int*)addr, __float_as_uint(v));
}

static __device__ __forceinline__ u16 f2bf(float f) {
  unsigned int u = __float_as_uint(f);
  u += 0x7fffu + ((u >> 16) & 1u);  // RNE
  return (u16)(u >> 16);
}
static __device__ __forceinline__ float bf2f(u16 s) {
  return __uint_as_float(((unsigned int)s) << 16);
}

__global__ void zero_u32(unsigned int* __restrict__ p, int n) {
  int i = blockIdx.x * 256 + threadIdx.x;
  if (i < n) p[i] = 0u;
}

// deg histogram over dst (with self loops) + batch histogram, one pass
__global__ void build_counts(const int* __restrict__ ei, const int* __restrict__ batch,
                             int* __restrict__ deg, int* __restrict__ gcnt) {
  int i = blockIdx.x * 256 + threadIdx.x;
  if (i < NE2) {
    int d = (i < NE) ? ei[NE + i] : (i - NE);
    atomicAdd(&deg[d], 1);
  }
  if (i < NN) atomicAdd(&gcnt[batch[i]], 1);
}

__global__ void compute_dinv(const int* __restrict__ deg, float* __restrict__ dinv) {
  int i = blockIdx.x * 256 + threadIdx.x;
  if (i < NN) dinv[i] = rsqrtf((float)deg[i]);
}

// ---- hierarchical exclusive scan (3 phases) ----
__global__ void scan_phase1(const int* __restrict__ deg, int* __restrict__ off,
                            int* __restrict__ bsum, int n) {
  __shared__ int tmp[256];
  int tid = (int)threadIdx.x;
  int i = blockIdx.x * 256 + tid;
  int v = (i < n) ? deg[i] : 0;
  tmp[tid] = v;
  __syncthreads();
  for (int o = 1; o < 256; o <<= 1) {
    int t = (tid >= o) ? tmp[tid - o] : 0;
    __syncthreads();
    tmp[tid] += t;
    __syncthreads();
  }
  if (i < n) off[i] = tmp[tid] - v;  // block-local exclusive
  if (tid == 255) bsum[blockIdx.x] = tmp[255];
}

__global__ __launch_bounds__(256) void scan_phase2(const int* __restrict__ bsum,
                                                   int* __restrict__ boff, int nb,
                                                   int* __restrict__ off_last) {
  __shared__ int tmp[256];
  int tid = (int)threadIdx.x;
  int v = (tid < nb) ? bsum[tid] : 0;
  tmp[tid] = v;
  __syncthreads();
  for (int o = 1; o < 256; o <<= 1) {
    int t = (tid >= o) ? tmp[tid - o] : 0;
    __syncthreads();
    tmp[tid] += t;
    __syncthreads();
  }
  if (tid < nb) boff[tid] = tmp[tid] - v;
  if (tid == 255) *off_last = tmp[255];  // total == NE2
}

__global__ void scan_phase3(int* __restrict__ off, const int* __restrict__ boff,
                            int* __restrict__ cur, int n) {
  int i = blockIdx.x * 256 + threadIdx.x;
  if (i < n) {
    int e = off[i] + boff[blockIdx.x];
    off[i] = e;
    cur[i] = e;
  }
}

// CSR by dst, materializing src ids per slot
__global__ void scatter_csr(const int* __restrict__ ei, int* __restrict__ cur,
                            int* __restrict__ src_csr) {
  int e = blockIdx.x * 256 + threadIdx.x;
  if (e >= NE2) return;
  int s, d;
  if (e < NE) {
    s = ei[e];
    d = ei[NE + e];
  } else {
    s = e - NE;
    d = e - NE;
  }
  int p = atomicAdd(&cur[d], 1);
  src_csr[p] = s;
}

// fp32 [M][K] -> bf16 hi/lo [M][K] (flat, 4 elems/thread)
__global__ void split_mat(const float* __restrict__ X, u16* __restrict__ hi,
                          u16* __restrict__ lo, int n4) {
  int i = blockIdx.x * 256 + threadIdx.x;
  if (i >= n4) return;
  float4 v = ((const float4*)X)[i];
  ushort4 h, l;
  h.x = f2bf(v.x); l.x = f2bf(v.x - bf2f(h.x));
  h.y = f2bf(v.y); l.y = f2bf(v.y - bf2f(h.y));
  h.z = f2bf(v.z); l.z = f2bf(v.z - bf2f(h.z));
  h.w = f2bf(v.w); l.w = f2bf(v.w - bf2f(h.w));
  ((ushort4*)hi)[i] = h;
  ((ushort4*)lo)[i] = l;
}

// W[K][N] row-major -> WT hi/lo [N][K] bf16, all three GAT weights in one launch
__global__ void split_weightsT(const float* __restrict__ W1, const float* __restrict__ W2,
                               const float* __restrict__ W3,
                               u16* __restrict__ w1h, u16* __restrict__ w1l,
                               u16* __restrict__ w2h, u16* __restrict__ w2l,
                               u16* __restrict__ w3h, u16* __restrict__ w3l) {
  const int S1 = FEATN * HD;
  const int S2 = S1 + HD * HD;
  const int S3 = S2 + HD * HD;
  int i = blockIdx.x * 256 + threadIdx.x;
  if (i >= S3) return;
  if (i < S1) {
    int k = i / HD, n = i % HD;
    float v = W1[i];
    u16 h = f2bf(v), l = f2bf(v - bf2f(h));
    w1h[n * FEATN + k] = h;
    w1l[n * FEATN + k] = l;
  } else if (i < S2) {
    int j = i - S1;
    int k = j / HD, n = j % HD;
    float v = W2[j];
    u16 h = f2bf(v), l = f2bf(v - bf2f(h));
    w2h[n * HD + k] = h;
    w2l[n * HD + k] = l;
  } else {
    int j = i - S2;
    int k = j / HD, n = j % HD;
    float v = W3[j];
    u16 h = f2bf(v), l = f2bf(v - bf2f(h));
    w3h[n * HD + k] = h;
    w3l[n * HD + k] = l;
  }
}

// ---------- bf16-split MFMA GEMM: C = A @ B, output written as bf16 ----------
template <int K, int N>
__global__ __launch_bounds__(256) void gemm_bf3(const u16* __restrict__ Ahg,
                                                const u16* __restrict__ Alg,
                                                const u16* __restrict__ Bhg,
                                                const u16* __restrict__ Blg,
                                                u16* __restrict__ Cb, int M) {
  constexpr int BKP = 40;
  __shared__ u16 sAh[128][BKP], sAl[128][BKP], sBh[128][BKP], sBl[128][BKP];
  const int t = (int)threadIdx.x;
  const int bm = blockIdx.x * 128, bn = blockIdx.y * 128;
  const int lane = t & 63, w = t >> 6;
  const int wm = w >> 1, wn = w & 1;
  const int fr = lane & 15, kg = lane >> 4;

  f32x4 zero4 = {0.f, 0.f, 0.f, 0.f};
  f32x4 acc[4][4];
#pragma unroll
  for (int i = 0; i < 4; i++)
#pragma unroll
    for (int j = 0; j < 4; j++) acc[i][j] = zero4;

  for (int k0 = 0; k0 < K; k0 += 32) {
    __syncthreads();
#pragma unroll
    for (int i = 0; i < 2; i++) {
      int idx = t * 2 + i;
      int r = idx >> 2, c = (idx & 3) * 8;
      int arow = bm + r;
      us8 vh, vl;
      if (arow < M) {
        vh = *(const us8*)(Ahg + (size_t)arow * K + k0 + c);
        vl = *(const us8*)(Alg + (size_t)arow * K + k0 + c);
      } else {
        vh = (us8)(u16)0;
        vl = (us8)(u16)0;
      }
      *(us8*)&sAh[r][c] = vh;
      *(us8*)&sAl[r][c] = vl;
      int brow = bn + r;
      *(us8*)&sBh[r][c] = *(const us8*)(Bhg + (size_t)brow * K + k0 + c);
      *(us8*)&sBl[r][c] = *(const us8*)(Blg + (size_t)brow * K + k0 + c);
    }
    __syncthreads();
    bf16x8 fah[4], fal[4], fbh[4], fbl[4];
#pragma unroll
    for (int mi = 0; mi < 4; mi++) {
      fah[mi] = *(const bf16x8*)&sAh[wm * 64 + mi * 16 + fr][kg * 8];
      fal[mi] = *(const bf16x8*)&sAl[wm * 64 + mi * 16 + fr][kg * 8];
    }
#pragma unroll
    for (int ni = 0; ni < 4; ni++) {
      fbh[ni] = *(const bf16x8*)&sBh[wn * 64 + ni * 16 + fr][kg * 8];
      fbl[ni] = *(const bf16x8*)&sBl[wn * 64 + ni * 16 + fr][kg * 8];
    }
#pragma unroll
    for (int mi = 0; mi < 4; mi++)
#pragma unroll
      for (int ni = 0; ni < 4; ni++) {
        acc[mi][ni] = __builtin_amdgcn_mfma_f32_16x16x32_bf16(fah[mi], fbh[ni], acc[mi][ni], 0, 0, 0);
        acc[mi][ni] = __builtin_amdgcn_mfma_f32_16x16x32_bf16(fah[mi], fbl[ni], acc[mi][ni], 0, 0, 0);
        acc[mi][ni] = __builtin_amdgcn_mfma_f32_16x16x32_bf16(fal[mi], fbh[ni], acc[mi][ni], 0, 0, 0);
      }
  }
#pragma unroll
  for (int mi = 0; mi < 4; mi++) {
    int rbase = bm + wm * 64 + mi * 16 + kg * 4;
#pragma unroll
    for (int ni = 0; ni < 4; ni++) {
      int col = bn + wn * 64 + ni * 16 + fr;
#pragma unroll
      for (int r = 0; r < 4; r++) {
        int row = rbase + r;
        if (row < M) Cb[(size_t)row * N + col] = f2bf(acc[mi][ni][r]);
      }
    }
  }
}

// ---------------- fp32 tiled GEMM (kept for the small Wg GEMM) ----------------
template <int BN, int TN>
__global__ __launch_bounds__(256) void gemm_f32(const float* __restrict__ A,
                                                const float* __restrict__ B,
                                                float* __restrict__ C, int M, int K, int Nld) {
  constexpr int BM = 128, BK = 16, TM = 8;
  __shared__ float As[BK][BM + 4];
  __shared__ float Bs[BK][BN + 4];
  const int tid = (int)threadIdx.x;
  const int bm = blockIdx.x * BM;
  const int bn = blockIdx.y * BN;
  const int arow = tid >> 1;
  const int acol = (tid & 1) * 8;
  const int brow = tid >> 4;
  const int bcol = (tid & 15) * (BN / 16);
  const int tmr = (tid >> 4) * TM;
  const int tnc = (tid & 15) * TN;

  float acc[TM][TN];
#pragma unroll
  for (int i = 0; i < TM; i++)
#pragma unroll
    for (int j = 0; j < TN; j++) acc[i][j] = 0.f;

  const bool avalid = (bm + arow) < M;
  const float* Arow = A + (size_t)(bm + arow) * K + acol;

  for (int k0 = 0; k0 < K; k0 += BK) {
    float4 a0, a1;
    if (avalid) {
      a0 = *(const float4*)(Arow + k0);
      a1 = *(const float4*)(Arow + k0 + 4);
    } else {
      a0 = make_float4(0.f, 0.f, 0.f, 0.f);
      a1 = a0;
    }
    float4 bv[BN / 64];
#pragma unroll
    for (int l = 0; l < BN / 64; l++)
      bv[l] = *(const float4*)(B + (size_t)(k0 + brow) * Nld + bn + bcol + 4 * l);
    __syncthreads();
    As[acol + 0][arow] = a0.x; As[acol + 1][arow] = a0.y;
    As[acol + 2][arow] = a0.z; As[acol + 3][arow] = a0.w;
    As[acol + 4][arow] = a1.x; As[acol + 5][arow] = a1.y;
    As[acol + 6][arow] = a1.z; As[acol + 7][arow] = a1.w;
#pragma unroll
    for (int l = 0; l < BN / 64; l++) *(float4*)&Bs[brow][bcol + 4 * l] = bv[l];
    __syncthreads();
#pragma unroll
    for (int k = 0; k < BK; k++) {
      float a[TM], b[TN];
#pragma unroll
      for (int i = 0; i < TM; i += 4) {
        float4 t = *(const float4*)&As[k][tmr + i];
        a[i] = t.x; a[i + 1] = t.y; a[i + 2] = t.z; a[i + 3] = t.w;
      }
#pragma unroll
      for (int j = 0; j < TN; j += 4) {
        float4 t = *(const float4*)&Bs[k][tnc + j];
        b[j] = t.x; b[j + 1] = t.y; b[j + 2] = t.z; b[j + 3] = t.w;
      }
#pragma unroll
      for (int i = 0; i < TM; i++)
#pragma unroll
        for (int j = 0; j < TN; j++) acc[i][j] += a[i] * b[j];
    }
  }
#pragma unroll
  for (int i = 0; i < TM; i++) {
    int row = bm + tmr + i;
    if (row < M) {
#pragma unroll
      for (int j = 0; j < TN; j += 4) {
        float4 t = make_float4(acc[i][j], acc[i][j + 1], acc[i][j + 2], acc[i][j + 3]);
        *(float4*)(C + (size_t)row * Nld + bn + tnc + j) = t;
      }
    }
  }
}

// as_h[n,h] = sum_c hfeat[n,h,c]*aS[h,c]; bf16 feature input. One wave per node.
__global__ void attn_proj(const u16* __restrict__ hfeat, const float* __restrict__ aS,
                          const float* __restrict__ aD, float* __restrict__ as_h,
                          float* __restrict__ ad_h) {
  int wid = (blockIdx.x * 256 + (int)threadIdx.x) >> 6;
  int lane = (int)threadIdx.x & 63;
  if (wid >= NN) return;
  const u16* hp = hfeat + (size_t)wid * HD;
#pragma unroll
  for (int h = 0; h < HEADS; h++) {
    float hv = bf2f(hp[h * HIDN + lane]);
    float sv = hv * aS[h * HIDN + lane];
    float dv = hv * aD[h * HIDN + lane];
#pragma unroll
    for (int o = 32; o; o >>= 1) {
      sv += __shfl_xor(sv, o);
      dv += __shfl_xor(dv, o);
    }
    if (lane == 0) {
      as_h[wid * HEADS + h] = sv;
      ad_h[wid * HEADS + h] = dv;
    }
  }
}

// Block-level merge of per-wave (graph, sum, sumsq) then atomics.
// Requires: every wave in the block active (grids exact multiples of 4 waves).
static __device__ __forceinline__ void block_stats_accum(float v, float v2, int g, int lane,
                                                         float* __restrict__ gsum,
                                                         float* __restrict__ gsumsq) {
#pragma unroll
  for (int o = 32; o; o >>= 1) {
    v += __shfl_xor(v, o);
    v2 += __shfl_xor(v2, o);
  }
  __shared__ float s_v[4], s_v2[4];
  __shared__ int s_g[4];
  int wavei = (int)threadIdx.x >> 6;
  if (lane == 0) {
    s_v[wavei] = v;
    s_v2[wavei] = v2;
    s_g[wavei] = g;
  }
  __syncthreads();
  if (threadIdx.x == 0) {
#pragma unroll
    for (int a = 0; a < 4; a++) {
      int ga = s_g[a];
      if (ga < 0) continue;
      float V = s_v[a], V2 = s_v2[a];
#pragma unroll
      for (int b = a + 1; b < 4; b++)
        if (s_g[b] == ga) {
          V += s_v[b];
          V2 += s_v2[b];
          s_g[b] = -1;
        }
      atomicAdd(&gsum[ga], V);
      atomicAdd(&gsumsq[ga], V2);
    }
  }
}

// One wave per NODE, all 8 heads together; bf16 feature gather (16B/lane/edge).
// Score role: lane = (edge_slot<<3)|head. Feature role: lane j covers elems [j*8, j*8+8).
// MODE 0: out row = alpha-agg + bias, fused LN stats.
// MODE 1 (layer 3): head-mean + b3 -> h3[N,64], fused LN stats.
template <int MODE>
__global__ void gat_agg(const u16* __restrict__ hfeat, const float* __restrict__ as_h,
                        const float* __restrict__ ad_h, const int* __restrict__ src_csr,
                        const int* __restrict__ off, const float* __restrict__ bias,
                        float* __restrict__ outp, const int* __restrict__ batch,
                        float* __restrict__ gsum, float* __restrict__ gsumsq) {
  int wid = (blockIdx.x * 256 + (int)threadIdx.x) >> 6;  // node (grid exact)
  int lane = (int)threadIdx.x & 63;
  int n = wid;
  int s0 = off[n], deg = off[n + 1] - s0;
  int hS = lane & 7;   // score-role head
  int eS = lane >> 3;  // score-role edge slot
  int hF = lane >> 3;  // feature-role head
  float adv = ad_h[n * HEADS + hS];

  float4 a0 = make_float4(0.f, 0.f, 0.f, 0.f), a1 = a0;
  float ssum = 0.f;
  for (int base = 0; base < deg; base += 8) {
    int i = base + eS;
    float wl = 0.f;
    int msrc = 0;
    if (i < deg) {
      msrc = src_csr[s0 + i];
      float ev = as_h[msrc * HEADS + hS] + adv;
      ev = (ev > 0.f) ? ev : 0.2f * ev;
      wl = __expf(ev);  // scores O(1); no segmax shift needed (identical ratio)
    }
    ssum += wl;
    int cnt = min(8, deg - base);
    for (int e = 0; e < cnt; ++e) {
      float wgt = __shfl(wl, e * 8 + hF);
      int src = __shfl(msrc, e * 8);
      us8 hv = *(const us8*)(hfeat + (size_t)src * HD + lane * 8);
      a0.x += wgt * bf2f(hv[0]); a0.y += wgt * bf2f(hv[1]);
      a0.z += wgt * bf2f(hv[2]); a0.w += wgt * bf2f(hv[3]);
      a1.x += wgt * bf2f(hv[4]); a1.y += wgt * bf2f(hv[5]);
      a1.z += wgt * bf2f(hv[6]); a1.w += wgt * bf2f(hv[7]);
    }
  }
  // reduce ssum over edge-slot lanes (same head = same lane&7)
  ssum += __shfl_xor(ssum, 8);
  ssum += __shfl_xor(ssum, 16);
  ssum += __shfl_xor(ssum, 32);
  float inv = 1.f / (__shfl(ssum, hF) + 1e-16f);  // lane hF (<8) holds head hF total
  a0.x *= inv; a0.y *= inv; a0.z *= inv; a0.w *= inv;
  a1.x *= inv; a1.y *= inv; a1.z *= inv; a1.w *= inv;

  if (MODE == 0) {
    const float4* bp = (const float4*)(bias + lane * 8);
    float4 b0 = bp[0], b1v = bp[1];
    a0.x += b0.x; a0.y += b0.y; a0.z += b0.z; a0.w += b0.w;
    a1.x += b1v.x; a1.y += b1v.y; a1.z += b1v.z; a1.w += b1v.w;
    float4* op = (float4*)(outp + (size_t)n * HD + lane * 8);
    op[0] = a0;
    op[1] = a1;
    float v = a0.x + a0.y + a0.z + a0.w + a1.x + a1.y + a1.z + a1.w;
    float v2 = a0.x * a0.x + a0.y * a0.y + a0.z * a0.z + a0.w * a0.w +
               a1.x * a1.x + a1.y * a1.y + a1.z * a1.z + a1.w * a1.w;
    block_stats_accum(v, v2, batch[n], lane, gsum, gsumsq);
  } else {
    // sum over heads: lanes with same (lane&7) hold same cols of different heads
#pragma unroll
    for (int o = 8; o <= 32; o <<= 1) {
      a0.x += __shfl_xor(a0.x, o); a0.y += __shfl_xor(a0.y, o);
      a0.z += __shfl_xor(a0.z, o); a0.w += __shfl_xor(a0.w, o);
      a1.x += __shfl_xor(a1.x, o); a1.y += __shfl_xor(a1.y, o);
      a1.z += __shfl_xor(a1.z, o); a1.w += __shfl_xor(a1.w, o);
    }
    const float4* bp = (const float4*)(bias + (lane & 7) * 8);  // bias = b3[64]
    float4 b0 = bp[0], b1v = bp[1];
    a0.x = a0.x * 0.125f + b0.x; a0.y = a0.y * 0.125f + b0.y;
    a0.z = a0.z * 0.125f + b0.z; a0.w = a0.w * 0.125f + b0.w;
    a1.x = a1.x * 0.125f + b1v.x; a1.y = a1.y * 0.125f + b1v.y;
    a1.z = a1.z * 0.125f + b1v.z; a1.w = a1.w * 0.125f + b1v.w;
    if (lane < 8) {
      float4* op = (float4*)(outp + (size_t)n * HIDN + lane * 8);
      op[0] = a0;
      op[1] = a1;
    }
    float v = 0.f, v2 = 0.f;
    if (lane < 8) {
      v = a0.x + a0.y + a0.z + a0.w + a1.x + a1.y + a1.z + a1.w;
      v2 = a0.x * a0.x + a0.y * a0.y + a0.z * a0.z + a0.w * a0.w +
           a1.x * a1.x + a1.y * a1.y + a1.z * a1.z + a1.w * a1.w;
    }
    block_stats_accum(v, v2, batch[n], lane, gsum, gsumsq);
  }
}

// One wave per node; prefetch+shuffle structure.
__global__ void gcn_agg(const float* __restrict__ h, const float* __restrict__ dinv,
                        const int* __restrict__ off, const int* __restrict__ src_csr,
                        const float* __restrict__ bg, const int* __restrict__ batch,
                        float* __restrict__ z) {
  int wid = (blockIdx.x * 256 + (int)threadIdx.x) >> 6;
  int lane = (int)threadIdx.x & 63;
  if (wid >= NN) return;
  int n = wid;
  int s0 = off[n], s1 = off[n + 1];
  int deg = s1 - s0;
  float acc = 0.f;
  for (int base = 0; base < deg; base += 64) {
    int i = base + lane;
    int msrc = (i < deg) ? src_csr[s0 + i] : 0;
    float mdv = (i < deg) ? dinv[msrc] : 0.f;
    int cnt = min(64, deg - base);
    for (int p = 0; p < cnt; ++p) {
      float dv = __shfl(mdv, p);
      int src = __shfl(msrc, p);
      acc += dv * h[(size_t)src * HIDN + lane];
    }
  }
  float y = fmaxf(acc * dinv[n] + bg[lane], 0.f);
  atomicMaxNonneg(&z[batch[n] * 128 + 64 + lane], y);
}

// LN+ReLU, writing bf16 hi/lo split directly (feeds next layer's MFMA GEMM only)
template <int F>
__global__ void ln_apply_split(const float* __restrict__ buf, const int* __restrict__ batch,
                               const float* __restrict__ gsum, const float* __restrict__ gsumsq,
                               const int* __restrict__ gcnt, const float* __restrict__ w,
                               const float* __restrict__ b, u16* __restrict__ hi,
                               u16* __restrict__ lo) {
  int i = blockIdx.x * 256 + (int)threadIdx.x;
  if (i >= NN * F) return;
  int n = i / F, f = i % F;
  int g = batch[n];
  float cnt = (float)gcnt[g] * (float)F;
  float mean = gsum[g] / cnt;
  float var = gsumsq[g] / cnt - mean * mean;
  float y = (buf[i] - mean) * rsqrtf(var + 1e-5f) * w[f] + b[f];
  y = fmaxf(y, 0.f);
  u16 hh = f2bf(y);
  hi[i] = hh;
  lo[i] = f2bf(y - bf2f(hh));
}

template <int F, bool ZMAX>
__global__ void ln_apply(float* __restrict__ buf, const int* __restrict__ batch,
                         const float* __restrict__ gsum, const float* __restrict__ gsumsq,
                         const int* __restrict__ gcnt, const float* __restrict__ w,
                         const float* __restrict__ b, float* __restrict__ z) {
  int i = blockIdx.x * 256 + (int)threadIdx.x;
  if (i >= NN * F) return;
  int n = i / F, f = i % F;
  int g = batch[n];
  float cnt = (float)gcnt[g] * (float)F;
  float mean = gsum[g] / cnt;
  float var = gsumsq[g] / cnt - mean * mean;
  float y = (buf[i] - mean) * rsqrtf(var + 1e-5f) * w[f] + b[f];
  y = fmaxf(y, 0.f);
  buf[i] = y;
  if (ZMAX) atomicMaxNonneg(&z[g * 128 + f], y);
}

__global__ __launch_bounds__(64) void mlp_head(const float* __restrict__ z,
                                               const float* __restrict__ Wl0, const float* __restrict__ bl0,
                                               const float* __restrict__ Wl1, const float* __restrict__ bl1,
                                               const float* __restrict__ Wl2, const float* __restrict__ bl2,
                                               const float* __restrict__ Wo, const float* __restrict__ bo,
                                               float* __restrict__ out) {
  __shared__ float zs[128], t0[64], t1[64], t2[64];
  int g = blockIdx.x, t = (int)threadIdx.x;
  zs[t] = z[g * 128 + t];
  zs[64 + t] = z[g * 128 + 64 + t];
  __syncthreads();
  float a = bl0[t];
  for (int k = 0; k < 128; k++) a += zs[k] * Wl0[k * 64 + t];
  t0[t] = fmaxf(a, 0.f);
  __syncthreads();
  a = bl1[t];
  for (int k = 0; k < 64; k++) a += t0[k] * Wl1[k * 64 + t];
  t1[t] = fmaxf(a, 0.f);
  __syncthreads();
  a = bl2[t];
  for (int k = 0; k < 64; k++) a += t1[k] * Wl2[k * 64 + t];
  t2[t] = fmaxf(a, 0.f);
  __syncthreads();
  if (t < 2) {
    float o = bo[t];
    for (int k = 0; k < 64; k++) o += t2[k] * Wo[k * 2 + t];
    out[g * 2 + t] = o;
  }
  out[128 + g * 128 + t] = zs[t];
  out[128 + g * 128 + 64 + t] = zs[64 + t];
}

extern "C" void kernel_launch(void* const* d_in, const int* in_sizes, int n_in,
                              void* d_out, int out_size, void* d_ws, size_t ws_size,
                              hipStream_t stream) {
  const float* x = (const float*)d_in[0];
  const int* ei = (const int*)d_in[1];
  const int* batch = (const int*)d_in[2];
  const float* W1 = (const float*)d_in[3];
  const float* aS1 = (const float*)d_in[4];
  const float* aD1 = (const float*)d_in[5];
  const float* b1 = (const float*)d_in[6];
  const float* W2 = (const float*)d_in[7];
  const float* aS2 = (const float*)d_in[8];
  const float* aD2 = (const float*)d_in[9];
  const float* b2 = (const float*)d_in[10];
  const float* W3 = (const float*)d_in[11];
  const float* aS3 = (const float*)d_in[12];
  const float* aD3 = (const float*)d_in[13];
  const float* b3 = (const float*)d_in[14];
  const float* Wg = (const float*)d_in[15];
  const float* bg = (const float*)d_in[16];
  const float* nw1 = (const float*)d_in[17];
  const float* nb1 = (const float*)d_in[18];
  const float* nw2 = (const float*)d_in[19];
  const float* nb2 = (const float*)d_in[20];
  const float* nw3 = (const float*)d_in[21];
  const float* nb3 = (const float*)d_in[22];
  const float* Wl0 = (const float*)d_in[23];
  const float* bl0 = (const float*)d_in[24];
  const float* Wl1 = (const float*)d_in[25];
  const float* bl1 = (const float*)d_in[26];
  const float* Wl2 = (const float*)d_in[27];
  const float* bl2 = (const float*)d_in[28];
  const float* Wo = (const float*)d_in[29];
  const float* bo = (const float*)d_in[30];
  float* out = (float*)d_out;

  char* wp = (char*)d_ws;
  auto alloc = [&](size_t bytes) -> void* {
    void* p = (void*)wp;
    wp += ((bytes + 255) & ~(size_t)255);
    return p;
  };
  u16* bufHb = (u16*)alloc((size_t)NN * HD * 2);      // GEMM output, bf16
  float* bufA = (float*)alloc((size_t)NN * HD * 4);   // aggregation output (fp32)
  float* f64b = (float*)alloc((size_t)NN * HIDN * 4);
  float* as_h = (float*)alloc((size_t)NN * HEADS * 4);
  float* ad_h = (float*)alloc((size_t)NN * HEADS * 4);
  const int ZWORDS = NN + NG + 6 * NG + NG * 128;
  int* initblk = (int*)alloc((size_t)ZWORDS * 4);
  int* deg = initblk;
  int* gcnt = deg + NN;
  float* stats = (float*)(gcnt + NG);
  float* zbuf = stats + 6 * NG;
  int* off = (int*)alloc((size_t)(NN + 1) * 4);
  int* cur = (int*)alloc((size_t)NN * 4);
  int* src_csr = (int*)alloc((size_t)NE2 * 4);
  float* dinv = (float*)alloc((size_t)NN * 4);
  int* bsum = (int*)alloc((size_t)256 * 4);
  int* boff = (int*)alloc((size_t)256 * 4);
  u16* xhi = (u16*)alloc((size_t)NN * FEATN * 2);
  u16* xlo = (u16*)alloc((size_t)NN * FEATN * 2);
  u16* ahi = (u16*)alloc((size_t)NN * HD * 2);
  u16* alo = (u16*)alloc((size_t)NN * HD * 2);
  u16* w1h = (u16*)alloc((size_t)FEATN * HD * 2);
  u16* w1l = (u16*)alloc((size_t)FEATN * HD * 2);
  u16* w2h = (u16*)alloc((size_t)HD * HD * 2);
  u16* w2l = (u16*)alloc((size_t)HD * HD * 2);
  u16* w3h = (u16*)alloc((size_t)HD * HD * 2);
  u16* w3l = (u16*)alloc((size_t)HD * HD * 2);

  dim3 b256(256);
  const int NB = (NN + 255) / 256;  // 79 scan blocks
  zero_u32<<<(ZWORDS + 255) / 256, b256, 0, stream>>>((unsigned int*)initblk, ZWORDS);
  build_counts<<<(NE2 + 255) / 256, b256, 0, stream>>>(ei, batch, deg, gcnt);
  scan_phase1<<<NB, b256, 0, stream>>>(deg, off, bsum, NN);
  scan_phase2<<<1, b256, 0, stream>>>(bsum, boff, NB, off + NN);
  scan_phase3<<<NB, b256, 0, stream>>>(off, boff, cur, NN);
  scatter_csr<<<(NE2 + 255) / 256, b256, 0, stream>>>(ei, cur, src_csr);
  compute_dinv<<<(NN + 255) / 256, b256, 0, stream>>>(deg, dinv);
  const int WTOT = FEATN * HD + 2 * HD * HD;
  split_weightsT<<<(WTOT + 255) / 256, b256, 0, stream>>>(W1, W2, W3, w1h, w1l, w2h, w2l, w3h, w3l);
  split_mat<<<(NN * FEATN / 4 + 255) / 256, b256, 0, stream>>>(x, xhi, xlo, NN * FEATN / 4);

  const int wgrid = (NN * 64) / 256;  // one wave per node (exact: 5000 blocks)
  dim3 gmm((NN + 127) / 128, HD / 128);

  // GCN branch
  {
    dim3 g((NN + 127) / 128, 1);
    gemm_f32<64, 4><<<g, b256, 0, stream>>>(x, Wg, f64b, NN, FEATN, HIDN);
    gcn_agg<<<wgrid, b256, 0, stream>>>(f64b, dinv, off, src_csr, bg, batch, zbuf);
  }
  // GAT layer 1
  {
    gemm_bf3<FEATN, HD><<<gmm, b256, 0, stream>>>(xhi, xlo, w1h, w1l, bufHb, NN);
    attn_proj<<<wgrid, b256, 0, stream>>>(bufHb, aS1, aD1, as_h, ad_h);
    gat_agg<0><<<wgrid, b256, 0, stream>>>(bufHb, as_h, ad_h, src_csr, off, b1, bufA,
                                           batch, stats + 0, stats + NG);
    ln_apply_split<HD><<<(NN * HD + 255) / 256, b256, 0, stream>>>(
        bufA, batch, stats + 0, stats + NG, gcnt, nw1, nb1, ahi, alo);
  }
  // GAT layer 2
  {
    gemm_bf3<HD, HD><<<gmm, b256, 0, stream>>>(ahi, alo, w2h, w2l, bufHb, NN);
    attn_proj<<<wgrid, b256, 0, stream>>>(bufHb, aS2, aD2, as_h, ad_h);
    gat_agg<0><<<wgrid, b256, 0, stream>>>(bufHb, as_h, ad_h, src_csr, off, b2, bufA,
                                           batch, stats + 2 * NG, stats + 3 * NG);
    ln_apply_split<HD><<<(NN * HD + 255) / 256, b256, 0, stream>>>(
        bufA, batch, stats + 2 * NG, stats + 3 * NG, gcnt, nw2, nb2, ahi, alo);
  }
  // GAT layer 3 (head-mean + b3 + stats fused into gat_agg)
  {
    gemm_bf3<HD, HD><<<gmm, b256, 0, stream>>>(ahi, alo, w3h, w3l, bufHb, NN);
    attn_proj<<<wgrid, b256, 0, stream>>>(bufHb, aS3, aD3, as_h, ad_h);
    gat_agg<1><<<wgrid, b256, 0, stream>>>(bufHb, as_h, ad_h, src_csr, off, b3, f64b,
                                           batch, stats + 4 * NG, stats + 5 * NG);
    ln_apply<HIDN, true><<<(NN * HIDN + 255) / 256, b256, 0, stream>>>(
        f64b, batch, stats + 4 * NG, stats + 5 * NG, gcnt, nw3, nb3, zbuf);
  }
  mlp_head<<<NG, 64, 0, stream>>>(zbuf, Wl0, bl0, Wl1, bl1, Wl2, bl2, Wo, bo, out);
}

// Round 12
// 559.019 us; speedup vs baseline: 3.0289x; 1.2434x over previous
//
#include <hip/hip_runtime.h>
#include <math.h>

#define NG    64
#define NN    20000
#define NE    160000
#define NE2   180000
#define FEATN 128
#define HIDN  64
#define HEADS 8
#define HD    512  // HEADS*HIDN

typedef unsigned short u16;
typedef __bf16 bf16x8 __attribute__((ext_vector_type(8)));
typedef u16 us8 __attribute__((ext_vector_type(8)));
typedef float f32x4 __attribute__((ext_vector_type(4)));

static __device__ __forceinline__ void atomicMaxNonneg(float* addr, float v) {
  atomicMax((unsigned int*)addr, __float_as_uint(v));
}

static __device__ __forceinline__ u16 f2bf(float f) {
  unsigned int u = __float_as_uint(f);
  u += 0x7fffu + ((u >> 16) & 1u);  // RNE
  return (u16)(u >> 16);
}
static __device__ __forceinline__ float bf2f(u16 s) {
  return __uint_as_float(((unsigned int)s) << 16);
}

// 8-element bf16 FMA into two float4 accumulators (function, not macro:
// a macro parameter named `w` previously captured the `.w` member access)
static __device__ __forceinline__ void acc8(float4& a0, float4& a1, float wgt, us8 v) {
  a0.x += wgt * bf2f(v[0]); a0.y += wgt * bf2f(v[1]);
  a0.z += wgt * bf2f(v[2]); a0.w += wgt * bf2f(v[3]);
  a1.x += wgt * bf2f(v[4]); a1.y += wgt * bf2f(v[5]);
  a1.z += wgt * bf2f(v[6]); a1.w += wgt * bf2f(v[7]);
}

__global__ void zero_u32(unsigned int* __restrict__ p, int n) {
  int i = blockIdx.x * 256 + threadIdx.x;
  if (i < n) p[i] = 0u;
}

// deg histogram (global atomics, low contention) + batch histogram via LDS
// (batch sorted -> per-block LDS bins kill the ~313-deep same-address chains)
__global__ void build_counts(const int* __restrict__ ei, const int* __restrict__ batch,
                             int* __restrict__ deg, int* __restrict__ gcnt) {
  __shared__ int lh[NG];
  int tid = (int)threadIdx.x;
  if (tid < NG) lh[tid] = 0;
  __syncthreads();
  int i = blockIdx.x * 256 + tid;
  if (i < NE2) {
    int d = (i < NE) ? ei[NE + i] : (i - NE);
    atomicAdd(&deg[d], 1);
  }
  if (i < NN) atomicAdd(&lh[batch[i]], 1);
  __syncthreads();
  if (tid < NG && lh[tid]) atomicAdd(&gcnt[tid], lh[tid]);
}

// ---- hierarchical exclusive scan (3 phases); phase1 also emits dinv ----
__global__ void scan_phase1(const int* __restrict__ deg, int* __restrict__ off,
                            int* __restrict__ bsum, float* __restrict__ dinv, int n) {
  __shared__ int tmp[256];
  int tid = (int)threadIdx.x;
  int i = blockIdx.x * 256 + tid;
  int v = (i < n) ? deg[i] : 0;
  if (i < n) dinv[i] = rsqrtf((float)v);
  tmp[tid] = v;
  __syncthreads();
  for (int o = 1; o < 256; o <<= 1) {
    int t = (tid >= o) ? tmp[tid - o] : 0;
    __syncthreads();
    tmp[tid] += t;
    __syncthreads();
  }
  if (i < n) off[i] = tmp[tid] - v;  // block-local exclusive
  if (tid == 255) bsum[blockIdx.x] = tmp[255];
}

__global__ __launch_bounds__(256) void scan_phase2(const int* __restrict__ bsum,
                                                   int* __restrict__ boff, int nb,
                                                   int* __restrict__ off_last) {
  __shared__ int tmp[256];
  int tid = (int)threadIdx.x;
  int v = (tid < nb) ? bsum[tid] : 0;
  tmp[tid] = v;
  __syncthreads();
  for (int o = 1; o < 256; o <<= 1) {
    int t = (tid >= o) ? tmp[tid - o] : 0;
    __syncthreads();
    tmp[tid] += t;
    __syncthreads();
  }
  if (tid < nb) boff[tid] = tmp[tid] - v;
  if (tid == 255) *off_last = tmp[255];  // total == NE2
}

__global__ void scan_phase3(int* __restrict__ off, const int* __restrict__ boff,
                            int* __restrict__ cur, int n) {
  int i = blockIdx.x * 256 + threadIdx.x;
  if (i < n) {
    int e = off[i] + boff[blockIdx.x];
    off[i] = e;
    cur[i] = e;
  }
}

// CSR by dst, materializing src ids per slot
__global__ void scatter_csr(const int* __restrict__ ei, int* __restrict__ cur,
                            int* __restrict__ src_csr) {
  int e = blockIdx.x * 256 + threadIdx.x;
  if (e >= NE2) return;
  int s, d;
  if (e < NE) {
    s = ei[e];
    d = ei[NE + e];
  } else {
    s = e - NE;
    d = e - NE;
  }
  int p = atomicAdd(&cur[d], 1);
  src_csr[p] = s;
}

// fp32 [M][K] -> bf16 hi/lo [M][K] (flat, 4 elems/thread)
__global__ void split_mat(const float* __restrict__ X, u16* __restrict__ hi,
                          u16* __restrict__ lo, int n4) {
  int i = blockIdx.x * 256 + threadIdx.x;
  if (i >= n4) return;
  float4 v = ((const float4*)X)[i];
  ushort4 h, l;
  h.x = f2bf(v.x); l.x = f2bf(v.x - bf2f(h.x));
  h.y = f2bf(v.y); l.y = f2bf(v.y - bf2f(h.y));
  h.z = f2bf(v.z); l.z = f2bf(v.z - bf2f(h.z));
  h.w = f2bf(v.w); l.w = f2bf(v.w - bf2f(h.w));
  ((ushort4*)hi)[i] = h;
  ((ushort4*)lo)[i] = l;
}

// W[K][N] row-major -> WT hi/lo [N][K] bf16, all three GAT weights in one launch
__global__ void split_weightsT(const float* __restrict__ W1, const float* __restrict__ W2,
                               const float* __restrict__ W3,
                               u16* __restrict__ w1h, u16* __restrict__ w1l,
                               u16* __restrict__ w2h, u16* __restrict__ w2l,
                               u16* __restrict__ w3h, u16* __restrict__ w3l) {
  const int S1 = FEATN * HD;
  const int S2 = S1 + HD * HD;
  const int S3 = S2 + HD * HD;
  int i = blockIdx.x * 256 + threadIdx.x;
  if (i >= S3) return;
  if (i < S1) {
    int k = i / HD, n = i % HD;
    float v = W1[i];
    u16 h = f2bf(v), l = f2bf(v - bf2f(h));
    w1h[n * FEATN + k] = h;
    w1l[n * FEATN + k] = l;
  } else if (i < S2) {
    int j = i - S1;
    int k = j / HD, n = j % HD;
    float v = W2[j];
    u16 h = f2bf(v), l = f2bf(v - bf2f(h));
    w2h[n * HD + k] = h;
    w2l[n * HD + k] = l;
  } else {
    int j = i - S2;
    int k = j / HD, n = j % HD;
    float v = W3[j];
    u16 h = f2bf(v), l = f2bf(v - bf2f(h));
    w3h[n * HD + k] = h;
    w3l[n * HD + k] = l;
  }
}

// ---------- bf16-split MFMA GEMM: C = A @ B, output written as bf16 ----------
template <int K, int N>
__global__ __launch_bounds__(256) void gemm_bf3(const u16* __restrict__ Ahg,
                                                const u16* __restrict__ Alg,
                                                const u16* __restrict__ Bhg,
                                                const u16* __restrict__ Blg,
                                                u16* __restrict__ Cb, int M) {
  constexpr int BKP = 40;
  __shared__ u16 sAh[128][BKP], sAl[128][BKP], sBh[128][BKP], sBl[128][BKP];
  const int t = (int)threadIdx.x;
  const int bm = blockIdx.x * 128, bn = blockIdx.y * 128;
  const int lane = t & 63, w = t >> 6;
  const int wm = w >> 1, wn = w & 1;
  const int fr = lane & 15, kg = lane >> 4;

  f32x4 zero4 = {0.f, 0.f, 0.f, 0.f};
  f32x4 acc[4][4];
#pragma unroll
  for (int i = 0; i < 4; i++)
#pragma unroll
    for (int j = 0; j < 4; j++) acc[i][j] = zero4;

  for (int k0 = 0; k0 < K; k0 += 32) {
    __syncthreads();
#pragma unroll
    for (int i = 0; i < 2; i++) {
      int idx = t * 2 + i;
      int r = idx >> 2, c = (idx & 3) * 8;
      int arow = bm + r;
      us8 vh, vl;
      if (arow < M) {
        vh = *(const us8*)(Ahg + (size_t)arow * K + k0 + c);
        vl = *(const us8*)(Alg + (size_t)arow * K + k0 + c);
      } else {
        vh = (us8)(u16)0;
        vl = (us8)(u16)0;
      }
      *(us8*)&sAh[r][c] = vh;
      *(us8*)&sAl[r][c] = vl;
      int brow = bn + r;
      *(us8*)&sBh[r][c] = *(const us8*)(Bhg + (size_t)brow * K + k0 + c);
      *(us8*)&sBl[r][c] = *(const us8*)(Blg + (size_t)brow * K + k0 + c);
    }
    __syncthreads();
    bf16x8 fah[4], fal[4], fbh[4], fbl[4];
#pragma unroll
    for (int mi = 0; mi < 4; mi++) {
      fah[mi] = *(const bf16x8*)&sAh[wm * 64 + mi * 16 + fr][kg * 8];
      fal[mi] = *(const bf16x8*)&sAl[wm * 64 + mi * 16 + fr][kg * 8];
    }
#pragma unroll
    for (int ni = 0; ni < 4; ni++) {
      fbh[ni] = *(const bf16x8*)&sBh[wn * 64 + ni * 16 + fr][kg * 8];
      fbl[ni] = *(const bf16x8*)&sBl[wn * 64 + ni * 16 + fr][kg * 8];
    }
#pragma unroll
    for (int mi = 0; mi < 4; mi++)
#pragma unroll
      for (int ni = 0; ni < 4; ni++) {
        acc[mi][ni] = __builtin_amdgcn_mfma_f32_16x16x32_bf16(fah[mi], fbh[ni], acc[mi][ni], 0, 0, 0);
        acc[mi][ni] = __builtin_amdgcn_mfma_f32_16x16x32_bf16(fah[mi], fbl[ni], acc[mi][ni], 0, 0, 0);
        acc[mi][ni] = __builtin_amdgcn_mfma_f32_16x16x32_bf16(fal[mi], fbh[ni], acc[mi][ni], 0, 0, 0);
      }
  }
#pragma unroll
  for (int mi = 0; mi < 4; mi++) {
    int rbase = bm + wm * 64 + mi * 16 + kg * 4;
#pragma unroll
    for (int ni = 0; ni < 4; ni++) {
      int col = bn + wn * 64 + ni * 16 + fr;
#pragma unroll
      for (int r = 0; r < 4; r++) {
        int row = rbase + r;
        if (row < M) Cb[(size_t)row * N + col] = f2bf(acc[mi][ni][r]);
      }
    }
  }
}

// ------------- fp32 tiled GEMM (small Wg GEMM), bf16 output -------------
template <int BN, int TN>
__global__ __launch_bounds__(256) void gemm_f32(const float* __restrict__ A,
                                                const float* __restrict__ B,
                                                u16* __restrict__ Cb, int M, int K, int Nld) {
  constexpr int BM = 128, BK = 16, TM = 8;
  __shared__ float As[BK][BM + 4];
  __shared__ float Bs[BK][BN + 4];
  const int tid = (int)threadIdx.x;
  const int bm = blockIdx.x * BM;
  const int bn = blockIdx.y * BN;
  const int arow = tid >> 1;
  const int acol = (tid & 1) * 8;
  const int brow = tid >> 4;
  const int bcol = (tid & 15) * (BN / 16);
  const int tmr = (tid >> 4) * TM;
  const int tnc = (tid & 15) * TN;

  float acc[TM][TN];
#pragma unroll
  for (int i = 0; i < TM; i++)
#pragma unroll
    for (int j = 0; j < TN; j++) acc[i][j] = 0.f;

  const bool avalid = (bm + arow) < M;
  const float* Arow = A + (size_t)(bm + arow) * K + acol;

  for (int k0 = 0; k0 < K; k0 += BK) {
    float4 a0, a1;
    if (avalid) {
      a0 = *(const float4*)(Arow + k0);
      a1 = *(const float4*)(Arow + k0 + 4);
    } else {
      a0 = make_float4(0.f, 0.f, 0.f, 0.f);
      a1 = a0;
    }
    float4 bv[BN / 64];
#pragma unroll
    for (int l = 0; l < BN / 64; l++)
      bv[l] = *(const float4*)(B + (size_t)(k0 + brow) * Nld + bn + bcol + 4 * l);
    __syncthreads();
    As[acol + 0][arow] = a0.x; As[acol + 1][arow] = a0.y;
    As[acol + 2][arow] = a0.z; As[acol + 3][arow] = a0.w;
    As[acol + 4][arow] = a1.x; As[acol + 5][arow] = a1.y;
    As[acol + 6][arow] = a1.z; As[acol + 7][arow] = a1.w;
#pragma unroll
    for (int l = 0; l < BN / 64; l++) *(float4*)&Bs[brow][bcol + 4 * l] = bv[l];
    __syncthreads();
#pragma unroll
    for (int k = 0; k < BK; k++) {
      float a[TM], b[TN];
#pragma unroll
      for (int i = 0; i < TM; i += 4) {
        float4 t = *(const float4*)&As[k][tmr + i];
        a[i] = t.x; a[i + 1] = t.y; a[i + 2] = t.z; a[i + 3] = t.w;
      }
#pragma unroll
      for (int j = 0; j < TN; j += 4) {
        float4 t = *(const float4*)&Bs[k][tnc + j];
        b[j] = t.x; b[j + 1] = t.y; b[j + 2] = t.z; b[j + 3] = t.w;
      }
#pragma unroll
      for (int i = 0; i < TM; i++)
#pragma unroll
        for (int j = 0; j < TN; j++) acc[i][j] += a[i] * b[j];
    }
  }
#pragma unroll
  for (int i = 0; i < TM; i++) {
    int row = bm + tmr + i;
    if (row < M) {
#pragma unroll
      for (int j = 0; j < TN; j += 4) {
        ushort4 t;
        t.x = f2bf(acc[i][j]); t.y = f2bf(acc[i][j + 1]);
        t.z = f2bf(acc[i][j + 2]); t.w = f2bf(acc[i][j + 3]);
        *(ushort4*)(Cb + (size_t)row * Nld + bn + tnc + j) = t;
      }
    }
  }
}

// as/ad projections: one us8 load + 6 shuffles per node. Lane j holds row
// elems [8j,8j+8) (head j>>3); 8-lane-group reduce; lanes 0-7 write coalesced.
__global__ void attn_proj(const u16* __restrict__ hfeat, const float* __restrict__ aS,
                          const float* __restrict__ aD, float* __restrict__ as_h,
                          float* __restrict__ ad_h) {
  int wid = (blockIdx.x * 256 + (int)threadIdx.x) >> 6;
  int lane = (int)threadIdx.x & 63;
  if (wid >= NN) return;
  us8 hv = *(const us8*)(hfeat + (size_t)wid * HD + lane * 8);
  float4 s0 = *(const float4*)(aS + lane * 8), s1 = *(const float4*)(aS + lane * 8 + 4);
  float4 d0 = *(const float4*)(aD + lane * 8), d1 = *(const float4*)(aD + lane * 8 + 4);
  float h0 = bf2f(hv[0]), h1 = bf2f(hv[1]), h2 = bf2f(hv[2]), h3 = bf2f(hv[3]);
  float h4 = bf2f(hv[4]), h5 = bf2f(hv[5]), h6 = bf2f(hv[6]), h7 = bf2f(hv[7]);
  float sv = h0 * s0.x + h1 * s0.y + h2 * s0.z + h3 * s0.w +
             h4 * s1.x + h5 * s1.y + h6 * s1.z + h7 * s1.w;
  float dv = h0 * d0.x + h1 * d0.y + h2 * d0.z + h3 * d0.w +
             h4 * d1.x + h5 * d1.y + h6 * d1.z + h7 * d1.w;
#pragma unroll
  for (int o = 1; o < 8; o <<= 1) {
    sv += __shfl_xor(sv, o);
    dv += __shfl_xor(dv, o);
  }
  float svh = __shfl(sv, (lane & 7) * 8);
  float dvh = __shfl(dv, (lane & 7) * 8);
  if (lane < 8) {
    as_h[wid * HEADS + lane] = svh;
    ad_h[wid * HEADS + lane] = dvh;
  }
}

// Block-level merge of per-wave (graph, sum, sumsq) then atomics.
// Requires: every wave in the block active (grids exact multiples of 4 waves).
static __device__ __forceinline__ void block_stats_accum(float v, float v2, int g, int lane,
                                                         float* __restrict__ gsum,
                                                         float* __restrict__ gsumsq) {
#pragma unroll
  for (int o = 32; o; o >>= 1) {
    v += __shfl_xor(v, o);
    v2 += __shfl_xor(v2, o);
  }
  __shared__ float s_v[4], s_v2[4];
  __shared__ int s_g[4];
  int wavei = (int)threadIdx.x >> 6;
  if (lane == 0) {
    s_v[wavei] = v;
    s_v2[wavei] = v2;
    s_g[wavei] = g;
  }
  __syncthreads();
  if (threadIdx.x == 0) {
#pragma unroll
    for (int a = 0; a < 4; a++) {
      int ga = s_g[a];
      if (ga < 0) continue;
      float V = s_v[a], V2 = s_v2[a];
#pragma unroll
      for (int b = a + 1; b < 4; b++)
        if (s_g[b] == ga) {
          V += s_v[b];
          V2 += s_v2[b];
          s_g[b] = -1;
        }
      atomicAdd(&gsum[ga], V);
      atomicAdd(&gsumsq[ga], V2);
    }
  }
}

// One wave per NODE, all 8 heads; bf16 gather. Full 8-edge groups take an
// unrolled path with 8 named us8 regs -> 8 gathers in flight per wave (MLP).
template <int MODE>
__global__ void gat_agg(const u16* __restrict__ hfeat, const float* __restrict__ as_h,
                        const float* __restrict__ ad_h, const int* __restrict__ src_csr,
                        const int* __restrict__ off, const float* __restrict__ bias,
                        float* __restrict__ outp, const int* __restrict__ batch,
                        float* __restrict__ gsum, float* __restrict__ gsumsq) {
  int wid = (blockIdx.x * 256 + (int)threadIdx.x) >> 6;  // node (grid exact)
  int lane = (int)threadIdx.x & 63;
  int n = wid;
  int s0 = off[n], deg = off[n + 1] - s0;
  int hS = lane & 7;   // score-role head
  int eS = lane >> 3;  // score-role edge slot
  int hF = lane >> 3;  // feature-role head
  float adv = ad_h[n * HEADS + hS];

  float4 a0 = make_float4(0.f, 0.f, 0.f, 0.f), a1 = a0;
  float ssum = 0.f;
  for (int base = 0; base < deg; base += 8) {
    int i = base + eS;
    float wl = 0.f;
    int msrc = 0;
    if (i < deg) {
      msrc = src_csr[s0 + i];
      float ev = as_h[msrc * HEADS + hS] + adv;
      ev = (ev > 0.f) ? ev : 0.2f * ev;
      wl = __expf(ev);  // scores O(1); no segmax shift needed (identical ratio)
    }
    ssum += wl;
    int cnt = min(8, deg - base);
    if (cnt == 8) {
      int r0 = __shfl(msrc, 0), r1 = __shfl(msrc, 8), r2 = __shfl(msrc, 16),
          r3 = __shfl(msrc, 24), r4 = __shfl(msrc, 32), r5 = __shfl(msrc, 40),
          r6 = __shfl(msrc, 48), r7 = __shfl(msrc, 56);
      us8 v0 = *(const us8*)(hfeat + (size_t)r0 * HD + lane * 8);
      us8 v1 = *(const us8*)(hfeat + (size_t)r1 * HD + lane * 8);
      us8 v2 = *(const us8*)(hfeat + (size_t)r2 * HD + lane * 8);
      us8 v3 = *(const us8*)(hfeat + (size_t)r3 * HD + lane * 8);
      us8 v4 = *(const us8*)(hfeat + (size_t)r4 * HD + lane * 8);
      us8 v5 = *(const us8*)(hfeat + (size_t)r5 * HD + lane * 8);
      us8 v6 = *(const us8*)(hfeat + (size_t)r6 * HD + lane * 8);
      us8 v7 = *(const us8*)(hfeat + (size_t)r7 * HD + lane * 8);
      float w0 = __shfl(wl, hF), w1 = __shfl(wl, 8 + hF), w2 = __shfl(wl, 16 + hF),
            w3 = __shfl(wl, 24 + hF), w4 = __shfl(wl, 32 + hF), w5 = __shfl(wl, 40 + hF),
            w6 = __shfl(wl, 48 + hF), w7 = __shfl(wl, 56 + hF);
      acc8(a0, a1, w0, v0); acc8(a0, a1, w1, v1);
      acc8(a0, a1, w2, v2); acc8(a0, a1, w3, v3);
      acc8(a0, a1, w4, v4); acc8(a0, a1, w5, v5);
      acc8(a0, a1, w6, v6); acc8(a0, a1, w7, v7);
    } else {
      for (int e = 0; e < cnt; ++e) {
        float wgt = __shfl(wl, e * 8 + hF);
        int src = __shfl(msrc, e * 8);
        us8 hv = *(const us8*)(hfeat + (size_t)src * HD + lane * 8);
        acc8(a0, a1, wgt, hv);
      }
    }
  }
  // reduce ssum over edge-slot lanes (same head = same lane&7)
  ssum += __shfl_xor(ssum, 8);
  ssum += __shfl_xor(ssum, 16);
  ssum += __shfl_xor(ssum, 32);
  float inv = 1.f / (__shfl(ssum, hF) + 1e-16f);  // lane hF (<8) holds head hF total
  a0.x *= inv; a0.y *= inv; a0.z *= inv; a0.w *= inv;
  a1.x *= inv; a1.y *= inv; a1.z *= inv; a1.w *= inv;

  if (MODE == 0) {
    const float4* bp = (const float4*)(bias + lane * 8);
    float4 b0 = bp[0], b1v = bp[1];
    a0.x += b0.x; a0.y += b0.y; a0.z += b0.z; a0.w += b0.w;
    a1.x += b1v.x; a1.y += b1v.y; a1.z += b1v.z; a1.w += b1v.w;
    float4* op = (float4*)(outp + (size_t)n * HD + lane * 8);
    op[0] = a0;
    op[1] = a1;
    float v = a0.x + a0.y + a0.z + a0.w + a1.x + a1.y + a1.z + a1.w;
    float v2 = a0.x * a0.x + a0.y * a0.y + a0.z * a0.z + a0.w * a0.w +
               a1.x * a1.x + a1.y * a1.y + a1.z * a1.z + a1.w * a1.w;
    block_stats_accum(v, v2, batch[n], lane, gsum, gsumsq);
  } else {
    // sum over heads: lanes with same (lane&7) hold same cols of different heads
#pragma unroll
    for (int o = 8; o <= 32; o <<= 1) {
      a0.x += __shfl_xor(a0.x, o); a0.y += __shfl_xor(a0.y, o);
      a0.z += __shfl_xor(a0.z, o); a0.w += __shfl_xor(a0.w, o);
      a1.x += __shfl_xor(a1.x, o); a1.y += __shfl_xor(a1.y, o);
      a1.z += __shfl_xor(a1.z, o); a1.w += __shfl_xor(a1.w, o);
    }
    const float4* bp = (const float4*)(bias + (lane & 7) * 8);  // bias = b3[64]
    float4 b0 = bp[0], b1v = bp[1];
    a0.x = a0.x * 0.125f + b0.x; a0.y = a0.y * 0.125f + b0.y;
    a0.z = a0.z * 0.125f + b0.z; a0.w = a0.w * 0.125f + b0.w;
    a1.x = a1.x * 0.125f + b1v.x; a1.y = a1.y * 0.125f + b1v.y;
    a1.z = a1.z * 0.125f + b1v.z; a1.w = a1.w * 0.125f + b1v.w;
    if (lane < 8) {
      float4* op = (float4*)(outp + (size_t)n * HIDN + lane * 8);
      op[0] = a0;
      op[1] = a1;
    }
    float v = 0.f, v2 = 0.f;
    if (lane < 8) {
      v = a0.x + a0.y + a0.z + a0.w + a1.x + a1.y + a1.z + a1.w;
      v2 = a0.x * a0.x + a0.y * a0.y + a0.z * a0.z + a0.w * a0.w +
           a1.x * a1.x + a1.y * a1.y + a1.z * a1.z + a1.w * a1.w;
    }
    block_stats_accum(v, v2, batch[n], lane, gsum, gsumsq);
  }
}

// One wave per node; bf16 feature gather, 4-wide unrolled inner loop.
__global__ void gcn_agg(const u16* __restrict__ hg, const float* __restrict__ dinv,
                        const int* __restrict__ off, const int* __restrict__ src_csr,
                        const float* __restrict__ bg, const int* __restrict__ batch,
                        float* __restrict__ z) {
  int wid = (blockIdx.x * 256 + (int)threadIdx.x) >> 6;
  int lane = (int)threadIdx.x & 63;
  if (wid >= NN) return;
  int n = wid;
  int s0 = off[n], s1 = off[n + 1];
  int deg = s1 - s0;
  float acc = 0.f;
  for (int base = 0; base < deg; base += 64) {
    int i = base + lane;
    int msrc = (i < deg) ? src_csr[s0 + i] : 0;
    float mdv = (i < deg) ? dinv[msrc] : 0.f;
    int cnt = min(64, deg - base);
    int e = 0;
    for (; e + 4 <= cnt; e += 4) {
      float dv0 = __shfl(mdv, e), dv1 = __shfl(mdv, e + 1);
      float dv2 = __shfl(mdv, e + 2), dv3 = __shfl(mdv, e + 3);
      int r0 = __shfl(msrc, e), r1 = __shfl(msrc, e + 1);
      int r2 = __shfl(msrc, e + 2), r3 = __shfl(msrc, e + 3);
      float h0 = bf2f(hg[(size_t)r0 * HIDN + lane]);
      float h1 = bf2f(hg[(size_t)r1 * HIDN + lane]);
      float h2 = bf2f(hg[(size_t)r2 * HIDN + lane]);
      float h3 = bf2f(hg[(size_t)r3 * HIDN + lane]);
      acc += dv0 * h0 + dv1 * h1 + dv2 * h2 + dv3 * h3;
    }
    for (; e < cnt; ++e) {
      float dv = __shfl(mdv, e);
      int src = __shfl(msrc, e);
      acc += dv * bf2f(hg[(size_t)src * HIDN + lane]);
    }
  }
  float y = fmaxf(acc * dinv[n] + bg[lane], 0.f);
  atomicMaxNonneg(&z[batch[n] * 128 + 64 + lane], y);
}

// LN+ReLU -> bf16 hi/lo split, float4-vectorized (4 elems/thread)
template <int F>
__global__ void ln_apply_split(const float* __restrict__ buf, const int* __restrict__ batch,
                               const float* __restrict__ gsum, const float* __restrict__ gsumsq,
                               const int* __restrict__ gcnt, const float* __restrict__ w,
                               const float* __restrict__ b, u16* __restrict__ hi,
                               u16* __restrict__ lo) {
  int i4 = blockIdx.x * 256 + (int)threadIdx.x;
  if (i4 >= NN * F / 4) return;
  int n = i4 / (F / 4), f = (i4 % (F / 4)) * 4;
  int g = batch[n];
  float cnt = (float)gcnt[g] * (float)F;
  float mean = gsum[g] / cnt;
  float var = gsumsq[g] / cnt - mean * mean;
  float rs = rsqrtf(var + 1e-5f);
  float4 v = *(const float4*)(buf + (size_t)n * F + f);
  float4 wv = *(const float4*)(w + f);
  float4 bv = *(const float4*)(b + f);
  float y0 = fmaxf((v.x - mean) * rs * wv.x + bv.x, 0.f);
  float y1 = fmaxf((v.y - mean) * rs * wv.y + bv.y, 0.f);
  float y2 = fmaxf((v.z - mean) * rs * wv.z + bv.z, 0.f);
  float y3 = fmaxf((v.w - mean) * rs * wv.w + bv.w, 0.f);
  ushort4 hh, ll;
  hh.x = f2bf(y0); ll.x = f2bf(y0 - bf2f(hh.x));
  hh.y = f2bf(y1); ll.y = f2bf(y1 - bf2f(hh.y));
  hh.z = f2bf(y2); ll.z = f2bf(y2 - bf2f(hh.z));
  hh.w = f2bf(y3); ll.w = f2bf(y3 - bf2f(hh.w));
  *(ushort4*)(hi + (size_t)n * F + f) = hh;
  *(ushort4*)(lo + (size_t)n * F + f) = ll;
}

template <int F, bool ZMAX>
__global__ void ln_apply(float* __restrict__ buf, const int* __restrict__ batch,
                         const float* __restrict__ gsum, const float* __restrict__ gsumsq,
                         const int* __restrict__ gcnt, const float* __restrict__ w,
                         const float* __restrict__ b, float* __restrict__ z) {
  int i = blockIdx.x * 256 + (int)threadIdx.x;
  if (i >= NN * F) return;
  int n = i / F, f = i % F;
  int g = batch[n];
  float cnt = (float)gcnt[g] * (float)F;
  float mean = gsum[g] / cnt;
  float var = gsumsq[g] / cnt - mean * mean;
  float y = (buf[i] - mean) * rsqrtf(var + 1e-5f) * w[f] + b[f];
  y = fmaxf(y, 0.f);
  buf[i] = y;
  if (ZMAX) atomicMaxNonneg(&z[g * 128 + f], y);
}

__global__ __launch_bounds__(64) void mlp_head(const float* __restrict__ z,
                                               const float* __restrict__ Wl0, const float* __restrict__ bl0,
                                               const float* __restrict__ Wl1, const float* __restrict__ bl1,
                                               const float* __restrict__ Wl2, const float* __restrict__ bl2,
                                               const float* __restrict__ Wo, const float* __restrict__ bo,
                                               float* __restrict__ out) {
  __shared__ float zs[128], t0[64], t1[64], t2[64];
  int g = blockIdx.x, t = (int)threadIdx.x;
  zs[t] = z[g * 128 + t];
  zs[64 + t] = z[g * 128 + 64 + t];
  __syncthreads();
  float a = bl0[t];
  for (int k = 0; k < 128; k++) a += zs[k] * Wl0[k * 64 + t];
  t0[t] = fmaxf(a, 0.f);
  __syncthreads();
  a = bl1[t];
  for (int k = 0; k < 64; k++) a += t0[k] * Wl1[k * 64 + t];
  t1[t] = fmaxf(a, 0.f);
  __syncthreads();
  a = bl2[t];
  for (int k = 0; k < 64; k++) a += t1[k] * Wl2[k * 64 + t];
  t2[t] = fmaxf(a, 0.f);
  __syncthreads();
  if (t < 2) {
    float o = bo[t];
    for (int k = 0; k < 64; k++) o += t2[k] * Wo[k * 2 + t];
    out[g * 2 + t] = o;
  }
  out[128 + g * 128 + t] = zs[t];
  out[128 + g * 128 + 64 + t] = zs[64 + t];
}

extern "C" void kernel_launch(void* const* d_in, const int* in_sizes, int n_in,
                              void* d_out, int out_size, void* d_ws, size_t ws_size,
                              hipStream_t stream) {
  const float* x = (const float*)d_in[0];
  const int* ei = (const int*)d_in[1];
  const int* batch = (const int*)d_in[2];
  const float* W1 = (const float*)d_in[3];
  const float* aS1 = (const float*)d_in[4];
  const float* aD1 = (const float*)d_in[5];
  const float* b1 = (const float*)d_in[6];
  const float* W2 = (const float*)d_in[7];
  const float* aS2 = (const float*)d_in[8];
  const float* aD2 = (const float*)d_in[9];
  const float* b2 = (const float*)d_in[10];
  const float* W3 = (const float*)d_in[11];
  const float* aS3 = (const float*)d_in[12];
  const float* aD3 = (const float*)d_in[13];
  const float* b3 = (const float*)d_in[14];
  const float* Wg = (const float*)d_in[15];
  const float* bg = (const float*)d_in[16];
  const float* nw1 = (const float*)d_in[17];
  const float* nb1 = (const float*)d_in[18];
  const float* nw2 = (const float*)d_in[19];
  const float* nb2 = (const float*)d_in[20];
  const float* nw3 = (const float*)d_in[21];
  const float* nb3 = (const float*)d_in[22];
  const float* Wl0 = (const float*)d_in[23];
  const float* bl0 = (const float*)d_in[24];
  const float* Wl1 = (const float*)d_in[25];
  const float* bl1 = (const float*)d_in[26];
  const float* Wl2 = (const float*)d_in[27];
  const float* bl2 = (const float*)d_in[28];
  const float* Wo = (const float*)d_in[29];
  const float* bo = (const float*)d_in[30];
  float* out = (float*)d_out;

  char* wp = (char*)d_ws;
  auto alloc = [&](size_t bytes) -> void* {
    void* p = (void*)wp;
    wp += ((bytes + 255) & ~(size_t)255);
    return p;
  };
  u16* bufHb = (u16*)alloc((size_t)NN * HD * 2);      // GEMM output, bf16
  float* bufA = (float*)alloc((size_t)NN * HD * 4);   // aggregation output (fp32)
  float* f64b = (float*)alloc((size_t)NN * HIDN * 4); // layer-3 h3 (fp32)
  u16* gcnb = (u16*)alloc((size_t)NN * HIDN * 2);     // gcn features bf16
  float* as_h = (float*)alloc((size_t)NN * HEADS * 4);
  float* ad_h = (float*)alloc((size_t)NN * HEADS * 4);
  const int ZWORDS = NN + NG + 6 * NG + NG * 128;
  int* initblk = (int*)alloc((size_t)ZWORDS * 4);
  int* deg = initblk;
  int* gcnt = deg + NN;
  float* stats = (float*)(gcnt + NG);
  float* zbuf = stats + 6 * NG;
  int* off = (int*)alloc((size_t)(NN + 1) * 4);
  int* cur = (int*)alloc((size_t)NN * 4);
  int* src_csr = (int*)alloc((size_t)NE2 * 4);
  float* dinv = (float*)alloc((size_t)NN * 4);
  int* bsum = (int*)alloc((size_t)256 * 4);
  int* boff = (int*)alloc((size_t)256 * 4);
  u16* xhi = (u16*)alloc((size_t)NN * FEATN * 2);
  u16* xlo = (u16*)alloc((size_t)NN * FEATN * 2);
  u16* ahi = (u16*)alloc((size_t)NN * HD * 2);
  u16* alo = (u16*)alloc((size_t)NN * HD * 2);
  u16* w1h = (u16*)alloc((size_t)FEATN * HD * 2);
  u16* w1l = (u16*)alloc((size_t)FEATN * HD * 2);
  u16* w2h = (u16*)alloc((size_t)HD * HD * 2);
  u16* w2l = (u16*)alloc((size_t)HD * HD * 2);
  u16* w3h = (u16*)alloc((size_t)HD * HD * 2);
  u16* w3l = (u16*)alloc((size_t)HD * HD * 2);

  dim3 b256(256);
  const int NB = (NN + 255) / 256;  // 79 scan blocks
  zero_u32<<<(ZWORDS + 255) / 256, b256, 0, stream>>>((unsigned int*)initblk, ZWORDS);
  build_counts<<<(NE2 + 255) / 256, b256, 0, stream>>>(ei, batch, deg, gcnt);
  scan_phase1<<<NB, b256, 0, stream>>>(deg, off, bsum, dinv, NN);
  scan_phase2<<<1, b256, 0, stream>>>(bsum, boff, NB, off + NN);
  scan_phase3<<<NB, b256, 0, stream>>>(off, boff, cur, NN);
  scatter_csr<<<(NE2 + 255) / 256, b256, 0, stream>>>(ei, cur, src_csr);
  const int WTOT = FEATN * HD + 2 * HD * HD;
  split_weightsT<<<(WTOT + 255) / 256, b256, 0, stream>>>(W1, W2, W3, w1h, w1l, w2h, w2l, w3h, w3l);
  split_mat<<<(NN * FEATN / 4 + 255) / 256, b256, 0, stream>>>(x, xhi, xlo, NN * FEATN / 4);

  const int wgrid = (NN * 64) / 256;  // one wave per node (exact: 5000 blocks)
  dim3 gmm((NN + 127) / 128, HD / 128);

  // GCN branch (bf16 features)
  {
    dim3 g((NN + 127) / 128, 1);
    gemm_f32<64, 4><<<g, b256, 0, stream>>>(x, Wg, gcnb, NN, FEATN, HIDN);
    gcn_agg<<<wgrid, b256, 0, stream>>>(gcnb, dinv, off, src_csr, bg, batch, zbuf);
  }
  // GAT layer 1
  {
    gemm_bf3<FEATN, HD><<<gmm, b256, 0, stream>>>(xhi, xlo, w1h, w1l, bufHb, NN);
    attn_proj<<<wgrid, b256, 0, stream>>>(bufHb, aS1, aD1, as_h, ad_h);
    gat_agg<0><<<wgrid, b256, 0, stream>>>(bufHb, as_h, ad_h, src_csr, off, b1, bufA,
                                           batch, stats + 0, stats + NG);
    ln_apply_split<HD><<<(NN * HD / 4 + 255) / 256, b256, 0, stream>>>(
        bufA, batch, stats + 0, stats + NG, gcnt, nw1, nb1, ahi, alo);
  }
  // GAT layer 2
  {
    gemm_bf3<HD, HD><<<gmm, b256, 0, stream>>>(ahi, alo, w2h, w2l, bufHb, NN);
    attn_proj<<<wgrid, b256, 0, stream>>>(bufHb, aS2, aD2, as_h, ad_h);
    gat_agg<0><<<wgrid, b256, 0, stream>>>(bufHb, as_h, ad_h, src_csr, off, b2, bufA,
                                           batch, stats + 2 * NG, stats + 3 * NG);
    ln_apply_split<HD><<<(NN * HD / 4 + 255) / 256, b256, 0, stream>>>(
        bufA, batch, stats + 2 * NG, stats + 3 * NG, gcnt, nw2, nb2, ahi, alo);
  }
  // GAT layer 3 (head-mean + b3 + stats fused into gat_agg)
  {
    gemm_bf3<HD, HD><<<gmm, b256, 0, stream>>>(ahi, alo, w3h, w3l, bufHb, NN);
    attn_proj<<<wgrid, b256, 0, stream>>>(bufHb, aS3, aD3, as_h, ad_h);
    gat_agg<1><<<wgrid, b256, 0, stream>>>(bufHb, as_h, ad_h, src_csr, off, b3, f64b,
                                           batch, stats + 4 * NG, stats + 5 * NG);
    ln_apply<HIDN, true><<<(NN * HIDN + 255) / 256, b256, 0, stream>>>(
        f64b, batch, stats + 4 * NG, stats + 5 * NG, gcnt, nw3, nb3, zbuf);
  }
  mlp_head<<<NG, 64, 0, stream>>>(zbuf, Wl0, bl0, Wl1, bl1, Wl2, bl2, Wo, bo, out);
}

// Round 13
// 552.318 us; speedup vs baseline: 3.0657x; 1.0121x over previous
//
#include <hip/hip_runtime.h>
#include <math.h>

#define NG    64
#define NN    20000
#define NE    160000
#define NE2   180000
#define FEATN 128
#define HIDN  64
#define HEADS 8
#define HD    512  // HEADS*HIDN

typedef unsigned short u16;
typedef __bf16 bf16x8 __attribute__((ext_vector_type(8)));
typedef u16 us8 __attribute__((ext_vector_type(8)));
typedef float f32x4 __attribute__((ext_vector_type(4)));

static __device__ __forceinline__ void atomicMaxNonneg(float* addr, float v) {
  atomicMax((unsigned int*)addr, __float_as_uint(v));
}

static __device__ __forceinline__ u16 f2bf(float f) {
  unsigned int u = __float_as_uint(f);
  u += 0x7fffu + ((u >> 16) & 1u);  // RNE
  return (u16)(u >> 16);
}
static __device__ __forceinline__ float bf2f(u16 s) {
  return __uint_as_float(((unsigned int)s) << 16);
}

// 8-element bf16 FMA into two float4 accumulators
static __device__ __forceinline__ void acc8(float4& a0, float4& a1, float wgt, us8 v) {
  a0.x += wgt * bf2f(v[0]); a0.y += wgt * bf2f(v[1]);
  a0.z += wgt * bf2f(v[2]); a0.w += wgt * bf2f(v[3]);
  a1.x += wgt * bf2f(v[4]); a1.y += wgt * bf2f(v[5]);
  a1.z += wgt * bf2f(v[6]); a1.w += wgt * bf2f(v[7]);
}

__global__ void zero_u32(unsigned int* __restrict__ p, int n) {
  int i = blockIdx.x * 256 + threadIdx.x;
  if (i < n) p[i] = 0u;
}

// deg histogram (global atomics) + batch histogram via LDS bins
__global__ void build_counts(const int* __restrict__ ei, const int* __restrict__ batch,
                             int* __restrict__ deg, int* __restrict__ gcnt) {
  __shared__ int lh[NG];
  int tid = (int)threadIdx.x;
  if (tid < NG) lh[tid] = 0;
  __syncthreads();
  int i = blockIdx.x * 256 + tid;
  if (i < NE2) {
    int d = (i < NE) ? ei[NE + i] : (i - NE);
    atomicAdd(&deg[d], 1);
  }
  if (i < NN) atomicAdd(&lh[batch[i]], 1);
  __syncthreads();
  if (tid < NG && lh[tid]) atomicAdd(&gcnt[tid], lh[tid]);
}

// ---- hierarchical exclusive scan (3 phases); phase1 also emits dinv ----
__global__ void scan_phase1(const int* __restrict__ deg, int* __restrict__ off,
                            int* __restrict__ bsum, float* __restrict__ dinv, int n) {
  __shared__ int tmp[256];
  int tid = (int)threadIdx.x;
  int i = blockIdx.x * 256 + tid;
  int v = (i < n) ? deg[i] : 0;
  if (i < n) dinv[i] = rsqrtf((float)v);
  tmp[tid] = v;
  __syncthreads();
  for (int o = 1; o < 256; o <<= 1) {
    int t = (tid >= o) ? tmp[tid - o] : 0;
    __syncthreads();
    tmp[tid] += t;
    __syncthreads();
  }
  if (i < n) off[i] = tmp[tid] - v;  // block-local exclusive
  if (tid == 255) bsum[blockIdx.x] = tmp[255];
}

__global__ __launch_bounds__(256) void scan_phase2(const int* __restrict__ bsum,
                                                   int* __restrict__ boff, int nb,
                                                   int* __restrict__ off_last) {
  __shared__ int tmp[256];
  int tid = (int)threadIdx.x;
  int v = (tid < nb) ? bsum[tid] : 0;
  tmp[tid] = v;
  __syncthreads();
  for (int o = 1; o < 256; o <<= 1) {
    int t = (tid >= o) ? tmp[tid - o] : 0;
    __syncthreads();
    tmp[tid] += t;
    __syncthreads();
  }
  if (tid < nb) boff[tid] = tmp[tid] - v;
  if (tid == 255) *off_last = tmp[255];  // total == NE2
}

__global__ void scan_phase3(int* __restrict__ off, const int* __restrict__ boff,
                            int* __restrict__ cur, int n) {
  int i = blockIdx.x * 256 + threadIdx.x;
  if (i < n) {
    int e = off[i] + boff[blockIdx.x];
    off[i] = e;
    cur[i] = e;
  }
}

// CSR by dst, materializing src ids per slot
__global__ void scatter_csr(const int* __restrict__ ei, int* __restrict__ cur,
                            int* __restrict__ src_csr) {
  int e = blockIdx.x * 256 + threadIdx.x;
  if (e >= NE2) return;
  int s, d;
  if (e < NE) {
    s = ei[e];
    d = ei[NE + e];
  } else {
    s = e - NE;
    d = e - NE;
  }
  int p = atomicAdd(&cur[d], 1);
  src_csr[p] = s;
}

// fp32 [M][K] -> bf16 hi/lo [M][K] (flat, 4 elems/thread)
__global__ void split_mat(const float* __restrict__ X, u16* __restrict__ hi,
                          u16* __restrict__ lo, int n4) {
  int i = blockIdx.x * 256 + threadIdx.x;
  if (i >= n4) return;
  float4 v = ((const float4*)X)[i];
  ushort4 h, l;
  h.x = f2bf(v.x); l.x = f2bf(v.x - bf2f(h.x));
  h.y = f2bf(v.y); l.y = f2bf(v.y - bf2f(h.y));
  h.z = f2bf(v.z); l.z = f2bf(v.z - bf2f(h.z));
  h.w = f2bf(v.w); l.w = f2bf(v.w - bf2f(h.w));
  ((ushort4*)hi)[i] = h;
  ((ushort4*)lo)[i] = l;
}

// W[K][N] row-major -> WT hi/lo [N][K] bf16, all three GAT weights in one launch
__global__ void split_weightsT(const float* __restrict__ W1, const float* __restrict__ W2,
                               const float* __restrict__ W3,
                               u16* __restrict__ w1h, u16* __restrict__ w1l,
                               u16* __restrict__ w2h, u16* __restrict__ w2l,
                               u16* __restrict__ w3h, u16* __restrict__ w3l) {
  const int S1 = FEATN * HD;
  const int S2 = S1 + HD * HD;
  const int S3 = S2 + HD * HD;
  int i = blockIdx.x * 256 + threadIdx.x;
  if (i >= S3) return;
  if (i < S1) {
    int k = i / HD, n = i % HD;
    float v = W1[i];
    u16 h = f2bf(v), l = f2bf(v - bf2f(h));
    w1h[n * FEATN + k] = h;
    w1l[n * FEATN + k] = l;
  } else if (i < S2) {
    int j = i - S1;
    int k = j / HD, n = j % HD;
    float v = W2[j];
    u16 h = f2bf(v), l = f2bf(v - bf2f(h));
    w2h[n * HD + k] = h;
    w2l[n * HD + k] = l;
  } else {
    int j = i - S2;
    int k = j / HD, n = j % HD;
    float v = W3[j];
    u16 h = f2bf(v), l = f2bf(v - bf2f(h));
    w3h[n * HD + k] = h;
    w3l[n * HD + k] = l;
  }
}

// ---------- bf16-split MFMA GEMM: C = A @ B, output written as bf16 ----------
template <int K, int N>
__global__ __launch_bounds__(256) void gemm_bf3(const u16* __restrict__ Ahg,
                                                const u16* __restrict__ Alg,
                                                const u16* __restrict__ Bhg,
                                                const u16* __restrict__ Blg,
                                                u16* __restrict__ Cb, int M) {
  constexpr int BKP = 40;
  __shared__ u16 sAh[128][BKP], sAl[128][BKP], sBh[128][BKP], sBl[128][BKP];
  const int t = (int)threadIdx.x;
  const int bm = blockIdx.x * 128, bn = blockIdx.y * 128;
  const int lane = t & 63, w = t >> 6;
  const int wm = w >> 1, wn = w & 1;
  const int fr = lane & 15, kg = lane >> 4;

  f32x4 zero4 = {0.f, 0.f, 0.f, 0.f};
  f32x4 acc[4][4];
#pragma unroll
  for (int i = 0; i < 4; i++)
#pragma unroll
    for (int j = 0; j < 4; j++) acc[i][j] = zero4;

  for (int k0 = 0; k0 < K; k0 += 32) {
    __syncthreads();
#pragma unroll
    for (int i = 0; i < 2; i++) {
      int idx = t * 2 + i;
      int r = idx >> 2, c = (idx & 3) * 8;
      int arow = bm + r;
      us8 vh, vl;
      if (arow < M) {
        vh = *(const us8*)(Ahg + (size_t)arow * K + k0 + c);
        vl = *(const us8*)(Alg + (size_t)arow * K + k0 + c);
      } else {
        vh = (us8)(u16)0;
        vl = (us8)(u16)0;
      }
      *(us8*)&sAh[r][c] = vh;
      *(us8*)&sAl[r][c] = vl;
      int brow = bn + r;
      *(us8*)&sBh[r][c] = *(const us8*)(Bhg + (size_t)brow * K + k0 + c);
      *(us8*)&sBl[r][c] = *(const us8*)(Blg + (size_t)brow * K + k0 + c);
    }
    __syncthreads();
    bf16x8 fah[4], fal[4], fbh[4], fbl[4];
#pragma unroll
    for (int mi = 0; mi < 4; mi++) {
      fah[mi] = *(const bf16x8*)&sAh[wm * 64 + mi * 16 + fr][kg * 8];
      fal[mi] = *(const bf16x8*)&sAl[wm * 64 + mi * 16 + fr][kg * 8];
    }
#pragma unroll
    for (int ni = 0; ni < 4; ni++) {
      fbh[ni] = *(const bf16x8*)&sBh[wn * 64 + ni * 16 + fr][kg * 8];
      fbl[ni] = *(const bf16x8*)&sBl[wn * 64 + ni * 16 + fr][kg * 8];
    }
#pragma unroll
    for (int mi = 0; mi < 4; mi++)
#pragma unroll
      for (int ni = 0; ni < 4; ni++) {
        acc[mi][ni] = __builtin_amdgcn_mfma_f32_16x16x32_bf16(fah[mi], fbh[ni], acc[mi][ni], 0, 0, 0);
        acc[mi][ni] = __builtin_amdgcn_mfma_f32_16x16x32_bf16(fah[mi], fbl[ni], acc[mi][ni], 0, 0, 0);
        acc[mi][ni] = __builtin_amdgcn_mfma_f32_16x16x32_bf16(fal[mi], fbh[ni], acc[mi][ni], 0, 0, 0);
      }
  }
#pragma unroll
  for (int mi = 0; mi < 4; mi++) {
    int rbase = bm + wm * 64 + mi * 16 + kg * 4;
#pragma unroll
    for (int ni = 0; ni < 4; ni++) {
      int col = bn + wn * 64 + ni * 16 + fr;
#pragma unroll
      for (int r = 0; r < 4; r++) {
        int row = rbase + r;
        if (row < M) Cb[(size_t)row * N + col] = f2bf(acc[mi][ni][r]);
      }
    }
  }
}

// ------------- fp32 tiled GEMM (small Wg GEMM), bf16 output -------------
template <int BN, int TN>
__global__ __launch_bounds__(256) void gemm_f32(const float* __restrict__ A,
                                                const float* __restrict__ B,
                                                u16* __restrict__ Cb, int M, int K, int Nld) {
  constexpr int BM = 128, BK = 16, TM = 8;
  __shared__ float As[BK][BM + 4];
  __shared__ float Bs[BK][BN + 4];
  const int tid = (int)threadIdx.x;
  const int bm = blockIdx.x * BM;
  const int bn = blockIdx.y * BN;
  const int arow = tid >> 1;
  const int acol = (tid & 1) * 8;
  const int brow = tid >> 4;
  const int bcol = (tid & 15) * (BN / 16);
  const int tmr = (tid >> 4) * TM;
  const int tnc = (tid & 15) * TN;

  float acc[TM][TN];
#pragma unroll
  for (int i = 0; i < TM; i++)
#pragma unroll
    for (int j = 0; j < TN; j++) acc[i][j] = 0.f;

  const bool avalid = (bm + arow) < M;
  const float* Arow = A + (size_t)(bm + arow) * K + acol;

  for (int k0 = 0; k0 < K; k0 += BK) {
    float4 a0, a1;
    if (avalid) {
      a0 = *(const float4*)(Arow + k0);
      a1 = *(const float4*)(Arow + k0 + 4);
    } else {
      a0 = make_float4(0.f, 0.f, 0.f, 0.f);
      a1 = a0;
    }
    float4 bv[BN / 64];
#pragma unroll
    for (int l = 0; l < BN / 64; l++)
      bv[l] = *(const float4*)(B + (size_t)(k0 + brow) * Nld + bn + bcol + 4 * l);
    __syncthreads();
    As[acol + 0][arow] = a0.x; As[acol + 1][arow] = a0.y;
    As[acol + 2][arow] = a0.z; As[acol + 3][arow] = a0.w;
    As[acol + 4][arow] = a1.x; As[acol + 5][arow] = a1.y;
    As[acol + 6][arow] = a1.z; As[acol + 7][arow] = a1.w;
#pragma unroll
    for (int l = 0; l < BN / 64; l++) *(float4*)&Bs[brow][bcol + 4 * l] = bv[l];
    __syncthreads();
#pragma unroll
    for (int k = 0; k < BK; k++) {
      float a[TM], b[TN];
#pragma unroll
      for (int i = 0; i < TM; i += 4) {
        float4 t = *(const float4*)&As[k][tmr + i];
        a[i] = t.x; a[i + 1] = t.y; a[i + 2] = t.z; a[i + 3] = t.w;
      }
#pragma unroll
      for (int j = 0; j < TN; j += 4) {
        float4 t = *(const float4*)&Bs[k][tnc + j];
        b[j] = t.x; b[j + 1] = t.y; b[j + 2] = t.z; b[j + 3] = t.w;
      }
#pragma unroll
      for (int i = 0; i < TM; i++)
#pragma unroll
        for (int j = 0; j < TN; j++) acc[i][j] += a[i] * b[j];
    }
  }
#pragma unroll
  for (int i = 0; i < TM; i++) {
    int row = bm + tmr + i;
    if (row < M) {
#pragma unroll
      for (int j = 0; j < TN; j += 4) {
        ushort4 t;
        t.x = f2bf(acc[i][j]); t.y = f2bf(acc[i][j + 1]);
        t.z = f2bf(acc[i][j + 2]); t.w = f2bf(acc[i][j + 3]);
        *(ushort4*)(Cb + (size_t)row * Nld + bn + tnc + j) = t;
      }
    }
  }
}

// as/ad projections: one us8 load + 6 shuffles per node.
__global__ void attn_proj(const u16* __restrict__ hfeat, const float* __restrict__ aS,
                          const float* __restrict__ aD, float* __restrict__ as_h,
                          float* __restrict__ ad_h) {
  int wid = (blockIdx.x * 256 + (int)threadIdx.x) >> 6;
  int lane = (int)threadIdx.x & 63;
  if (wid >= NN) return;
  us8 hv = *(const us8*)(hfeat + (size_t)wid * HD + lane * 8);
  float4 s0 = *(const float4*)(aS + lane * 8), s1 = *(const float4*)(aS + lane * 8 + 4);
  float4 d0 = *(const float4*)(aD + lane * 8), d1 = *(const float4*)(aD + lane * 8 + 4);
  float h0 = bf2f(hv[0]), h1 = bf2f(hv[1]), h2 = bf2f(hv[2]), h3 = bf2f(hv[3]);
  float h4 = bf2f(hv[4]), h5 = bf2f(hv[5]), h6 = bf2f(hv[6]), h7 = bf2f(hv[7]);
  float sv = h0 * s0.x + h1 * s0.y + h2 * s0.z + h3 * s0.w +
             h4 * s1.x + h5 * s1.y + h6 * s1.z + h7 * s1.w;
  float dv = h0 * d0.x + h1 * d0.y + h2 * d0.z + h3 * d0.w +
             h4 * d1.x + h5 * d1.y + h6 * d1.z + h7 * d1.w;
#pragma unroll
  for (int o = 1; o < 8; o <<= 1) {
    sv += __shfl_xor(sv, o);
    dv += __shfl_xor(dv, o);
  }
  float svh = __shfl(sv, (lane & 7) * 8);
  float dvh = __shfl(dv, (lane & 7) * 8);
  if (lane < 8) {
    as_h[wid * HEADS + lane] = svh;
    ad_h[wid * HEADS + lane] = dvh;
  }
}

// Block-level merge of per-wave (graph, sum, sumsq) then atomics.
static __device__ __forceinline__ void block_stats_accum(float v, float v2, int g, int lane,
                                                         float* __restrict__ gsum,
                                                         float* __restrict__ gsumsq) {
#pragma unroll
  for (int o = 32; o; o >>= 1) {
    v += __shfl_xor(v, o);
    v2 += __shfl_xor(v2, o);
  }
  __shared__ float s_v[4], s_v2[4];
  __shared__ int s_g[4];
  int wavei = (int)threadIdx.x >> 6;
  if (lane == 0) {
    s_v[wavei] = v;
    s_v2[wavei] = v2;
    s_g[wavei] = g;
  }
  __syncthreads();
  if (threadIdx.x == 0) {
#pragma unroll
    for (int a = 0; a < 4; a++) {
      int ga = s_g[a];
      if (ga < 0) continue;
      float V = s_v[a], V2 = s_v2[a];
#pragma unroll
      for (int b = a + 1; b < 4; b++)
        if (s_g[b] == ga) {
          V += s_v[b];
          V2 += s_v2[b];
          s_g[b] = -1;
        }
      atomicAdd(&gsum[ga], V);
      atomicAdd(&gsumsq[ga], V2);
    }
  }
}

// One wave per NODE, all 8 heads; bf16 gather. Single-round issue of up to 16
// edge-row loads per chunk (wave-uniform per-slot guards -> no waste, no
// divergence; deg<=16 nodes complete all loads in ONE latency round).
// MODE 0: out row (bf16) = alpha-agg + bias, fused LN stats (fp32).
// MODE 1 (layer 3): head-mean + b3 -> outf[N,64] fp32, fused LN stats.
template <int MODE>
__global__ void gat_agg(const u16* __restrict__ hfeat, const float* __restrict__ as_h,
                        const float* __restrict__ ad_h, const int* __restrict__ src_csr,
                        const int* __restrict__ off, const float* __restrict__ bias,
                        u16* __restrict__ outb, float* __restrict__ outf,
                        const int* __restrict__ batch,
                        float* __restrict__ gsum, float* __restrict__ gsumsq) {
  int wid = (blockIdx.x * 256 + (int)threadIdx.x) >> 6;  // node (grid exact)
  int lane = (int)threadIdx.x & 63;
  int n = wid;
  int s0 = off[n], deg = off[n + 1] - s0;
  int hS = lane & 7;   // score-role head
  int eS = lane >> 3;  // score-role edge slot
  int hF = lane >> 3;  // feature-role head
  float adv = ad_h[n * HEADS + hS];

  float4 a0 = make_float4(0.f, 0.f, 0.f, 0.f), a1 = a0;
  float ssum = 0.f;
  for (int base = 0; base < deg; base += 16) {
    // scores for two 8-edge slots (per-lane guards; deg wave-uniform)
    int iA = base + eS, iB = base + 8 + eS;
    float wlA = 0.f, wlB = 0.f;
    int mA = 0, mB = 0;
    if (iA < deg) {
      mA = src_csr[s0 + iA];
      float ev = as_h[mA * HEADS + hS] + adv;
      ev = (ev > 0.f) ? ev : 0.2f * ev;
      wlA = __expf(ev);  // scores O(1); no segmax shift needed
    }
    if (iB < deg) {
      mB = src_csr[s0 + iB];
      float ev = as_h[mB * HEADS + hS] + adv;
      ev = (ev > 0.f) ? ev : 0.2f * ev;
      wlB = __expf(ev);
    }
    ssum += wlA + wlB;
    // issue up to 16 feature-row loads (wave-uniform guards, all in flight)
    us8 v0, v1, v2, v3, v4, v5, v6, v7, v8, v9, v10, v11, v12, v13, v14, v15;
    const size_t lo8 = (size_t)lane * 8;
    if (base + 0 < deg)  v0  = *(const us8*)(hfeat + (size_t)__shfl(mA, 0)  * HD + lo8);
    if (base + 1 < deg)  v1  = *(const us8*)(hfeat + (size_t)__shfl(mA, 8)  * HD + lo8);
    if (base + 2 < deg)  v2  = *(const us8*)(hfeat + (size_t)__shfl(mA, 16) * HD + lo8);
    if (base + 3 < deg)  v3  = *(const us8*)(hfeat + (size_t)__shfl(mA, 24) * HD + lo8);
    if (base + 4 < deg)  v4  = *(const us8*)(hfeat + (size_t)__shfl(mA, 32) * HD + lo8);
    if (base + 5 < deg)  v5  = *(const us8*)(hfeat + (size_t)__shfl(mA, 40) * HD + lo8);
    if (base + 6 < deg)  v6  = *(const us8*)(hfeat + (size_t)__shfl(mA, 48) * HD + lo8);
    if (base + 7 < deg)  v7  = *(const us8*)(hfeat + (size_t)__shfl(mA, 56) * HD + lo8);
    if (base + 8 < deg)  v8  = *(const us8*)(hfeat + (size_t)__shfl(mB, 0)  * HD + lo8);
    if (base + 9 < deg)  v9  = *(const us8*)(hfeat + (size_t)__shfl(mB, 8)  * HD + lo8);
    if (base + 10 < deg) v10 = *(const us8*)(hfeat + (size_t)__shfl(mB, 16) * HD + lo8);
    if (base + 11 < deg) v11 = *(const us8*)(hfeat + (size_t)__shfl(mB, 24) * HD + lo8);
    if (base + 12 < deg) v12 = *(const us8*)(hfeat + (size_t)__shfl(mB, 32) * HD + lo8);
    if (base + 13 < deg) v13 = *(const us8*)(hfeat + (size_t)__shfl(mB, 40) * HD + lo8);
    if (base + 14 < deg) v14 = *(const us8*)(hfeat + (size_t)__shfl(mB, 48) * HD + lo8);
    if (base + 15 < deg) v15 = *(const us8*)(hfeat + (size_t)__shfl(mB, 56) * HD + lo8);
    // consume (same guards)
    if (base + 0 < deg)  acc8(a0, a1, __shfl(wlA, 0 + hF),  v0);
    if (base + 1 < deg)  acc8(a0, a1, __shfl(wlA, 8 + hF),  v1);
    if (base + 2 < deg)  acc8(a0, a1, __shfl(wlA, 16 + hF), v2);
    if (base + 3 < deg)  acc8(a0, a1, __shfl(wlA, 24 + hF), v3);
    if (base + 4 < deg)  acc8(a0, a1, __shfl(wlA, 32 + hF), v4);
    if (base + 5 < deg)  acc8(a0, a1, __shfl(wlA, 40 + hF), v5);
    if (base + 6 < deg)  acc8(a0, a1, __shfl(wlA, 48 + hF), v6);
    if (base + 7 < deg)  acc8(a0, a1, __shfl(wlA, 56 + hF), v7);
    if (base + 8 < deg)  acc8(a0, a1, __shfl(wlB, 0 + hF),  v8);
    if (base + 9 < deg)  acc8(a0, a1, __shfl(wlB, 8 + hF),  v9);
    if (base + 10 < deg) acc8(a0, a1, __shfl(wlB, 16 + hF), v10);
    if (base + 11 < deg) acc8(a0, a1, __shfl(wlB, 24 + hF), v11);
    if (base + 12 < deg) acc8(a0, a1, __shfl(wlB, 32 + hF), v12);
    if (base + 13 < deg) acc8(a0, a1, __shfl(wlB, 40 + hF), v13);
    if (base + 14 < deg) acc8(a0, a1, __shfl(wlB, 48 + hF), v14);
    if (base + 15 < deg) acc8(a0, a1, __shfl(wlB, 56 + hF), v15);
  }
  // reduce ssum over edge-slot lanes (same head = same lane&7)
  ssum += __shfl_xor(ssum, 8);
  ssum += __shfl_xor(ssum, 16);
  ssum += __shfl_xor(ssum, 32);
  float inv = 1.f / (__shfl(ssum, hF) + 1e-16f);  // lane hF (<8) holds head hF total
  a0.x *= inv; a0.y *= inv; a0.z *= inv; a0.w *= inv;
  a1.x *= inv; a1.y *= inv; a1.z *= inv; a1.w *= inv;

  if (MODE == 0) {
    const float4* bp = (const float4*)(bias + lane * 8);
    float4 b0 = bp[0], b1v = bp[1];
    a0.x += b0.x; a0.y += b0.y; a0.z += b0.z; a0.w += b0.w;
    a1.x += b1v.x; a1.y += b1v.y; a1.z += b1v.z; a1.w += b1v.w;
    us8 ov;
    ov[0] = f2bf(a0.x); ov[1] = f2bf(a0.y); ov[2] = f2bf(a0.z); ov[3] = f2bf(a0.w);
    ov[4] = f2bf(a1.x); ov[5] = f2bf(a1.y); ov[6] = f2bf(a1.z); ov[7] = f2bf(a1.w);
    *(us8*)(outb + (size_t)n * HD + lane * 8) = ov;
    float v = a0.x + a0.y + a0.z + a0.w + a1.x + a1.y + a1.z + a1.w;
    float v2 = a0.x * a0.x + a0.y * a0.y + a0.z * a0.z + a0.w * a0.w +
               a1.x * a1.x + a1.y * a1.y + a1.z * a1.z + a1.w * a1.w;
    block_stats_accum(v, v2, batch[n], lane, gsum, gsumsq);
  } else {
    // sum over heads: lanes with same (lane&7) hold same cols of different heads
#pragma unroll
    for (int o = 8; o <= 32; o <<= 1) {
      a0.x += __shfl_xor(a0.x, o); a0.y += __shfl_xor(a0.y, o);
      a0.z += __shfl_xor(a0.z, o); a0.w += __shfl_xor(a0.w, o);
      a1.x += __shfl_xor(a1.x, o); a1.y += __shfl_xor(a1.y, o);
      a1.z += __shfl_xor(a1.z, o); a1.w += __shfl_xor(a1.w, o);
    }
    const float4* bp = (const float4*)(bias + (lane & 7) * 8);  // bias = b3[64]
    float4 b0 = bp[0], b1v = bp[1];
    a0.x = a0.x * 0.125f + b0.x; a0.y = a0.y * 0.125f + b0.y;
    a0.z = a0.z * 0.125f + b0.z; a0.w = a0.w * 0.125f + b0.w;
    a1.x = a1.x * 0.125f + b1v.x; a1.y = a1.y * 0.125f + b1v.y;
    a1.z = a1.z * 0.125f + b1v.z; a1.w = a1.w * 0.125f + b1v.w;
    if (lane < 8) {
      float4* op = (float4*)(outf + (size_t)n * HIDN + lane * 8);
      op[0] = a0;
      op[1] = a1;
    }
    float v = 0.f, v2 = 0.f;
    if (lane < 8) {
      v = a0.x + a0.y + a0.z + a0.w + a1.x + a1.y + a1.z + a1.w;
      v2 = a0.x * a0.x + a0.y * a0.y + a0.z * a0.z + a0.w * a0.w +
           a1.x * a1.x + a1.y * a1.y + a1.z * a1.z + a1.w * a1.w;
    }
    block_stats_accum(v, v2, batch[n], lane, gsum, gsumsq);
  }
}

// One wave per node; bf16 feature gather, 4-wide unrolled inner loop.
__global__ void gcn_agg(const u16* __restrict__ hg, const float* __restrict__ dinv,
                        const int* __restrict__ off, const int* __restrict__ src_csr,
                        const float* __restrict__ bg, const int* __restrict__ batch,
                        float* __restrict__ z) {
  int wid = (blockIdx.x * 256 + (int)threadIdx.x) >> 6;
  int lane = (int)threadIdx.x & 63;
  if (wid >= NN) return;
  int n = wid;
  int s0 = off[n], s1 = off[n + 1];
  int deg = s1 - s0;
  float acc = 0.f;
  for (int base = 0; base < deg; base += 64) {
    int i = base + lane;
    int msrc = (i < deg) ? src_csr[s0 + i] : 0;
    float mdv = (i < deg) ? dinv[msrc] : 0.f;
    int cnt = min(64, deg - base);
    int e = 0;
    for (; e + 4 <= cnt; e += 4) {
      float dv0 = __shfl(mdv, e), dv1 = __shfl(mdv, e + 1);
      float dv2 = __shfl(mdv, e + 2), dv3 = __shfl(mdv, e + 3);
      int r0 = __shfl(msrc, e), r1 = __shfl(msrc, e + 1);
      int r2 = __shfl(msrc, e + 2), r3 = __shfl(msrc, e + 3);
      float h0 = bf2f(hg[(size_t)r0 * HIDN + lane]);
      float h1 = bf2f(hg[(size_t)r1 * HIDN + lane]);
      float h2 = bf2f(hg[(size_t)r2 * HIDN + lane]);
      float h3 = bf2f(hg[(size_t)r3 * HIDN + lane]);
      acc += dv0 * h0 + dv1 * h1 + dv2 * h2 + dv3 * h3;
    }
    for (; e < cnt; ++e) {
      float dv = __shfl(mdv, e);
      int src = __shfl(msrc, e);
      acc += dv * bf2f(hg[(size_t)src * HIDN + lane]);
    }
  }
  float y = fmaxf(acc * dinv[n] + bg[lane], 0.f);
  atomicMaxNonneg(&z[batch[n] * 128 + 64 + lane], y);
}

// LN+ReLU on bf16 input -> bf16 hi/lo split (4 elems/thread)
template <int F>
__global__ void ln_apply_split(const u16* __restrict__ buf, const int* __restrict__ batch,
                               const float* __restrict__ gsum, const float* __restrict__ gsumsq,
                               const int* __restrict__ gcnt, const float* __restrict__ w,
                               const float* __restrict__ b, u16* __restrict__ hi,
                               u16* __restrict__ lo) {
  int i4 = blockIdx.x * 256 + (int)threadIdx.x;
  if (i4 >= NN * F / 4) return;
  int n = i4 / (F / 4), f = (i4 % (F / 4)) * 4;
  int g = batch[n];
  float cnt = (float)gcnt[g] * (float)F;
  float mean = gsum[g] / cnt;
  float var = gsumsq[g] / cnt - mean * mean;
  float rs = rsqrtf(var + 1e-5f);
  ushort4 hv = *(const ushort4*)(buf + (size_t)n * F + f);
  float4 wv = *(const float4*)(w + f);
  float4 bv = *(const float4*)(b + f);
  float y0 = fmaxf((bf2f(hv.x) - mean) * rs * wv.x + bv.x, 0.f);
  float y1 = fmaxf((bf2f(hv.y) - mean) * rs * wv.y + bv.y, 0.f);
  float y2 = fmaxf((bf2f(hv.z) - mean) * rs * wv.z + bv.z, 0.f);
  float y3 = fmaxf((bf2f(hv.w) - mean) * rs * wv.w + bv.w, 0.f);
  ushort4 hh, ll;
  hh.x = f2bf(y0); ll.x = f2bf(y0 - bf2f(hh.x));
  hh.y = f2bf(y1); ll.y = f2bf(y1 - bf2f(hh.y));
  hh.z = f2bf(y2); ll.z = f2bf(y2 - bf2f(hh.z));
  hh.w = f2bf(y3); ll.w = f2bf(y3 - bf2f(hh.w));
  *(ushort4*)(hi + (size_t)n * F + f) = hh;
  *(ushort4*)(lo + (size_t)n * F + f) = ll;
}

template <int F, bool ZMAX>
__global__ void ln_apply(float* __restrict__ buf, const int* __restrict__ batch,
                         const float* __restrict__ gsum, const float* __restrict__ gsumsq,
                         const int* __restrict__ gcnt, const float* __restrict__ w,
                         const float* __restrict__ b, float* __restrict__ z) {
  int i = blockIdx.x * 256 + (int)threadIdx.x;
  if (i >= NN * F) return;
  int n = i / F, f = i % F;
  int g = batch[n];
  float cnt = (float)gcnt[g] * (float)F;
  float mean = gsum[g] / cnt;
  float var = gsumsq[g] / cnt - mean * mean;
  float y = (buf[i] - mean) * rsqrtf(var + 1e-5f) * w[f] + b[f];
  y = fmaxf(y, 0.f);
  buf[i] = y;
  if (ZMAX) atomicMaxNonneg(&z[g * 128 + f], y);
}

__global__ __launch_bounds__(64) void mlp_head(const float* __restrict__ z,
                                               const float* __restrict__ Wl0, const float* __restrict__ bl0,
                                               const float* __restrict__ Wl1, const float* __restrict__ bl1,
                                               const float* __restrict__ Wl2, const float* __restrict__ bl2,
                                               const float* __restrict__ Wo, const float* __restrict__ bo,
                                               float* __restrict__ out) {
  __shared__ float zs[128], t0[64], t1[64], t2[64];
  int g = blockIdx.x, t = (int)threadIdx.x;
  zs[t] = z[g * 128 + t];
  zs[64 + t] = z[g * 128 + 64 + t];
  __syncthreads();
  float a = bl0[t];
  for (int k = 0; k < 128; k++) a += zs[k] * Wl0[k * 64 + t];
  t0[t] = fmaxf(a, 0.f);
  __syncthreads();
  a = bl1[t];
  for (int k = 0; k < 64; k++) a += t0[k] * Wl1[k * 64 + t];
  t1[t] = fmaxf(a, 0.f);
  __syncthreads();
  a = bl2[t];
  for (int k = 0; k < 64; k++) a += t1[k] * Wl2[k * 64 + t];
  t2[t] = fmaxf(a, 0.f);
  __syncthreads();
  if (t < 2) {
    float o = bo[t];
    for (int k = 0; k < 64; k++) o += t2[k] * Wo[k * 2 + t];
    out[g * 2 + t] = o;
  }
  out[128 + g * 128 + t] = zs[t];
  out[128 + g * 128 + 64 + t] = zs[64 + t];
}

extern "C" void kernel_launch(void* const* d_in, const int* in_sizes, int n_in,
                              void* d_out, int out_size, void* d_ws, size_t ws_size,
                              hipStream_t stream) {
  const float* x = (const float*)d_in[0];
  const int* ei = (const int*)d_in[1];
  const int* batch = (const int*)d_in[2];
  const float* W1 = (const float*)d_in[3];
  const float* aS1 = (const float*)d_in[4];
  const float* aD1 = (const float*)d_in[5];
  const float* b1 = (const float*)d_in[6];
  const float* W2 = (const float*)d_in[7];
  const float* aS2 = (const float*)d_in[8];
  const float* aD2 = (const float*)d_in[9];
  const float* b2 = (const float*)d_in[10];
  const float* W3 = (const float*)d_in[11];
  const float* aS3 = (const float*)d_in[12];
  const float* aD3 = (const float*)d_in[13];
  const float* b3 = (const float*)d_in[14];
  const float* Wg = (const float*)d_in[15];
  const float* bg = (const float*)d_in[16];
  const float* nw1 = (const float*)d_in[17];
  const float* nb1 = (const float*)d_in[18];
  const float* nw2 = (const float*)d_in[19];
  const float* nb2 = (const float*)d_in[20];
  const float* nw3 = (const float*)d_in[21];
  const float* nb3 = (const float*)d_in[22];
  const float* Wl0 = (const float*)d_in[23];
  const float* bl0 = (const float*)d_in[24];
  const float* Wl1 = (const float*)d_in[25];
  const float* bl1 = (const float*)d_in[26];
  const float* Wl2 = (const float*)d_in[27];
  const float* bl2 = (const float*)d_in[28];
  const float* Wo = (const float*)d_in[29];
  const float* bo = (const float*)d_in[30];
  float* out = (float*)d_out;

  char* wp = (char*)d_ws;
  auto alloc = [&](size_t bytes) -> void* {
    void* p = (void*)wp;
    wp += ((bytes + 255) & ~(size_t)255);
    return p;
  };
  u16* bufHb = (u16*)alloc((size_t)NN * HD * 2);      // GEMM output, bf16
  u16* bufAb = (u16*)alloc((size_t)NN * HD * 2);      // aggregation output, bf16
  float* f64b = (float*)alloc((size_t)NN * HIDN * 4); // layer-3 h3 (fp32)
  u16* gcnb = (u16*)alloc((size_t)NN * HIDN * 2);     // gcn features bf16
  float* as_h = (float*)alloc((size_t)NN * HEADS * 4);
  float* ad_h = (float*)alloc((size_t)NN * HEADS * 4);
  const int ZWORDS = NN + NG + 6 * NG + NG * 128;
  int* initblk = (int*)alloc((size_t)ZWORDS * 4);
  int* deg = initblk;
  int* gcnt = deg + NN;
  float* stats = (float*)(gcnt + NG);
  float* zbuf = stats + 6 * NG;
  int* off = (int*)alloc((size_t)(NN + 1) * 4);
  int* cur = (int*)alloc((size_t)NN * 4);
  int* src_csr = (int*)alloc((size_t)NE2 * 4);
  float* dinv = (float*)alloc((size_t)NN * 4);
  int* bsum = (int*)alloc((size_t)256 * 4);
  int* boff = (int*)alloc((size_t)256 * 4);
  u16* xhi = (u16*)alloc((size_t)NN * FEATN * 2);
  u16* xlo = (u16*)alloc((size_t)NN * FEATN * 2);
  u16* ahi = (u16*)alloc((size_t)NN * HD * 2);
  u16* alo = (u16*)alloc((size_t)NN * HD * 2);
  u16* w1h = (u16*)alloc((size_t)FEATN * HD * 2);
  u16* w1l = (u16*)alloc((size_t)FEATN * HD * 2);
  u16* w2h = (u16*)alloc((size_t)HD * HD * 2);
  u16* w2l = (u16*)alloc((size_t)HD * HD * 2);
  u16* w3h = (u16*)alloc((size_t)HD * HD * 2);
  u16* w3l = (u16*)alloc((size_t)HD * HD * 2);

  dim3 b256(256);
  const int NB = (NN + 255) / 256;  // 79 scan blocks
  zero_u32<<<(ZWORDS + 255) / 256, b256, 0, stream>>>((unsigned int*)initblk, ZWORDS);
  build_counts<<<(NE2 + 255) / 256, b256, 0, stream>>>(ei, batch, deg, gcnt);
  scan_phase1<<<NB, b256, 0, stream>>>(deg, off, bsum, dinv, NN);
  scan_phase2<<<1, b256, 0, stream>>>(bsum, boff, NB, off + NN);
  scan_phase3<<<NB, b256, 0, stream>>>(off, boff, cur, NN);
  scatter_csr<<<(NE2 + 255) / 256, b256, 0, stream>>>(ei, cur, src_csr);
  const int WTOT = FEATN * HD + 2 * HD * HD;
  split_weightsT<<<(WTOT + 255) / 256, b256, 0, stream>>>(W1, W2, W3, w1h, w1l, w2h, w2l, w3h, w3l);
  split_mat<<<(NN * FEATN / 4 + 255) / 256, b256, 0, stream>>>(x, xhi, xlo, NN * FEATN / 4);

  const int wgrid = (NN * 64) / 256;  // one wave per node (exact: 5000 blocks)
  dim3 gmm((NN + 127) / 128, HD / 128);

  // GCN branch (bf16 features)
  {
    dim3 g((NN + 127) / 128, 1);
    gemm_f32<64, 4><<<g, b256, 0, stream>>>(x, Wg, gcnb, NN, FEATN, HIDN);
    gcn_agg<<<wgrid, b256, 0, stream>>>(gcnb, dinv, off, src_csr, bg, batch, zbuf);
  }
  // GAT layer 1
  {
    gemm_bf3<FEATN, HD><<<gmm, b256, 0, stream>>>(xhi, xlo, w1h, w1l, bufHb, NN);
    attn_proj<<<wgrid, b256, 0, stream>>>(bufHb, aS1, aD1, as_h, ad_h);
    gat_agg<0><<<wgrid, b256, 0, stream>>>(bufHb, as_h, ad_h, src_csr, off, b1, bufAb,
                                           nullptr, batch, stats + 0, stats + NG);
    ln_apply_split<HD><<<(NN * HD / 4 + 255) / 256, b256, 0, stream>>>(
        bufAb, batch, stats + 0, stats + NG, gcnt, nw1, nb1, ahi, alo);
  }
  // GAT layer 2
  {
    gemm_bf3<HD, HD><<<gmm, b256, 0, stream>>>(ahi, alo, w2h, w2l, bufHb, NN);
    attn_proj<<<wgrid, b256, 0, stream>>>(bufHb, aS2, aD2, as_h, ad_h);
    gat_agg<0><<<wgrid, b256, 0, stream>>>(bufHb, as_h, ad_h, src_csr, off, b2, bufAb,
                                           nullptr, batch, stats + 2 * NG, stats + 3 * NG);
    ln_apply_split<HD><<<(NN * HD / 4 + 255) / 256, b256, 0, stream>>>(
        bufAb, batch, stats + 2 * NG, stats + 3 * NG, gcnt, nw2, nb2, ahi, alo);
  }
  // GAT layer 3 (head-mean + b3 + stats fused into gat_agg)
  {
    gemm_bf3<HD, HD><<<gmm, b256, 0, stream>>>(ahi, alo, w3h, w3l, bufHb, NN);
    attn_proj<<<wgrid, b256, 0, stream>>>(bufHb, aS3, aD3, as_h, ad_h);
    gat_agg<1><<<wgrid, b256, 0, stream>>>(bufHb, as_h, ad_h, src_csr, off, b3, nullptr,
                                           f64b, batch, stats + 4 * NG, stats + 5 * NG);
    ln_apply<HIDN, true><<<(NN * HIDN + 255) / 256, b256, 0, stream>>>(
        f64b, batch, stats + 4 * NG, stats + 5 * NG, gcnt, nw3, nb3, zbuf);
  }
  mlp_head<<<NG, 64, 0, stream>>>(zbuf, Wl0, bl0, Wl1, bl1, Wl2, bl2, Wo, bo, out);
}